// Round 10
// baseline (1208.702 us; speedup 1.0000x reference)
//
#include <hip/hip_runtime.h>

#define N_NODES 100000
#define N_EDGES 220000
#define N_B     4096
#define HIDDEN  256
#define BN_S    0.9999950000374997f
#define NSCANB  98       // ceil(100000/1024)

typedef __attribute__((ext_vector_type(8))) short bf16x8;
typedef __attribute__((ext_vector_type(4))) float f32x4;

__device__ __forceinline__ float bf2f(unsigned short u) {
  return __uint_as_float(((unsigned int)u) << 16);
}
__device__ __forceinline__ unsigned short f2bf(float f) {
  unsigned int x = __float_as_uint(f);
  unsigned int lsb = (x >> 16) & 1u;
  x += 0x7fffu + lsb;
  return (unsigned short)(x >> 16);
}

// async global->LDS 16B: dest is wave-uniform base + lane*16 (linear);
// per-lane GLOBAL address carries the XOR swizzle (m173 pattern).
__device__ __forceinline__ void g2lds16(const void* g, void* l) {
  __builtin_amdgcn_global_load_lds(
      (const __attribute__((address_space(1))) unsigned int*)g,
      (__attribute__((address_space(3))) unsigned int*)l, 16, 0, 0);
}

// bijective XCD swizzle (m204)
__device__ __forceinline__ int xcd_swz(int b, int nwg) {
  int q = nwg >> 3, r = nwg & 7;
  int xcd = b & 7, idx = b >> 3;
  int base = (xcd < r) ? xcd * (q + 1) : r * (q + 1) + (xcd - r) * q;
  return base + idx;
}

// ---------------- zero-init of counters ----------------
__global__ void zero_kernel(int* __restrict__ deg, int* __restrict__ cursor, float* __restrict__ macc) {
  int i = blockIdx.x * blockDim.x + threadIdx.x;
  if (i < N_NODES) { deg[i] = 0; cursor[i] = 0; }
  if (i < 16) macc[i] = 0.f;
}

// ---------------- mean of edge_attr (block-reduced, 1 atomic/k/block) ----------------
__global__ __launch_bounds__(256) void mean_kernel(const float* __restrict__ ea, float* __restrict__ macc) {
  __shared__ float sred[4][16];
  int lane = threadIdx.x & 63;
  int wv = threadIdx.x >> 6;
  float loc[10];
#pragma unroll
  for (int k = 0; k < 10; ++k) loc[k] = 0.f;
  for (int e = blockIdx.x * blockDim.x + threadIdx.x; e < N_EDGES; e += gridDim.x * blockDim.x) {
    const float* p = ea + (size_t)e * 10;
#pragma unroll
    for (int k = 0; k < 10; ++k) loc[k] += p[k];
  }
#pragma unroll
  for (int k = 0; k < 10; ++k) {
    float v = loc[k];
#pragma unroll
    for (int o = 1; o < 64; o <<= 1) v += __shfl_xor(v, o);
    if (lane == 0) sred[wv][k] = v;
  }
  __syncthreads();
  if (threadIdx.x < 10) {
    float s = sred[0][threadIdx.x] + sred[1][threadIdx.x] +
              sred[2][threadIdx.x] + sred[3][threadIdx.x];
    atomicAdd(&macc[threadIdx.x], s);
  }
}

__global__ void meanattr_kernel(const float* __restrict__ macc, float* __restrict__ meanattr) {
  int t = threadIdx.x;
  const float invE = 1.f / (float)N_EDGES;
  if (t < 10) meanattr[t] = macc[t] * invE;
}

// ---------------- ep_self[i][c] = meanattr . We[i][:,c] ----------------
__global__ void epself_kernel(const float* __restrict__ meanattr, const float* __restrict__ We,
                              float* __restrict__ ep_self) {
  int i = blockIdx.x;
  int c = threadIdx.x;
  float s = 0.f;
#pragma unroll
  for (int k = 0; k < 10; ++k)
    s += meanattr[k] * We[(size_t)i * 2560 + k * 256 + c];
  ep_self[i * 256 + c] = s;
}

// ---------------- CSR build (REAL edges only) ----------------
__global__ void count_kernel(const int* __restrict__ ei, int* __restrict__ deg) {
  for (int e = blockIdx.x * blockDim.x + threadIdx.x; e < N_EDGES; e += gridDim.x * blockDim.x) {
    atomicAdd(&deg[ei[N_EDGES + e]], 1);
  }
}

// ---------------- 3-phase scan ----------------
__global__ __launch_bounds__(1024) void scan1_kernel(const int* __restrict__ deg,
                                                     int* __restrict__ rowptr,
                                                     int* __restrict__ bsum) {
  __shared__ int buf[1024];
  int t = threadIdx.x;
  int i = blockIdx.x * 1024 + t;
  int v = (i < N_NODES) ? deg[i] : 0;
  buf[t] = v;
  __syncthreads();
  for (int off = 1; off < 1024; off <<= 1) {
    int add = (t >= off) ? buf[t - off] : 0;
    __syncthreads();
    buf[t] += add;
    __syncthreads();
  }
  if (i < N_NODES) rowptr[i + 1] = buf[t];
  if (t == 1023) bsum[blockIdx.x] = buf[t];
  if (i == 0) rowptr[0] = 0;
}

__global__ __launch_bounds__(128) void scan2_kernel(int* __restrict__ bsum) {
  __shared__ int buf[128];
  int t = threadIdx.x;
  int v = (t < NSCANB) ? bsum[t] : 0;
  buf[t] = v;
  __syncthreads();
  for (int off = 1; off < 128; off <<= 1) {
    int add = (t >= off) ? buf[t - off] : 0;
    __syncthreads();
    buf[t] += add;
    __syncthreads();
  }
  if (t < NSCANB) bsum[t] = buf[t];
}

__global__ __launch_bounds__(1024) void scan3_kernel(int* __restrict__ rowptr,
                                                     const int* __restrict__ bsum) {
  int b = blockIdx.x;
  if (b == 0) return;
  int i = b * 1024 + threadIdx.x;
  if (i < N_NODES) rowptr[i + 1] += bsum[b - 1];
}

__global__ void scatter_kernel(const int* __restrict__ ei, const int* __restrict__ rowptr,
                               int* __restrict__ cursor, int* __restrict__ csr) {
  for (int e = blockIdx.x * blockDim.x + threadIdx.x; e < N_EDGES; e += gridDim.x * blockDim.x) {
    int t = ei[N_EDGES + e];
    int pos = atomicAdd(&cursor[t], 1);
    csr[rowptr[t] + pos] = e;
  }
}

__global__ void brp_kernel(const int* __restrict__ batch, int* __restrict__ brp) {
  for (int i = blockIdx.x * blockDim.x + threadIdx.x; i < N_NODES; i += gridDim.x * blockDim.x) {
    int bi = batch[i];
    int bp = (i == 0) ? -1 : batch[i - 1];
    for (int b = bp + 1; b <= bi; ++b) brp[b] = i;
    if (i == N_NODES - 1) {
      for (int b = bi + 1; b <= N_B; ++b) brp[b] = N_NODES;
    }
  }
}

// ---------------- x -> padded bf16 [N,128] (K pad for BK=64 GEMM) ----------------
__global__ void convx_kernel(const float* __restrict__ x, unsigned short* __restrict__ xp) {
  int total = N_NODES * 128;
  for (int idx = blockIdx.x * blockDim.x + threadIdx.x; idx < total; idx += gridDim.x * blockDim.x) {
    int nn = idx >> 7;
    int j = idx & 127;
    unsigned short v = 0;
    if (j < 75) v = f2bf(x[(size_t)nn * 75 + j]);
    xp[idx] = v;
  }
}

// ---------------- weight transpose+bf16 ----------------
__global__ void wt_kernel(const float* __restrict__ src, unsigned short* __restrict__ dst,
                          int K, int Kp, int N) {
  int idx = blockIdx.x * blockDim.x + threadIdx.x;
  int total = N * Kp;
  if (idx >= total) return;
  int n = idx / Kp, k = idx - n * Kp;
  dst[idx] = (k < K) ? f2bf(src[(size_t)k * N + n]) : (unsigned short)0;
}

// ---------------- all 4 layers Wl^T||Wr^T in one launch ----------------
__global__ void wlr_kernel(const float* __restrict__ Wl, const float* __restrict__ Wr,
                           unsigned short* __restrict__ dst) {
  const int total = 4 * 512 * 256;
  for (int idx = blockIdx.x * blockDim.x + threadIdx.x; idx < total; idx += gridDim.x * blockDim.x) {
    int i = idx >> 17;          // /131072
    int rem = idx & 131071;
    int n = rem >> 8;           // 0..511
    int k = rem & 255;
    float v = (n < 256) ? Wl[(size_t)i * 65536 + k * 256 + n]
                        : Wr[(size_t)i * 65536 + k * 256 + (n - 256)];
    dst[idx] = f2bf(v);
  }
}

// ---------------- bf16 MFMA GEMM, BK=64 staging + LDS-staged C-write ----------------
// K-step 64 (32 MFMA per barrier pair, 2x the old amortization). LDS rows are
// 64 elems with XOR swizzle slot^=(row&7) applied on BOTH the pre-swizzled
// per-lane global source (g2lds dest linear) and the ds_read address.
// Requires K % 64 == 0.
__global__ __launch_bounds__(256) void gemm_mfma(
    const unsigned short* __restrict__ A, const unsigned short* __restrict__ Bt,
    const float* __restrict__ bias, float* __restrict__ Cf, unsigned short* __restrict__ Cb,
    int M, int Ncol, int K, int act, float scale, int gx)
{
  __shared__ unsigned short smem[16384];   // 32KB: As[128*64]+Bs[128*64]; C-stage reuses
  unsigned short* As = smem;
  unsigned short* Bs = smem + 8192;
  const int tid = threadIdx.x;
  const int wave = tid >> 6;
  const int lane = tid & 63;

  const int wg = xcd_swz(blockIdx.x, gridDim.x);
  const int col0 = (wg % gx) * 128;
  const int row0 = (wg / gx) * 128;

  const int wrow = (wave >> 1) * 64;
  const int wcol = (wave & 1) * 64;
  const int lrow = lane & 15;
  const int quad = lane >> 4;

  // staging: wave stages tile rows [32*wave, 32*wave+32); each g2lds = 8 rows.
  const int rbase = wave * 32;
  const int lr8 = lane >> 3;               // 0..7: row within 8-row group
  const int slot = lane & 7;               // 16B slot within 64-elem row
  const int sw = ((slot ^ lr8) << 3);      // pre-swizzled source elem offset (row&7 == lr8)
  const unsigned short* pa[4];
  const unsigned short* pb[4];
#pragma unroll
  for (int j = 0; j < 4; ++j) {
    int tr = rbase + j * 8 + lr8;
    int gra = row0 + tr; if (gra > M - 1) gra = M - 1;  // clamp: rows >= M discarded in epilogue
    pa[j] = A + (size_t)gra * K + sw;
    pb[j] = Bt + (size_t)(col0 + tr) * K + sw;
  }

  f32x4 acc[4][4] = {};

  for (int k0 = 0; k0 < K; k0 += 64) {
#pragma unroll
    for (int j = 0; j < 4; ++j)
      g2lds16(pa[j] + k0, &As[(rbase + j * 8) * 64]);
#pragma unroll
    for (int j = 0; j < 4; ++j)
      g2lds16(pb[j] + k0, &Bs[(rbase + j * 8) * 64]);
    __syncthreads();   // drains vmcnt (global_load_lds) before LDS reads
#pragma unroll
    for (int kk = 0; kk < 2; ++kk) {
      bf16x8 afr[4], bfr[4];
#pragma unroll
      for (int mt = 0; mt < 4; ++mt) {
        int rr = wrow + mt * 16 + lrow;
        afr[mt] = *(const bf16x8*)(&As[rr * 64 + ((((kk << 2) + quad) ^ (rr & 7)) << 3)]);
      }
#pragma unroll
      for (int nt = 0; nt < 4; ++nt) {
        int rr = wcol + nt * 16 + lrow;
        bfr[nt] = *(const bf16x8*)(&Bs[rr * 64 + ((((kk << 2) + quad) ^ (rr & 7)) << 3)]);
      }
#pragma unroll
      for (int mt = 0; mt < 4; ++mt)
#pragma unroll
        for (int nt = 0; nt < 4; ++nt)
          acc[mt][nt] = __builtin_amdgcn_mfma_f32_16x16x32_bf16(afr[mt], bfr[nt], acc[mt][nt], 0, 0, 0);
    }
    __syncthreads();
  }

  // ---- epilogue: two 64-row passes through LDS, coalesced 16B bf16 stores ----
#pragma unroll
  for (int p = 0; p < 2; ++p) {
#pragma unroll
    for (int mtl = 0; mtl < 2; ++mtl) {
      int mt = 2 * p + mtl;
#pragma unroll
      for (int nt = 0; nt < 4; ++nt) {
        int lcol = wcol + nt * 16 + lrow;
        float bv = bias ? bias[col0 + lcol] : 0.f;
#pragma unroll
        for (int r = 0; r < 4; ++r) {
          float v = (acc[mt][nt][r] + bv) * scale;
          if (act == 1) v = fmaxf(v, 0.f);
          else if (act == 2) v = (v > 0.f) ? v : (__expf(v) - 1.f);
          int srow = (wave >> 1) * 32 + mtl * 16 + quad * 4 + r;
          smem[srow * 136 + lcol] = f2bf(v);
          if (Cf) {
            int grow = row0 + wrow + mt * 16 + quad * 4 + r;
            if (grow < M) Cf[(size_t)grow * Ncol + col0 + lcol] = v;
          }
        }
      }
    }
    __syncthreads();
    if (Cb) {
#pragma unroll
      for (int round = 0; round < 4; ++round) {
        int s_r = round * 16 + (tid >> 4);
        int ce = (tid & 15) * 8;
        int w2 = s_r >> 5, mtl = (s_r >> 4) & 1, rr = s_r & 15;
        int grow = row0 + w2 * 64 + (2 * p + mtl) * 16 + rr;
        if (grow < M) {
          uint4 v = *(const uint4*)(&smem[s_r * 136 + ce]);
          *(uint4*)(Cb + (size_t)grow * Ncol + col0 + ce) = v;
        }
      }
    }
    __syncthreads();
  }
}

// ---------------- fused pooling-gate GEMM (single-buffer BK=32 staging, K=256) ----------------
__global__ __launch_bounds__(256) void gemm_gate(
    const unsigned short* __restrict__ A, const unsigned short* __restrict__ Bt,
    const float* __restrict__ bg1, const float* __restrict__ Wg2,
    const float* __restrict__ bg2, float* __restrict__ gate, int M)
{
  __shared__ unsigned short As[128 * 32];
  __shared__ unsigned short Bs[128 * 32];
  __shared__ float gbuf[128][2];
  const int tid = threadIdx.x;
  const int wave = tid >> 6;
  const int lane = tid & 63;

  const int wg = xcd_swz(blockIdx.x, gridDim.x);
  const int row0 = wg * 128;

  const int wrow = (wave >> 1) * 64;
  const int wcol = (wave & 1) * 64;
  const int lrow = lane & 15;
  const int quad = lane >> 4;

  const int rbase = wave * 32;
  const int lr4 = lane >> 2;
  const int lc = lane & 3;
  const int tr0 = rbase + lr4;
  const int tr1 = rbase + 16 + lr4;
  int gra0 = row0 + tr0; if (gra0 > M - 1) gra0 = M - 1;
  int gra1 = row0 + tr1; if (gra1 > M - 1) gra1 = M - 1;
  const int sca0 = (lc ^ ((tr0 >> 1) & 3)) * 8;
  const int sca1 = (lc ^ ((tr1 >> 1) & 3)) * 8;
  const unsigned short* pa0 = A + (size_t)gra0 * 256 + sca0;
  const unsigned short* pa1 = A + (size_t)gra1 * 256 + sca1;
  const unsigned short* pb0 = Bt + (size_t)tr0 * 256 + sca0;
  const unsigned short* pb1 = Bt + (size_t)tr1 * 256 + sca1;

  f32x4 acc[4][4] = {};

  for (int k0 = 0; k0 < 256; k0 += 32) {
    g2lds16(pa0 + k0, &As[rbase * 32]);
    g2lds16(pa1 + k0, &As[(rbase + 16) * 32]);
    g2lds16(pb0 + k0, &Bs[rbase * 32]);
    g2lds16(pb1 + k0, &Bs[(rbase + 16) * 32]);
    __syncthreads();
    bf16x8 afr[4], bfr[4];
#pragma unroll
    for (int mt = 0; mt < 4; ++mt) {
      int rr = wrow + mt * 16 + lrow;
      afr[mt] = *(const bf16x8*)(&As[rr * 32 + ((quad ^ ((rr >> 1) & 3)) << 3)]);
    }
#pragma unroll
    for (int nt = 0; nt < 4; ++nt) {
      int rr = wcol + nt * 16 + lrow;
      bfr[nt] = *(const bf16x8*)(&Bs[rr * 32 + ((quad ^ ((rr >> 1) & 3)) << 3)]);
    }
#pragma unroll
    for (int mt = 0; mt < 4; ++mt)
#pragma unroll
      for (int nt = 0; nt < 4; ++nt)
        acc[mt][nt] = __builtin_amdgcn_mfma_f32_16x16x32_bf16(afr[mt], bfr[nt], acc[mt][nt], 0, 0, 0);
    __syncthreads();
  }

  float p[4][4];
#pragma unroll
  for (int mt = 0; mt < 4; ++mt)
#pragma unroll
    for (int r = 0; r < 4; ++r) p[mt][r] = 0.f;
#pragma unroll
  for (int nt = 0; nt < 4; ++nt) {
    int gcol = wcol + nt * 16 + lrow;
    float b1v = bg1[gcol];
    float w2v = Wg2[gcol];
#pragma unroll
    for (int mt = 0; mt < 4; ++mt)
#pragma unroll
      for (int r = 0; r < 4; ++r) {
        float v = fmaxf(acc[mt][nt][r] + b1v, 0.f);
        p[mt][r] = fmaf(v, w2v, p[mt][r]);
      }
  }
#pragma unroll
  for (int mt = 0; mt < 4; ++mt)
#pragma unroll
    for (int r = 0; r < 4; ++r) {
      float v = p[mt][r];
      v += __shfl_xor(v, 1);
      v += __shfl_xor(v, 2);
      v += __shfl_xor(v, 4);
      v += __shfl_xor(v, 8);
      if (lrow == 0) gbuf[wrow + mt * 16 + quad * 4 + r][wcol >> 6] = v;
    }
  __syncthreads();
  if (tid < 128) {
    int grow = row0 + tid;
    if (grow < M) gate[grow] = gbuf[tid][0] + gbuf[tid][1] + bg2[0];
  }
}

// ---------------- f32 GEMM for the tiny readout layers ----------------
__global__ __launch_bounds__(256) void gemm_f32(
    const float* __restrict__ A, const float* __restrict__ B,
    const float* __restrict__ bias, float* __restrict__ C,
    int M, int Ncol, int K, int act, float scale)
{
  __shared__ float As[32][68];
  __shared__ float Bs[32][68];
  const int tid = threadIdx.x;
  const int tx = tid & 15, ty = tid >> 4;
  const int col0 = blockIdx.x * 64;
  const int row0 = blockIdx.y * 64;
  float acc[4][4];
#pragma unroll
  for (int i = 0; i < 4; ++i)
#pragma unroll
    for (int j = 0; j < 4; ++j) acc[i][j] = 0.f;

  const int ar = tid >> 3;
  const int ak = (tid & 7) * 4;
  const int bk = tid >> 4;
  const int bc = (tid & 15) * 4;

  for (int k0 = 0; k0 < K; k0 += 32) {
#pragma unroll
    for (int p = 0; p < 2; ++p) {
      int r = ar + p * 32;
      int grow = row0 + r;
      float4 v = make_float4(0.f, 0.f, 0.f, 0.f);
      if (grow < M) v = *(const float4*)(A + (size_t)grow * K + k0 + ak);
      As[ak + 0][r] = v.x; As[ak + 1][r] = v.y; As[ak + 2][r] = v.z; As[ak + 3][r] = v.w;
    }
#pragma unroll
    for (int p = 0; p < 2; ++p) {
      int kk = bk + p * 16;
      float4 v = *(const float4*)(B + (size_t)(k0 + kk) * Ncol + col0 + bc);
      *(float4*)(&Bs[kk][bc]) = v;
    }
    __syncthreads();
#pragma unroll
    for (int kk = 0; kk < 32; ++kk) {
      float4 a = *(const float4*)(&As[kk][ty * 4]);
      float4 b = *(const float4*)(&Bs[kk][tx * 4]);
      float av[4] = {a.x, a.y, a.z, a.w};
      float bv[4] = {b.x, b.y, b.z, b.w};
#pragma unroll
      for (int i = 0; i < 4; ++i)
#pragma unroll
        for (int j = 0; j < 4; ++j) acc[i][j] = fmaf(av[i], bv[j], acc[i][j]);
    }
    __syncthreads();
  }
  float bvals[4] = {0.f, 0.f, 0.f, 0.f};
  if (bias) {
#pragma unroll
    for (int j = 0; j < 4; ++j) bvals[j] = bias[col0 + tx * 4 + j];
  }
#pragma unroll
  for (int i = 0; i < 4; ++i) {
    int r = row0 + ty * 4 + i;
    if (r >= M) continue;
    float4 outv;
    float* o = (float*)&outv;
#pragma unroll
    for (int j = 0; j < 4; ++j) {
      float v = (acc[i][j] + bvals[j]) * scale;
      if (act == 1) v = fmaxf(v, 0.f);
      else if (act == 2) v = (v > 0.f) ? v : (__expf(v) - 1.f);
      o[j] = v;
    }
    *(float4*)(C + (size_t)r * Ncol + col0 + tx * 4) = outv;
  }
}

// ---------------- PASS A: edge-parallel logits (real edges only) ----------------
__global__ __launch_bounds__(256) void logits_kernel(
    const unsigned short* __restrict__ xlr,
    const int* __restrict__ ei, const float* __restrict__ eattr,
    const float* __restrict__ We, const float* __restrict__ att,
    float* __restrict__ logits)
{
  const int lane = threadIdx.x & 63;
  const int wv = threadIdx.x >> 6;
  const int c0 = lane * 4;
  const int head = lane >> 3;

  float4 attf4 = *(const float4*)(att + c0);
  float attf[4] = {attf4.x, attf4.y, attf4.z, attf4.w};
  float wef[10][4];
#pragma unroll
  for (int k = 0; k < 10; ++k) {
    float4 w4 = *(const float4*)(We + k * 256 + c0);
    wef[k][0] = w4.x; wef[k][1] = w4.y; wef[k][2] = w4.z; wef[k][3] = w4.w;
  }

  auto edge_logit = [&](int e) {
    int src = ei[e];
    int tgt = ei[N_EDGES + e];
    const float* eap = eattr + (size_t)e * 10;
    float2 q0 = *(const float2*)(eap + 0);
    float2 q1 = *(const float2*)(eap + 2);
    float2 q2 = *(const float2*)(eap + 4);
    float2 q3 = *(const float2*)(eap + 6);
    float2 q4 = *(const float2*)(eap + 8);
    ushort4 ua = *(const ushort4*)(xlr + (size_t)src * 512 + c0);
    ushort4 ub = *(const ushort4*)(xlr + (size_t)tgt * 512 + 256 + c0);
    float ev[10] = {q0.x, q0.y, q1.x, q1.y, q2.x, q2.y, q3.x, q3.y, q4.x, q4.y};
    float p0 = 0.f, p1 = 0.f, p2 = 0.f, p3 = 0.f;
#pragma unroll
    for (int k = 0; k < 10; ++k) {
      p0 = fmaf(ev[k], wef[k][0], p0);
      p1 = fmaf(ev[k], wef[k][1], p1);
      p2 = fmaf(ev[k], wef[k][2], p2);
      p3 = fmaf(ev[k], wef[k][3], p3);
    }
    float s0 = bf2f(ua.x) + bf2f(ub.x) + p0;
    float s1 = bf2f(ua.y) + bf2f(ub.y) + p1;
    float s2 = bf2f(ua.z) + bf2f(ub.z) + p2;
    float s3 = bf2f(ua.w) + bf2f(ub.w) + p3;
    s0 = (s0 > 0.f) ? s0 : 0.2f * s0;
    s1 = (s1 > 0.f) ? s1 : 0.2f * s1;
    s2 = (s2 > 0.f) ? s2 : 0.2f * s2;
    s3 = (s3 > 0.f) ? s3 : 0.2f * s3;
    float part = s0 * attf[0] + s1 * attf[1] + s2 * attf[2] + s3 * attf[3];
    part += __shfl_xor(part, 1);
    part += __shfl_xor(part, 2);
    part += __shfl_xor(part, 4);
    if ((lane & 7) == 0) logits[(size_t)e * 8 + head] = part;
  };

  const int nw = gridDim.x * 4;
  const int e0 = (blockIdx.x * 4 + wv) * 2;
  for (int e = e0; e < N_EDGES; e += nw * 2) {
    edge_logit(e);
    if (e + 1 < N_EDGES) edge_logit(e + 1);
  }
}

// ---------------- PASS B: node-parallel softmax + aggregate + BN/ELU/residual ----------------
// Register-phase softmax: up to 8 edges' (csr,logit,src) loaded into registers
// with clamped indices (8-wide MLP per dependency level); padding slots get
// w=0 and the self row (no NaN). Rare deg>8 tail falls back to a loop.
__global__ __launch_bounds__(256) void attn_kernel(
    const unsigned short* __restrict__ xlr,
    float* __restrict__ h, unsigned short* __restrict__ hb,
    const int* __restrict__ ei, const float* __restrict__ logits,
    const float* __restrict__ att, const float* __restrict__ bgat,
    const float* __restrict__ ep_self,
    const int* __restrict__ rowptr, const int* __restrict__ csr)
{
  const int lane = threadIdx.x & 63;
  const int wv = threadIdx.x >> 6;
  const int n = blockIdx.x * 4 + wv;
  if (n >= N_NODES) return;
  const int c0 = lane * 4;
  const int head = lane >> 3;

  const int s = rowptr[n], e = rowptr[n + 1];
  const int deg = e - s;

  ushort4 ul = *(const ushort4*)(xlr + (size_t)n * 512 + c0);        // xl[n]
  ushort4 ur = *(const ushort4*)(xlr + (size_t)n * 512 + 256 + c0);  // xr[n]
  float4 hold = *(const float4*)(h + (size_t)n * HIDDEN + c0);
  float4 attf = *(const float4*)(att + c0);
  float4 eps = *(const float4*)(ep_self + c0);

  float xln[4] = {bf2f(ul.x), bf2f(ul.y), bf2f(ul.z), bf2f(ul.w)};

  // self-loop logit
  float lself;
  {
    float s0 = xln[0] + bf2f(ur.x) + eps.x;
    float s1 = xln[1] + bf2f(ur.y) + eps.y;
    float s2 = xln[2] + bf2f(ur.z) + eps.z;
    float s3 = xln[3] + bf2f(ur.w) + eps.w;
    s0 = (s0 > 0.f) ? s0 : 0.2f * s0;
    s1 = (s1 > 0.f) ? s1 : 0.2f * s1;
    s2 = (s2 > 0.f) ? s2 : 0.2f * s2;
    s3 = (s3 > 0.f) ? s3 : 0.2f * s3;
    float part = s0 * attf.x + s1 * attf.y + s2 * attf.z + s3 * attf.w;
    part += __shfl_xor(part, 1);
    part += __shfl_xor(part, 2);
    part += __shfl_xor(part, 4);
    lself = part;
  }

  // phase 1: load up to 8 (csr -> logit, src) into registers; global max
  float lg[8];
  int src[8];
  float m = lself;
  if (deg > 0) {
    const int elast = e - 1;
#pragma unroll
    for (int j = 0; j < 8; ++j) {
      int idx = s + j;
      if (idx > elast) idx = elast;
      int eid = csr[idx];
      lg[j] = logits[(size_t)eid * 8 + head];
      src[j] = ei[eid];
    }
#pragma unroll
    for (int j = 0; j < 8; ++j)
      if (j < deg) m = fmaxf(m, lg[j]);
    for (int idx = s + 8; idx < e; ++idx) {   // rare tail (deg > 8)
      int eid = csr[idx];
      m = fmaxf(m, logits[(size_t)eid * 8 + head]);
    }
  }

  // phase 2: weights, then all gathers in flight, then accumulate
  float w[8];
#pragma unroll
  for (int j = 0; j < 8; ++j)
    w[j] = (j < deg) ? __expf(lg[j] - m) : 0.f;

  ushort4 uu[8];
#pragma unroll
  for (int j = 0; j < 8; ++j) uu[j] = ul;    // padding default: self row (no NaN)
#pragma unroll
  for (int j = 0; j < 8; ++j)
    if (j < deg) uu[j] = *(const ushort4*)(xlr + (size_t)src[j] * 512 + c0);

  float wself = __expf(lself - m);
  float d = wself;
  float a0 = wself * xln[0], a1 = wself * xln[1], a2 = wself * xln[2], a3 = wself * xln[3];
#pragma unroll
  for (int j = 0; j < 8; ++j) {
    d += w[j];
    a0 += w[j] * bf2f(uu[j].x);
    a1 += w[j] * bf2f(uu[j].y);
    a2 += w[j] * bf2f(uu[j].z);
    a3 += w[j] * bf2f(uu[j].w);
  }
  // rare tail (deg > 8)
  for (int idx = s + 8; idx < e; ++idx) {
    int eid = csr[idx];
    float l = logits[(size_t)eid * 8 + head];
    int sn = ei[eid];
    float ww = __expf(l - m);
    ushort4 u = *(const ushort4*)(xlr + (size_t)sn * 512 + c0);
    d += ww;
    a0 += ww * bf2f(u.x);
    a1 += ww * bf2f(u.y);
    a2 += ww * bf2f(u.z);
    a3 += ww * bf2f(u.w);
  }

  float inv = 1.f / (d + 1e-16f);
  float4 bg = *(const float4*)(bgat + c0);
  float ov[4] = {a0 * inv, a1 * inv, a2 * inv, a3 * inv};
  float bgv[4] = {bg.x, bg.y, bg.z, bg.w};
  float hv[4] = {hold.x, hold.y, hold.z, hold.w};
  float4 res;
  float* rp = (float*)&res;
  ushort4 resb;
  unsigned short* rb = (unsigned short*)&resb;
#pragma unroll
  for (int j = 0; j < 4; ++j) {
    float v = (ov[j] + bgv[j]) * BN_S;
    v = (v > 0.f) ? v : (__expf(v) - 1.f);
    float nv = v + hv[j];
    rp[j] = nv;
    rb[j] = f2bf(nv);
  }
  *(float4*)(h + (size_t)n * HIDDEN + c0) = res;
  *(ushort4*)(hb + (size_t)n * HIDDEN + c0) = resb;
}

// ---------------- global attention pooling per graph ----------------
__global__ __launch_bounds__(64) void pool_kernel(
    const float* __restrict__ gate, const float* __restrict__ h,
    const int* __restrict__ brp, float* __restrict__ pooled)
{
  int b = blockIdx.x;
  int lane = threadIdx.x;
  int s = brp[b], e = brp[b + 1];
  float m = -__builtin_inff();
  for (int i = s + lane; i < e; i += 64) m = fmaxf(m, gate[i]);
#pragma unroll
  for (int o = 1; o < 64; o <<= 1) m = fmaxf(m, __shfl_xor(m, o));
  float d = 0.f;
  for (int i = s + lane; i < e; i += 64) d += __expf(gate[i] - m);
#pragma unroll
  for (int o = 1; o < 64; o <<= 1) d += __shfl_xor(d, o);
  float inv = 1.f / (d + 1e-16f);
  int c0 = lane * 4;
  float acc[4] = {0.f, 0.f, 0.f, 0.f};
  for (int i = s; i < e; ++i) {
    float w = __expf(gate[i] - m) * inv;
    float4 hv = *(const float4*)(h + (size_t)i * HIDDEN + c0);
    acc[0] = fmaf(w, hv.x, acc[0]);
    acc[1] = fmaf(w, hv.y, acc[1]);
    acc[2] = fmaf(w, hv.z, acc[2]);
    acc[3] = fmaf(w, hv.w, acc[3]);
  }
  float4 outv = make_float4(acc[0], acc[1], acc[2], acc[3]);
  *(float4*)(pooled + (size_t)b * HIDDEN + c0) = outv;
}

// ---------------- final: out[b] = r3[b,:] . W4 + b4 ----------------
__global__ __launch_bounds__(256) void out_kernel(
    const float* __restrict__ r3, const float* __restrict__ W4,
    const float* __restrict__ b4, float* __restrict__ out)
{
  int lane = threadIdx.x & 63;
  int wv = threadIdx.x >> 6;
  int b = blockIdx.x * 4 + wv;
  if (b >= N_B) return;
  float v = r3[(size_t)b * 64 + lane] * W4[lane];
#pragma unroll
  for (int o = 1; o < 64; o <<= 1) v += __shfl_xor(v, o);
  if (lane == 0) out[b] = v + b4[0];
}

extern "C" void kernel_launch(void* const* d_in, const int* in_sizes, int n_in,
                              void* d_out, int out_size, void* d_ws, size_t ws_size,
                              hipStream_t stream)
{
  const float* x    = (const float*)d_in[0];
  const int* ei     = (const int*)d_in[1];
  const float* ea   = (const float*)d_in[2];
  const int* batch  = (const int*)d_in[3];
  const float* W_in = (const float*)d_in[4];
  const float* b_in = (const float*)d_in[5];
  const float* Wl   = (const float*)d_in[6];
  const float* Wr   = (const float*)d_in[7];
  const float* We   = (const float*)d_in[8];
  const float* att  = (const float*)d_in[9];
  const float* bgat = (const float*)d_in[10];
  const float* Wg1  = (const float*)d_in[11];
  const float* bg1  = (const float*)d_in[12];
  const float* Wg2  = (const float*)d_in[13];
  const float* bg2  = (const float*)d_in[14];
  const float* W1   = (const float*)d_in[15];
  const float* b1   = (const float*)d_in[16];
  const float* W2   = (const float*)d_in[17];
  const float* b2   = (const float*)d_in[18];
  const float* W3   = (const float*)d_in[19];
  const float* b3   = (const float*)d_in[20];
  const float* W4   = (const float*)d_in[21];
  const float* b4   = (const float*)d_in[22];
  float* out = (float*)d_out;

  char* ws = (char*)d_ws;
  size_t off = 0;
  auto alloc = [&](size_t bytes) -> char* {
    char* p = ws + off;
    off += (bytes + 255) & ~(size_t)255;
    return p;
  };
  float* h            = (float*)alloc((size_t)N_NODES * HIDDEN * 4);           // 102.4 MB
  unsigned short* hb  = (unsigned short*)alloc((size_t)N_NODES * HIDDEN * 2);  // 51.2 MB
  unsigned short* xlr = (unsigned short*)alloc((size_t)N_NODES * 512 * 2);     // 102.4 MB
  int* deg       = (int*)alloc((size_t)N_NODES * 4);
  int* rowptr    = (int*)alloc((size_t)(N_NODES + 1) * 4);
  int* cursor    = (int*)alloc((size_t)N_NODES * 4);
  int* csr       = (int*)alloc((size_t)N_EDGES * 4);       // real edges only
  int* brp       = (int*)alloc((size_t)(N_B + 1) * 4);
  int* bsum      = (int*)alloc(512);
  float* macc    = (float*)alloc(64);
  float* meanattr= (float*)alloc(64);
  float* ep_self = (float*)alloc(4 * 256 * 4);
  float* logits  = (float*)alloc((size_t)N_EDGES * 8 * 4); // 7.04 MB
  unsigned short* Wint  = (unsigned short*)alloc(256 * 128 * 2);      // [256][128]
  unsigned short* Wlrt  = (unsigned short*)alloc(4 * 512 * 256 * 2);  // [i][512][256] = Wl^T || Wr^T
  unsigned short* Wg1t  = (unsigned short*)alloc(128 * 256 * 2);      // [128][256]
  // total ≈ 266.3 MB < 268.4 MB ws  ✓

  // aliases into dead regions of xlr:
  unsigned short* xpad = xlr;            // [N,128] bf16, pre-layer0 only (25.6 MB < 102.4)
  float* base2  = (float*)xlr;           // xlr fully dead after last attn layer
  float* gate   = base2;                 // [N] f32
  float* pooled = base2 + 1000000;       // [B,256] f32
  float* r1     = base2 + 3000000;       // [B,256] f32
  float* r2     = base2 + 5000000;       // [B,128] f32
  float* r3     = base2 + 6000000;       // [B,64]  f32

  if (ws_size < off) {
    hipMemsetAsync(d_out, 0, (size_t)out_size * 4, stream);
    return;
  }

  zero_kernel<<<391, 256, 0, stream>>>(deg, cursor, macc);
  mean_kernel<<<64, 256, 0, stream>>>(ea, macc);
  meanattr_kernel<<<1, 64, 0, stream>>>(macc, meanattr);
  epself_kernel<<<4, 256, 0, stream>>>(meanattr, We, ep_self);
  count_kernel<<<860, 256, 0, stream>>>(ei, deg);
  scan1_kernel<<<NSCANB, 1024, 0, stream>>>(deg, rowptr, bsum);
  scan2_kernel<<<1, 128, 0, stream>>>(bsum);
  scan3_kernel<<<NSCANB, 1024, 0, stream>>>(rowptr, bsum);
  scatter_kernel<<<860, 256, 0, stream>>>(ei, rowptr, cursor, csr);
  brp_kernel<<<512, 256, 0, stream>>>(batch, brp);

  // weight conversions (transpose + bf16); Wint padded to K=128
  wt_kernel<<<(256 * 128 + 255) / 256, 256, 0, stream>>>(W_in, Wint, 75, 128, 256);
  wlr_kernel<<<512, 256, 0, stream>>>(Wl, Wr, Wlrt);
  wt_kernel<<<128, 256, 0, stream>>>(Wg1, Wg1t, 256, 256, 128);
  convx_kernel<<<4096, 256, 0, stream>>>(x, xpad);

  // input projection: h = elu((x @ W_in + b_in) * BN_S)  [MFMA, K=128 padded]
  gemm_mfma<<<1564, 256, 0, stream>>>(xpad, Wint, b_in, h, hb,
                                      N_NODES, 256, 128, 2, BN_S, 2);

  for (int i = 0; i < 4; ++i) {
    // fused xl||xr GEMM: [N,256] @ [256,512] -> xlr [N,512]
    gemm_mfma<<<3128, 256, 0, stream>>>(hb, Wlrt + (size_t)i * 131072, nullptr,
                                        nullptr, xlr, N_NODES, 512, 256, 0, 1.f, 4);
    // pass A: edge-parallel logits
    logits_kernel<<<2048, 256, 0, stream>>>(xlr, ei, ea, We + (size_t)i * 2560,
                                            att + (size_t)i * 256, logits);
    // pass B: node-parallel softmax + aggregate
    attn_kernel<<<25000, 256, 0, stream>>>(xlr, h, hb, ei, logits,
                                           att + (size_t)i * 256, bgat + (size_t)i * 256,
                                           ep_self + (size_t)i * 256, rowptr, csr);
  }

  // fused pooling gate: gate = relu(hb @ Wg1 + bg1) . Wg2 + bg2
  gemm_gate<<<782, 256, 0, stream>>>(hb, Wg1t, bg1, Wg2, bg2, gate, N_NODES);
  pool_kernel<<<N_B, 64, 0, stream>>>(gate, h, brp, pooled);

  // readout MLP (f32, tiny)
  gemm_f32<<<dim3(4, 64), 256, 0, stream>>>(pooled, W1, b1, r1, N_B, 256, 256, 1, BN_S);
  gemm_f32<<<dim3(2, 64), 256, 0, stream>>>(r1, W2, b2, r2, N_B, 128, 256, 1, BN_S);
  gemm_f32<<<dim3(1, 64), 256, 0, stream>>>(r2, W3, b3, r3, N_B, 64, 128, 1, 1.f);
  out_kernel<<<1024, 256, 0, stream>>>(r3, W4, b4, out);
}

// Round 11
// 1191.950 us; speedup vs baseline: 1.0141x; 1.0141x over previous
//
#include <hip/hip_runtime.h>

#define N_NODES 100000
#define N_EDGES 220000
#define N_B     4096
#define HIDDEN  256
#define BN_S    0.9999950000374997f
#define NSCANB  98       // ceil(100000/1024)

typedef __attribute__((ext_vector_type(8))) short bf16x8;
typedef __attribute__((ext_vector_type(4))) float f32x4;

__device__ __forceinline__ float bf2f(unsigned short u) {
  return __uint_as_float(((unsigned int)u) << 16);
}
__device__ __forceinline__ unsigned short f2bf(float f) {
  unsigned int x = __float_as_uint(f);
  unsigned int lsb = (x >> 16) & 1u;
  x += 0x7fffu + lsb;
  return (unsigned short)(x >> 16);
}

// async global->LDS 16B: dest is wave-uniform base + lane*16 (linear);
// per-lane GLOBAL address carries the XOR swizzle (m173 pattern).
__device__ __forceinline__ void g2lds16(const void* g, void* l) {
  __builtin_amdgcn_global_load_lds(
      (const __attribute__((address_space(1))) unsigned int*)g,
      (__attribute__((address_space(3))) unsigned int*)l, 16, 0, 0);
}

// bijective XCD swizzle (m204)
__device__ __forceinline__ int xcd_swz(int b, int nwg) {
  int q = nwg >> 3, r = nwg & 7;
  int xcd = b & 7, idx = b >> 3;
  int base = (xcd < r) ? xcd * (q + 1) : r * (q + 1) + (xcd - r) * q;
  return base + idx;
}

// ---------------- zero-init of counters ----------------
__global__ void zero_kernel(int* __restrict__ deg, int* __restrict__ cursor, float* __restrict__ macc) {
  int i = blockIdx.x * blockDim.x + threadIdx.x;
  if (i < N_NODES) { deg[i] = 0; cursor[i] = 0; }
  if (i < 16) macc[i] = 0.f;
}

// ---------------- mean of edge_attr (block-reduced, 1 atomic/k/block) ----------------
__global__ __launch_bounds__(256) void mean_kernel(const float* __restrict__ ea, float* __restrict__ macc) {
  __shared__ float sred[4][16];
  int lane = threadIdx.x & 63;
  int wv = threadIdx.x >> 6;
  float loc[10];
#pragma unroll
  for (int k = 0; k < 10; ++k) loc[k] = 0.f;
  for (int e = blockIdx.x * blockDim.x + threadIdx.x; e < N_EDGES; e += gridDim.x * blockDim.x) {
    const float* p = ea + (size_t)e * 10;
#pragma unroll
    for (int k = 0; k < 10; ++k) loc[k] += p[k];
  }
#pragma unroll
  for (int k = 0; k < 10; ++k) {
    float v = loc[k];
#pragma unroll
    for (int o = 1; o < 64; o <<= 1) v += __shfl_xor(v, o);
    if (lane == 0) sred[wv][k] = v;
  }
  __syncthreads();
  if (threadIdx.x < 10) {
    float s = sred[0][threadIdx.x] + sred[1][threadIdx.x] +
              sred[2][threadIdx.x] + sred[3][threadIdx.x];
    atomicAdd(&macc[threadIdx.x], s);
  }
}

__global__ void meanattr_kernel(const float* __restrict__ macc, float* __restrict__ meanattr) {
  int t = threadIdx.x;
  const float invE = 1.f / (float)N_EDGES;
  if (t < 10) meanattr[t] = macc[t] * invE;
}

// ---------------- ep_self[i][c] = meanattr . We[i][:,c] ----------------
__global__ void epself_kernel(const float* __restrict__ meanattr, const float* __restrict__ We,
                              float* __restrict__ ep_self) {
  int i = blockIdx.x;
  int c = threadIdx.x;
  float s = 0.f;
#pragma unroll
  for (int k = 0; k < 10; ++k)
    s += meanattr[k] * We[(size_t)i * 2560 + k * 256 + c];
  ep_self[i * 256 + c] = s;
}

// ---------------- CSR build (REAL edges only) ----------------
__global__ void count_kernel(const int* __restrict__ ei, int* __restrict__ deg) {
  for (int e = blockIdx.x * blockDim.x + threadIdx.x; e < N_EDGES; e += gridDim.x * blockDim.x) {
    atomicAdd(&deg[ei[N_EDGES + e]], 1);
  }
}

// ---------------- 3-phase scan ----------------
__global__ __launch_bounds__(1024) void scan1_kernel(const int* __restrict__ deg,
                                                     int* __restrict__ rowptr,
                                                     int* __restrict__ bsum) {
  __shared__ int buf[1024];
  int t = threadIdx.x;
  int i = blockIdx.x * 1024 + t;
  int v = (i < N_NODES) ? deg[i] : 0;
  buf[t] = v;
  __syncthreads();
  for (int off = 1; off < 1024; off <<= 1) {
    int add = (t >= off) ? buf[t - off] : 0;
    __syncthreads();
    buf[t] += add;
    __syncthreads();
  }
  if (i < N_NODES) rowptr[i + 1] = buf[t];
  if (t == 1023) bsum[blockIdx.x] = buf[t];
  if (i == 0) rowptr[0] = 0;
}

__global__ __launch_bounds__(128) void scan2_kernel(int* __restrict__ bsum) {
  __shared__ int buf[128];
  int t = threadIdx.x;
  int v = (t < NSCANB) ? bsum[t] : 0;
  buf[t] = v;
  __syncthreads();
  for (int off = 1; off < 128; off <<= 1) {
    int add = (t >= off) ? buf[t - off] : 0;
    __syncthreads();
    buf[t] += add;
    __syncthreads();
  }
  if (t < NSCANB) bsum[t] = buf[t];
}

__global__ __launch_bounds__(1024) void scan3_kernel(int* __restrict__ rowptr,
                                                     const int* __restrict__ bsum) {
  int b = blockIdx.x;
  if (b == 0) return;
  int i = b * 1024 + threadIdx.x;
  if (i < N_NODES) rowptr[i + 1] += bsum[b - 1];
}

__global__ void scatter_kernel(const int* __restrict__ ei, const int* __restrict__ rowptr,
                               int* __restrict__ cursor, int* __restrict__ csr) {
  for (int e = blockIdx.x * blockDim.x + threadIdx.x; e < N_EDGES; e += gridDim.x * blockDim.x) {
    int t = ei[N_EDGES + e];
    int pos = atomicAdd(&cursor[t], 1);
    csr[rowptr[t] + pos] = e;
  }
}

__global__ void brp_kernel(const int* __restrict__ batch, int* __restrict__ brp) {
  for (int i = blockIdx.x * blockDim.x + threadIdx.x; i < N_NODES; i += gridDim.x * blockDim.x) {
    int bi = batch[i];
    int bp = (i == 0) ? -1 : batch[i - 1];
    for (int b = bp + 1; b <= bi; ++b) brp[b] = i;
    if (i == N_NODES - 1) {
      for (int b = bi + 1; b <= N_B; ++b) brp[b] = N_NODES;
    }
  }
}

// ---------------- x -> padded bf16 [N,128] (K pad for BK=64 GEMM) ----------------
__global__ void convx_kernel(const float* __restrict__ x, unsigned short* __restrict__ xp) {
  int total = N_NODES * 128;
  for (int idx = blockIdx.x * blockDim.x + threadIdx.x; idx < total; idx += gridDim.x * blockDim.x) {
    int nn = idx >> 7;
    int j = idx & 127;
    unsigned short v = 0;
    if (j < 75) v = f2bf(x[(size_t)nn * 75 + j]);
    xp[idx] = v;
  }
}

// ---------------- weight transpose+bf16 ----------------
__global__ void wt_kernel(const float* __restrict__ src, unsigned short* __restrict__ dst,
                          int K, int Kp, int N) {
  int idx = blockIdx.x * blockDim.x + threadIdx.x;
  int total = N * Kp;
  if (idx >= total) return;
  int n = idx / Kp, k = idx - n * Kp;
  dst[idx] = (k < K) ? f2bf(src[(size_t)k * N + n]) : (unsigned short)0;
}

// ---------------- all 4 layers Wl^T||Wr^T in one launch ----------------
__global__ void wlr_kernel(const float* __restrict__ Wl, const float* __restrict__ Wr,
                           unsigned short* __restrict__ dst) {
  const int total = 4 * 512 * 256;
  for (int idx = blockIdx.x * blockDim.x + threadIdx.x; idx < total; idx += gridDim.x * blockDim.x) {
    int i = idx >> 17;          // /131072
    int rem = idx & 131071;
    int n = rem >> 8;           // 0..511
    int k = rem & 255;
    float v = (n < 256) ? Wl[(size_t)i * 65536 + k * 256 + n]
                        : Wr[(size_t)i * 65536 + k * 256 + (n - 256)];
    dst[idx] = f2bf(v);
  }
}

// ---------------- bf16 MFMA GEMM, BK=64 staging + LDS-staged C-write ----------------
// K-step 64 (32 MFMA per barrier pair). LDS rows are 64 elems with XOR swizzle
// slot^=(row&7) applied on BOTH the pre-swizzled per-lane global source (g2lds
// dest linear) and the ds_read address. Requires K % 64 == 0.
__global__ __launch_bounds__(256) void gemm_mfma(
    const unsigned short* __restrict__ A, const unsigned short* __restrict__ Bt,
    const float* __restrict__ bias, float* __restrict__ Cf, unsigned short* __restrict__ Cb,
    int M, int Ncol, int K, int act, float scale, int gx)
{
  __shared__ unsigned short smem[16384];   // 32KB: As[128*64]+Bs[128*64]; C-stage reuses
  unsigned short* As = smem;
  unsigned short* Bs = smem + 8192;
  const int tid = threadIdx.x;
  const int wave = tid >> 6;
  const int lane = tid & 63;

  const int wg = xcd_swz(blockIdx.x, gridDim.x);
  const int col0 = (wg % gx) * 128;
  const int row0 = (wg / gx) * 128;

  const int wrow = (wave >> 1) * 64;
  const int wcol = (wave & 1) * 64;
  const int lrow = lane & 15;
  const int quad = lane >> 4;

  // staging: wave stages tile rows [32*wave, 32*wave+32); each g2lds = 8 rows.
  const int rbase = wave * 32;
  const int lr8 = lane >> 3;               // 0..7: row within 8-row group
  const int slot = lane & 7;               // 16B slot within 64-elem row
  const int sw = ((slot ^ lr8) << 3);      // pre-swizzled source elem offset (row&7 == lr8)
  const unsigned short* pa[4];
  const unsigned short* pb[4];
#pragma unroll
  for (int j = 0; j < 4; ++j) {
    int tr = rbase + j * 8 + lr8;
    int gra = row0 + tr; if (gra > M - 1) gra = M - 1;  // clamp: rows >= M discarded in epilogue
    pa[j] = A + (size_t)gra * K + sw;
    pb[j] = Bt + (size_t)(col0 + tr) * K + sw;
  }

  f32x4 acc[4][4] = {};

  for (int k0 = 0; k0 < K; k0 += 64) {
#pragma unroll
    for (int j = 0; j < 4; ++j)
      g2lds16(pa[j] + k0, &As[(rbase + j * 8) * 64]);
#pragma unroll
    for (int j = 0; j < 4; ++j)
      g2lds16(pb[j] + k0, &Bs[(rbase + j * 8) * 64]);
    __syncthreads();   // drains vmcnt (global_load_lds) before LDS reads
#pragma unroll
    for (int kk = 0; kk < 2; ++kk) {
      bf16x8 afr[4], bfr[4];
#pragma unroll
      for (int mt = 0; mt < 4; ++mt) {
        int rr = wrow + mt * 16 + lrow;
        afr[mt] = *(const bf16x8*)(&As[rr * 64 + ((((kk << 2) + quad) ^ (rr & 7)) << 3)]);
      }
#pragma unroll
      for (int nt = 0; nt < 4; ++nt) {
        int rr = wcol + nt * 16 + lrow;
        bfr[nt] = *(const bf16x8*)(&Bs[rr * 64 + ((((kk << 2) + quad) ^ (rr & 7)) << 3)]);
      }
#pragma unroll
      for (int mt = 0; mt < 4; ++mt)
#pragma unroll
        for (int nt = 0; nt < 4; ++nt)
          acc[mt][nt] = __builtin_amdgcn_mfma_f32_16x16x32_bf16(afr[mt], bfr[nt], acc[mt][nt], 0, 0, 0);
    }
    __syncthreads();
  }

  // ---- epilogue: two 64-row passes through LDS, coalesced 16B bf16 stores ----
#pragma unroll
  for (int p = 0; p < 2; ++p) {
#pragma unroll
    for (int mtl = 0; mtl < 2; ++mtl) {
      int mt = 2 * p + mtl;
#pragma unroll
      for (int nt = 0; nt < 4; ++nt) {
        int lcol = wcol + nt * 16 + lrow;
        float bv = bias ? bias[col0 + lcol] : 0.f;
#pragma unroll
        for (int r = 0; r < 4; ++r) {
          float v = (acc[mt][nt][r] + bv) * scale;
          if (act == 1) v = fmaxf(v, 0.f);
          else if (act == 2) v = (v > 0.f) ? v : (__expf(v) - 1.f);
          int srow = (wave >> 1) * 32 + mtl * 16 + quad * 4 + r;
          smem[srow * 136 + lcol] = f2bf(v);
          if (Cf) {
            int grow = row0 + wrow + mt * 16 + quad * 4 + r;
            if (grow < M) Cf[(size_t)grow * Ncol + col0 + lcol] = v;
          }
        }
      }
    }
    __syncthreads();
    if (Cb) {
#pragma unroll
      for (int round = 0; round < 4; ++round) {
        int s_r = round * 16 + (tid >> 4);
        int ce = (tid & 15) * 8;
        int w2 = s_r >> 5, mtl = (s_r >> 4) & 1, rr = s_r & 15;
        int grow = row0 + w2 * 64 + (2 * p + mtl) * 16 + rr;
        if (grow < M) {
          uint4 v = *(const uint4*)(&smem[s_r * 136 + ce]);
          *(uint4*)(Cb + (size_t)grow * Ncol + col0 + ce) = v;
        }
      }
    }
    __syncthreads();
  }
}

// ---------------- fused pooling-gate GEMM (single-buffer BK=32 staging, K=256) ----------------
__global__ __launch_bounds__(256) void gemm_gate(
    const unsigned short* __restrict__ A, const unsigned short* __restrict__ Bt,
    const float* __restrict__ bg1, const float* __restrict__ Wg2,
    const float* __restrict__ bg2, float* __restrict__ gate, int M)
{
  __shared__ unsigned short As[128 * 32];
  __shared__ unsigned short Bs[128 * 32];
  __shared__ float gbuf[128][2];
  const int tid = threadIdx.x;
  const int wave = tid >> 6;
  const int lane = tid & 63;

  const int wg = xcd_swz(blockIdx.x, gridDim.x);
  const int row0 = wg * 128;

  const int wrow = (wave >> 1) * 64;
  const int wcol = (wave & 1) * 64;
  const int lrow = lane & 15;
  const int quad = lane >> 4;

  const int rbase = wave * 32;
  const int lr4 = lane >> 2;
  const int lc = lane & 3;
  const int tr0 = rbase + lr4;
  const int tr1 = rbase + 16 + lr4;
  int gra0 = row0 + tr0; if (gra0 > M - 1) gra0 = M - 1;
  int gra1 = row0 + tr1; if (gra1 > M - 1) gra1 = M - 1;
  const int sca0 = (lc ^ ((tr0 >> 1) & 3)) * 8;
  const int sca1 = (lc ^ ((tr1 >> 1) & 3)) * 8;
  const unsigned short* pa0 = A + (size_t)gra0 * 256 + sca0;
  const unsigned short* pa1 = A + (size_t)gra1 * 256 + sca1;
  const unsigned short* pb0 = Bt + (size_t)tr0 * 256 + sca0;
  const unsigned short* pb1 = Bt + (size_t)tr1 * 256 + sca1;

  f32x4 acc[4][4] = {};

  for (int k0 = 0; k0 < 256; k0 += 32) {
    g2lds16(pa0 + k0, &As[rbase * 32]);
    g2lds16(pa1 + k0, &As[(rbase + 16) * 32]);
    g2lds16(pb0 + k0, &Bs[rbase * 32]);
    g2lds16(pb1 + k0, &Bs[(rbase + 16) * 32]);
    __syncthreads();
    bf16x8 afr[4], bfr[4];
#pragma unroll
    for (int mt = 0; mt < 4; ++mt) {
      int rr = wrow + mt * 16 + lrow;
      afr[mt] = *(const bf16x8*)(&As[rr * 32 + ((quad ^ ((rr >> 1) & 3)) << 3)]);
    }
#pragma unroll
    for (int nt = 0; nt < 4; ++nt) {
      int rr = wcol + nt * 16 + lrow;
      bfr[nt] = *(const bf16x8*)(&Bs[rr * 32 + ((quad ^ ((rr >> 1) & 3)) << 3)]);
    }
#pragma unroll
    for (int mt = 0; mt < 4; ++mt)
#pragma unroll
      for (int nt = 0; nt < 4; ++nt)
        acc[mt][nt] = __builtin_amdgcn_mfma_f32_16x16x32_bf16(afr[mt], bfr[nt], acc[mt][nt], 0, 0, 0);
    __syncthreads();
  }

  float p[4][4];
#pragma unroll
  for (int mt = 0; mt < 4; ++mt)
#pragma unroll
    for (int r = 0; r < 4; ++r) p[mt][r] = 0.f;
#pragma unroll
  for (int nt = 0; nt < 4; ++nt) {
    int gcol = wcol + nt * 16 + lrow;
    float b1v = bg1[gcol];
    float w2v = Wg2[gcol];
#pragma unroll
    for (int mt = 0; mt < 4; ++mt)
#pragma unroll
      for (int r = 0; r < 4; ++r) {
        float v = fmaxf(acc[mt][nt][r] + b1v, 0.f);
        p[mt][r] = fmaf(v, w2v, p[mt][r]);
      }
  }
#pragma unroll
  for (int mt = 0; mt < 4; ++mt)
#pragma unroll
    for (int r = 0; r < 4; ++r) {
      float v = p[mt][r];
      v += __shfl_xor(v, 1);
      v += __shfl_xor(v, 2);
      v += __shfl_xor(v, 4);
      v += __shfl_xor(v, 8);
      if (lrow == 0) gbuf[wrow + mt * 16 + quad * 4 + r][wcol >> 6] = v;
    }
  __syncthreads();
  if (tid < 128) {
    int grow = row0 + tid;
    if (grow < M) gate[grow] = gbuf[tid][0] + gbuf[tid][1] + bg2[0];
  }
}

// ---------------- f32 GEMM for the tiny readout layers ----------------
__global__ __launch_bounds__(256) void gemm_f32(
    const float* __restrict__ A, const float* __restrict__ B,
    const float* __restrict__ bias, float* __restrict__ C,
    int M, int Ncol, int K, int act, float scale)
{
  __shared__ float As[32][68];
  __shared__ float Bs[32][68];
  const int tid = threadIdx.x;
  const int tx = tid & 15, ty = tid >> 4;
  const int col0 = blockIdx.x * 64;
  const int row0 = blockIdx.y * 64;
  float acc[4][4];
#pragma unroll
  for (int i = 0; i < 4; ++i)
#pragma unroll
    for (int j = 0; j < 4; ++j) acc[i][j] = 0.f;

  const int ar = tid >> 3;
  const int ak = (tid & 7) * 4;
  const int bk = tid >> 4;
  const int bc = (tid & 15) * 4;

  for (int k0 = 0; k0 < K; k0 += 32) {
#pragma unroll
    for (int p = 0; p < 2; ++p) {
      int r = ar + p * 32;
      int grow = row0 + r;
      float4 v = make_float4(0.f, 0.f, 0.f, 0.f);
      if (grow < M) v = *(const float4*)(A + (size_t)grow * K + k0 + ak);
      As[ak + 0][r] = v.x; As[ak + 1][r] = v.y; As[ak + 2][r] = v.z; As[ak + 3][r] = v.w;
    }
#pragma unroll
    for (int p = 0; p < 2; ++p) {
      int kk = bk + p * 16;
      float4 v = *(const float4*)(B + (size_t)(k0 + kk) * Ncol + col0 + bc);
      *(float4*)(&Bs[kk][bc]) = v;
    }
    __syncthreads();
#pragma unroll
    for (int kk = 0; kk < 32; ++kk) {
      float4 a = *(const float4*)(&As[kk][ty * 4]);
      float4 b = *(const float4*)(&Bs[kk][tx * 4]);
      float av[4] = {a.x, a.y, a.z, a.w};
      float bv[4] = {b.x, b.y, b.z, b.w};
#pragma unroll
      for (int i = 0; i < 4; ++i)
#pragma unroll
        for (int j = 0; j < 4; ++j) acc[i][j] = fmaf(av[i], bv[j], acc[i][j]);
    }
    __syncthreads();
  }
  float bvals[4] = {0.f, 0.f, 0.f, 0.f};
  if (bias) {
#pragma unroll
    for (int j = 0; j < 4; ++j) bvals[j] = bias[col0 + tx * 4 + j];
  }
#pragma unroll
  for (int i = 0; i < 4; ++i) {
    int r = row0 + ty * 4 + i;
    if (r >= M) continue;
    float4 outv;
    float* o = (float*)&outv;
#pragma unroll
    for (int j = 0; j < 4; ++j) {
      float v = (acc[i][j] + bvals[j]) * scale;
      if (act == 1) v = fmaxf(v, 0.f);
      else if (act == 2) v = (v > 0.f) ? v : (__expf(v) - 1.f);
      o[j] = v;
    }
    *(float4*)(C + (size_t)r * Ncol + col0 + tx * 4) = outv;
  }
}

// ---------------- PASS A: edge-parallel logits (real edges only) ----------------
__global__ __launch_bounds__(256) void logits_kernel(
    const unsigned short* __restrict__ xlr,
    const int* __restrict__ ei, const float* __restrict__ eattr,
    const float* __restrict__ We, const float* __restrict__ att,
    float* __restrict__ logits)
{
  const int lane = threadIdx.x & 63;
  const int wv = threadIdx.x >> 6;
  const int c0 = lane * 4;
  const int head = lane >> 3;

  float4 attf4 = *(const float4*)(att + c0);
  float attf[4] = {attf4.x, attf4.y, attf4.z, attf4.w};
  float wef[10][4];
#pragma unroll
  for (int k = 0; k < 10; ++k) {
    float4 w4 = *(const float4*)(We + k * 256 + c0);
    wef[k][0] = w4.x; wef[k][1] = w4.y; wef[k][2] = w4.z; wef[k][3] = w4.w;
  }

  auto edge_logit = [&](int e) {
    int src = ei[e];
    int tgt = ei[N_EDGES + e];
    const float* eap = eattr + (size_t)e * 10;
    float2 q0 = *(const float2*)(eap + 0);
    float2 q1 = *(const float2*)(eap + 2);
    float2 q2 = *(const float2*)(eap + 4);
    float2 q3 = *(const float2*)(eap + 6);
    float2 q4 = *(const float2*)(eap + 8);
    ushort4 ua = *(const ushort4*)(xlr + (size_t)src * 512 + c0);
    ushort4 ub = *(const ushort4*)(xlr + (size_t)tgt * 512 + 256 + c0);
    float ev[10] = {q0.x, q0.y, q1.x, q1.y, q2.x, q2.y, q3.x, q3.y, q4.x, q4.y};
    float p0 = 0.f, p1 = 0.f, p2 = 0.f, p3 = 0.f;
#pragma unroll
    for (int k = 0; k < 10; ++k) {
      p0 = fmaf(ev[k], wef[k][0], p0);
      p1 = fmaf(ev[k], wef[k][1], p1);
      p2 = fmaf(ev[k], wef[k][2], p2);
      p3 = fmaf(ev[k], wef[k][3], p3);
    }
    float s0 = bf2f(ua.x) + bf2f(ub.x) + p0;
    float s1 = bf2f(ua.y) + bf2f(ub.y) + p1;
    float s2 = bf2f(ua.z) + bf2f(ub.z) + p2;
    float s3 = bf2f(ua.w) + bf2f(ub.w) + p3;
    s0 = (s0 > 0.f) ? s0 : 0.2f * s0;
    s1 = (s1 > 0.f) ? s1 : 0.2f * s1;
    s2 = (s2 > 0.f) ? s2 : 0.2f * s2;
    s3 = (s3 > 0.f) ? s3 : 0.2f * s3;
    float part = s0 * attf[0] + s1 * attf[1] + s2 * attf[2] + s3 * attf[3];
    part += __shfl_xor(part, 1);
    part += __shfl_xor(part, 2);
    part += __shfl_xor(part, 4);
    if ((lane & 7) == 0) logits[(size_t)e * 8 + head] = part;
  };

  const int nw = gridDim.x * 4;
  const int e0 = (blockIdx.x * 4 + wv) * 2;
  for (int e = e0; e < N_EDGES; e += nw * 2) {
    edge_logit(e);
    if (e + 1 < N_EDGES) edge_logit(e + 1);
  }
}

// ---------------- PASS B: node-parallel softmax + aggregate + BN/ELU/residual ----------------
// Register-phase softmax with wave-uniform degree specialization:
// deg<=4 (93% of nodes, Poisson(2.2)) uses a 4-slot phase (half the addr math,
// exps, gathers); deg 5..8 uses the 8-slot phase; deg>8 loops. All indices are
// 32-bit (fits: E*8 and N*512 < 2^31). Padding slots: w=0, self row (no NaN).
__global__ __launch_bounds__(256) void attn_kernel(
    const unsigned short* __restrict__ xlr,
    float* __restrict__ h, unsigned short* __restrict__ hb,
    const int* __restrict__ ei, const float* __restrict__ logits,
    const float* __restrict__ att, const float* __restrict__ bgat,
    const float* __restrict__ ep_self,
    const int* __restrict__ rowptr, const int* __restrict__ csr)
{
  const int lane = threadIdx.x & 63;
  const int wv = threadIdx.x >> 6;
  const int n = blockIdx.x * 4 + wv;
  if (n >= N_NODES) return;
  const int c0 = lane * 4;
  const int head = lane >> 3;

  const int s = rowptr[n], e = rowptr[n + 1];
  const int deg = e - s;

  ushort4 ul = *(const ushort4*)(xlr + n * 512 + c0);        // xl[n]
  ushort4 ur = *(const ushort4*)(xlr + n * 512 + 256 + c0);  // xr[n]
  float4 hold = *(const float4*)(h + n * HIDDEN + c0);
  float4 attf = *(const float4*)(att + c0);
  float4 eps = *(const float4*)(ep_self + c0);

  float xln[4] = {bf2f(ul.x), bf2f(ul.y), bf2f(ul.z), bf2f(ul.w)};

  // self-loop logit
  float lself;
  {
    float s0 = xln[0] + bf2f(ur.x) + eps.x;
    float s1 = xln[1] + bf2f(ur.y) + eps.y;
    float s2 = xln[2] + bf2f(ur.z) + eps.z;
    float s3 = xln[3] + bf2f(ur.w) + eps.w;
    s0 = (s0 > 0.f) ? s0 : 0.2f * s0;
    s1 = (s1 > 0.f) ? s1 : 0.2f * s1;
    s2 = (s2 > 0.f) ? s2 : 0.2f * s2;
    s3 = (s3 > 0.f) ? s3 : 0.2f * s3;
    float part = s0 * attf.x + s1 * attf.y + s2 * attf.z + s3 * attf.w;
    part += __shfl_xor(part, 1);
    part += __shfl_xor(part, 2);
    part += __shfl_xor(part, 4);
    lself = part;
  }

  float m = lself;
  float d, a0, a1, a2, a3;

  if (deg <= 4) {
    // ---- 4-slot fast path (93% of nodes; wave-uniform branch) ----
    float lg[4];
    int src[4];
    if (deg > 0) {
      const int elast = e - 1;
      int eid[4];
#pragma unroll
      for (int j = 0; j < 4; ++j) {
        int idx = s + j; if (idx > elast) idx = elast;
        eid[j] = csr[idx];
      }
#pragma unroll
      for (int j = 0; j < 4; ++j) {
        lg[j] = logits[eid[j] * 8 + head];
        src[j] = ei[eid[j]];
      }
#pragma unroll
      for (int j = 0; j < 4; ++j)
        if (j < deg) m = fmaxf(m, lg[j]);
    }
    float w[4];
#pragma unroll
    for (int j = 0; j < 4; ++j)
      w[j] = (j < deg) ? __expf(lg[j] - m) : 0.f;
    ushort4 uu[4];
#pragma unroll
    for (int j = 0; j < 4; ++j) uu[j] = ul;
#pragma unroll
    for (int j = 0; j < 4; ++j)
      if (j < deg) uu[j] = *(const ushort4*)(xlr + src[j] * 512 + c0);
    float wself = __expf(lself - m);
    d = wself;
    a0 = wself * xln[0]; a1 = wself * xln[1]; a2 = wself * xln[2]; a3 = wself * xln[3];
#pragma unroll
    for (int j = 0; j < 4; ++j) {
      d += w[j];
      a0 += w[j] * bf2f(uu[j].x);
      a1 += w[j] * bf2f(uu[j].y);
      a2 += w[j] * bf2f(uu[j].z);
      a3 += w[j] * bf2f(uu[j].w);
    }
  } else {
    // ---- 8-slot path + loop tail (deg > 4) ----
    float lg[8];
    int src[8];
    const int elast = e - 1;
    int eid[8];
#pragma unroll
    for (int j = 0; j < 8; ++j) {
      int idx = s + j; if (idx > elast) idx = elast;
      eid[j] = csr[idx];
    }
#pragma unroll
    for (int j = 0; j < 8; ++j) {
      lg[j] = logits[eid[j] * 8 + head];
      src[j] = ei[eid[j]];
    }
#pragma unroll
    for (int j = 0; j < 8; ++j)
      if (j < deg) m = fmaxf(m, lg[j]);
    for (int idx = s + 8; idx < e; ++idx) {   // rare tail (deg > 8)
      int eidt = csr[idx];
      m = fmaxf(m, logits[eidt * 8 + head]);
    }
    float w[8];
#pragma unroll
    for (int j = 0; j < 8; ++j)
      w[j] = (j < deg) ? __expf(lg[j] - m) : 0.f;
    ushort4 uu[8];
#pragma unroll
    for (int j = 0; j < 8; ++j) uu[j] = ul;
#pragma unroll
    for (int j = 0; j < 8; ++j)
      if (j < deg) uu[j] = *(const ushort4*)(xlr + src[j] * 512 + c0);
    float wself = __expf(lself - m);
    d = wself;
    a0 = wself * xln[0]; a1 = wself * xln[1]; a2 = wself * xln[2]; a3 = wself * xln[3];
#pragma unroll
    for (int j = 0; j < 8; ++j) {
      d += w[j];
      a0 += w[j] * bf2f(uu[j].x);
      a1 += w[j] * bf2f(uu[j].y);
      a2 += w[j] * bf2f(uu[j].z);
      a3 += w[j] * bf2f(uu[j].w);
    }
    for (int idx = s + 8; idx < e; ++idx) {   // rare tail (deg > 8)
      int eidt = csr[idx];
      float l = logits[eidt * 8 + head];
      int sn = ei[eidt];
      float ww = __expf(l - m);
      ushort4 u = *(const ushort4*)(xlr + sn * 512 + c0);
      d += ww;
      a0 += ww * bf2f(u.x);
      a1 += ww * bf2f(u.y);
      a2 += ww * bf2f(u.z);
      a3 += ww * bf2f(u.w);
    }
  }

  float inv = 1.f / (d + 1e-16f);
  float4 bg = *(const float4*)(bgat + c0);
  float ov[4] = {a0 * inv, a1 * inv, a2 * inv, a3 * inv};
  float bgv[4] = {bg.x, bg.y, bg.z, bg.w};
  float hv[4] = {hold.x, hold.y, hold.z, hold.w};
  float4 res;
  float* rp = (float*)&res;
  ushort4 resb;
  unsigned short* rb = (unsigned short*)&resb;
#pragma unroll
  for (int j = 0; j < 4; ++j) {
    float v = (ov[j] + bgv[j]) * BN_S;
    v = (v > 0.f) ? v : (__expf(v) - 1.f);
    float nv = v + hv[j];
    rp[j] = nv;
    rb[j] = f2bf(nv);
  }
  *(float4*)(h + n * HIDDEN + c0) = res;
  *(ushort4*)(hb + n * HIDDEN + c0) = resb;
}

// ---------------- global attention pooling per graph ----------------
__global__ __launch_bounds__(64) void pool_kernel(
    const float* __restrict__ gate, const float* __restrict__ h,
    const int* __restrict__ brp, float* __restrict__ pooled)
{
  int b = blockIdx.x;
  int lane = threadIdx.x;
  int s = brp[b], e = brp[b + 1];
  float m = -__builtin_inff();
  for (int i = s + lane; i < e; i += 64) m = fmaxf(m, gate[i]);
#pragma unroll
  for (int o = 1; o < 64; o <<= 1) m = fmaxf(m, __shfl_xor(m, o));
  float d = 0.f;
  for (int i = s + lane; i < e; i += 64) d += __expf(gate[i] - m);
#pragma unroll
  for (int o = 1; o < 64; o <<= 1) d += __shfl_xor(d, o);
  float inv = 1.f / (d + 1e-16f);
  int c0 = lane * 4;
  float acc[4] = {0.f, 0.f, 0.f, 0.f};
  for (int i = s; i < e; ++i) {
    float w = __expf(gate[i] - m) * inv;
    float4 hv = *(const float4*)(h + (size_t)i * HIDDEN + c0);
    acc[0] = fmaf(w, hv.x, acc[0]);
    acc[1] = fmaf(w, hv.y, acc[1]);
    acc[2] = fmaf(w, hv.z, acc[2]);
    acc[3] = fmaf(w, hv.w, acc[3]);
  }
  float4 outv = make_float4(acc[0], acc[1], acc[2], acc[3]);
  *(float4*)(pooled + (size_t)b * HIDDEN + c0) = outv;
}

// ---------------- final: out[b] = r3[b,:] . W4 + b4 ----------------
__global__ __launch_bounds__(256) void out_kernel(
    const float* __restrict__ r3, const float* __restrict__ W4,
    const float* __restrict__ b4, float* __restrict__ out)
{
  int lane = threadIdx.x & 63;
  int wv = threadIdx.x >> 6;
  int b = blockIdx.x * 4 + wv;
  if (b >= N_B) return;
  float v = r3[(size_t)b * 64 + lane] * W4[lane];
#pragma unroll
  for (int o = 1; o < 64; o <<= 1) v += __shfl_xor(v, o);
  if (lane == 0) out[b] = v + b4[0];
}

extern "C" void kernel_launch(void* const* d_in, const int* in_sizes, int n_in,
                              void* d_out, int out_size, void* d_ws, size_t ws_size,
                              hipStream_t stream)
{
  const float* x    = (const float*)d_in[0];
  const int* ei     = (const int*)d_in[1];
  const float* ea   = (const float*)d_in[2];
  const int* batch  = (const int*)d_in[3];
  const float* W_in = (const float*)d_in[4];
  const float* b_in = (const float*)d_in[5];
  const float* Wl   = (const float*)d_in[6];
  const float* Wr   = (const float*)d_in[7];
  const float* We   = (const float*)d_in[8];
  const float* att  = (const float*)d_in[9];
  const float* bgat = (const float*)d_in[10];
  const float* Wg1  = (const float*)d_in[11];
  const float* bg1  = (const float*)d_in[12];
  const float* Wg2  = (const float*)d_in[13];
  const float* bg2  = (const float*)d_in[14];
  const float* W1   = (const float*)d_in[15];
  const float* b1   = (const float*)d_in[16];
  const float* W2   = (const float*)d_in[17];
  const float* b2   = (const float*)d_in[18];
  const float* W3   = (const float*)d_in[19];
  const float* b3   = (const float*)d_in[20];
  const float* W4   = (const float*)d_in[21];
  const float* b4   = (const float*)d_in[22];
  float* out = (float*)d_out;

  char* ws = (char*)d_ws;
  size_t off = 0;
  auto alloc = [&](size_t bytes) -> char* {
    char* p = ws + off;
    off += (bytes + 255) & ~(size_t)255;
    return p;
  };
  float* h            = (float*)alloc((size_t)N_NODES * HIDDEN * 4);           // 102.4 MB
  unsigned short* hb  = (unsigned short*)alloc((size_t)N_NODES * HIDDEN * 2);  // 51.2 MB
  unsigned short* xlr = (unsigned short*)alloc((size_t)N_NODES * 512 * 2);     // 102.4 MB
  int* deg       = (int*)alloc((size_t)N_NODES * 4);
  int* rowptr    = (int*)alloc((size_t)(N_NODES + 1) * 4);
  int* cursor    = (int*)alloc((size_t)N_NODES * 4);
  int* csr       = (int*)alloc((size_t)N_EDGES * 4);       // real edges only
  int* brp       = (int*)alloc((size_t)(N_B + 1) * 4);
  int* bsum      = (int*)alloc(512);
  float* macc    = (float*)alloc(64);
  float* meanattr= (float*)alloc(64);
  float* ep_self = (float*)alloc(4 * 256 * 4);
  float* logits  = (float*)alloc((size_t)N_EDGES * 8 * 4); // 7.04 MB
  unsigned short* Wint  = (unsigned short*)alloc(256 * 128 * 2);      // [256][128]
  unsigned short* Wlrt  = (unsigned short*)alloc(4 * 512 * 256 * 2);  // [i][512][256] = Wl^T || Wr^T
  unsigned short* Wg1t  = (unsigned short*)alloc(128 * 256 * 2);      // [128][256]
  // total ≈ 266.3 MB < 268.4 MB ws  ✓

  // aliases into dead regions of xlr:
  unsigned short* xpad = xlr;            // [N,128] bf16, pre-layer0 only (25.6 MB < 102.4)
  float* base2  = (float*)xlr;           // xlr fully dead after last attn layer
  float* gate   = base2;                 // [N] f32
  float* pooled = base2 + 1000000;       // [B,256] f32
  float* r1     = base2 + 3000000;       // [B,256] f32
  float* r2     = base2 + 5000000;       // [B,128] f32
  float* r3     = base2 + 6000000;       // [B,64]  f32

  if (ws_size < off) {
    hipMemsetAsync(d_out, 0, (size_t)out_size * 4, stream);
    return;
  }

  zero_kernel<<<391, 256, 0, stream>>>(deg, cursor, macc);
  mean_kernel<<<64, 256, 0, stream>>>(ea, macc);
  meanattr_kernel<<<1, 64, 0, stream>>>(macc, meanattr);
  epself_kernel<<<4, 256, 0, stream>>>(meanattr, We, ep_self);
  count_kernel<<<860, 256, 0, stream>>>(ei, deg);
  scan1_kernel<<<NSCANB, 1024, 0, stream>>>(deg, rowptr, bsum);
  scan2_kernel<<<1, 128, 0, stream>>>(bsum);
  scan3_kernel<<<NSCANB, 1024, 0, stream>>>(rowptr, bsum);
  scatter_kernel<<<860, 256, 0, stream>>>(ei, rowptr, cursor, csr);
  brp_kernel<<<512, 256, 0, stream>>>(batch, brp);

  // weight conversions (transpose + bf16); Wint padded to K=128
  wt_kernel<<<(256 * 128 + 255) / 256, 256, 0, stream>>>(W_in, Wint, 75, 128, 256);
  wlr_kernel<<<512, 256, 0, stream>>>(Wl, Wr, Wlrt);
  wt_kernel<<<128, 256, 0, stream>>>(Wg1, Wg1t, 256, 256, 128);
  convx_kernel<<<4096, 256, 0, stream>>>(x, xpad);

  // input projection: h = elu((x @ W_in + b_in) * BN_S)  [MFMA, K=128 padded]
  gemm_mfma<<<1564, 256, 0, stream>>>(xpad, Wint, b_in, h, hb,
                                      N_NODES, 256, 128, 2, BN_S, 2);

  for (int i = 0; i < 4; ++i) {
    // fused xl||xr GEMM: [N,256] @ [256,512] -> xlr [N,512]
    gemm_mfma<<<3128, 256, 0, stream>>>(hb, Wlrt + (size_t)i * 131072, nullptr,
                                        nullptr, xlr, N_NODES, 512, 256, 0, 1.f, 4);
    // pass A: edge-parallel logits
    logits_kernel<<<2048, 256, 0, stream>>>(xlr, ei, ea, We + (size_t)i * 2560,
                                            att + (size_t)i * 256, logits);
    // pass B: node-parallel softmax + aggregate
    attn_kernel<<<25000, 256, 0, stream>>>(xlr, h, hb, ei, logits,
                                           att + (size_t)i * 256, bgat + (size_t)i * 256,
                                           ep_self + (size_t)i * 256, rowptr, csr);
  }

  // fused pooling gate: gate = relu(hb @ Wg1 + bg1) . Wg2 + bg2
  gemm_gate<<<782, 256, 0, stream>>>(hb, Wg1t, bg1, Wg2, bg2, gate, N_NODES);
  pool_kernel<<<N_B, 64, 0, stream>>>(gate, h, brp, pooled);

  // readout MLP (f32, tiny)
  gemm_f32<<<dim3(4, 64), 256, 0, stream>>>(pooled, W1, b1, r1, N_B, 256, 256, 1, BN_S);
  gemm_f32<<<dim3(2, 64), 256, 0, stream>>>(r1, W2, b2, r2, N_B, 128, 256, 1, BN_S);
  gemm_f32<<<dim3(1, 64), 256, 0, stream>>>(r2, W3, b3, r3, N_B, 64, 128, 1, 1.f);
  out_kernel<<<1024, 256, 0, stream>>>(r3, W4, b4, out);
}

// Round 12
// 1139.251 us; speedup vs baseline: 1.0610x; 1.0463x over previous
//
#include <hip/hip_runtime.h>

#define N_NODES 100000
#define N_EDGES 220000
#define N_B     4096
#define HIDDEN  256
#define BN_S    0.9999950000374997f
#define NSCANB  98       // ceil(100000/1024)

typedef __attribute__((ext_vector_type(8))) short bf16x8;
typedef __attribute__((ext_vector_type(4))) float f32x4;

__device__ __forceinline__ float bf2f(unsigned short u) {
  return __uint_as_float(((unsigned int)u) << 16);
}
__device__ __forceinline__ unsigned short f2bf(float f) {
  unsigned int x = __float_as_uint(f);
  unsigned int lsb = (x >> 16) & 1u;
  x += 0x7fffu + lsb;
  return (unsigned short)(x >> 16);
}

// async global->LDS 16B: dest is wave-uniform base + lane*16 (linear);
// per-lane GLOBAL address carries the XOR swizzle (m173 pattern).
__device__ __forceinline__ void g2lds16(const void* g, void* l) {
  __builtin_amdgcn_global_load_lds(
      (const __attribute__((address_space(1))) unsigned int*)g,
      (__attribute__((address_space(3))) unsigned int*)l, 16, 0, 0);
}

// bijective XCD swizzle (m204)
__device__ __forceinline__ int xcd_swz(int b, int nwg) {
  int q = nwg >> 3, r = nwg & 7;
  int xcd = b & 7, idx = b >> 3;
  int base = (xcd < r) ? xcd * (q + 1) : r * (q + 1) + (xcd - r) * q;
  return base + idx;
}

// ---------------- zero-init of counters ----------------
__global__ void zero_kernel(int* __restrict__ deg, int* __restrict__ cursor, float* __restrict__ macc) {
  int i = blockIdx.x * blockDim.x + threadIdx.x;
  if (i < N_NODES) { deg[i] = 0; cursor[i] = 0; }
  if (i < 16) macc[i] = 0.f;
}

// ---------------- mean of edge_attr (block-reduced, 1 atomic/k/block) ----------------
__global__ __launch_bounds__(256) void mean_kernel(const float* __restrict__ ea, float* __restrict__ macc) {
  __shared__ float sred[4][16];
  int lane = threadIdx.x & 63;
  int wv = threadIdx.x >> 6;
  float loc[10];
#pragma unroll
  for (int k = 0; k < 10; ++k) loc[k] = 0.f;
  for (int e = blockIdx.x * blockDim.x + threadIdx.x; e < N_EDGES; e += gridDim.x * blockDim.x) {
    const float* p = ea + (size_t)e * 10;
#pragma unroll
    for (int k = 0; k < 10; ++k) loc[k] += p[k];
  }
#pragma unroll
  for (int k = 0; k < 10; ++k) {
    float v = loc[k];
#pragma unroll
    for (int o = 1; o < 64; o <<= 1) v += __shfl_xor(v, o);
    if (lane == 0) sred[wv][k] = v;
  }
  __syncthreads();
  if (threadIdx.x < 10) {
    float s = sred[0][threadIdx.x] + sred[1][threadIdx.x] +
              sred[2][threadIdx.x] + sred[3][threadIdx.x];
    atomicAdd(&macc[threadIdx.x], s);
  }
}

__global__ void meanattr_kernel(const float* __restrict__ macc, float* __restrict__ meanattr) {
  int t = threadIdx.x;
  const float invE = 1.f / (float)N_EDGES;
  if (t < 10) meanattr[t] = macc[t] * invE;
}

// ---------------- ep_self[i][c] = meanattr . We[i][:,c] ----------------
__global__ void epself_kernel(const float* __restrict__ meanattr, const float* __restrict__ We,
                              float* __restrict__ ep_self) {
  int i = blockIdx.x;
  int c = threadIdx.x;
  float s = 0.f;
#pragma unroll
  for (int k = 0; k < 10; ++k)
    s += meanattr[k] * We[(size_t)i * 2560 + k * 256 + c];
  ep_self[i * 256 + c] = s;
}

// ---------------- CSR build (REAL edges only) ----------------
__global__ void count_kernel(const int* __restrict__ ei, int* __restrict__ deg) {
  for (int e = blockIdx.x * blockDim.x + threadIdx.x; e < N_EDGES; e += gridDim.x * blockDim.x) {
    atomicAdd(&deg[ei[N_EDGES + e]], 1);
  }
}

// ---------------- 3-phase scan ----------------
__global__ __launch_bounds__(1024) void scan1_kernel(const int* __restrict__ deg,
                                                     int* __restrict__ rowptr,
                                                     int* __restrict__ bsum) {
  __shared__ int buf[1024];
  int t = threadIdx.x;
  int i = blockIdx.x * 1024 + t;
  int v = (i < N_NODES) ? deg[i] : 0;
  buf[t] = v;
  __syncthreads();
  for (int off = 1; off < 1024; off <<= 1) {
    int add = (t >= off) ? buf[t - off] : 0;
    __syncthreads();
    buf[t] += add;
    __syncthreads();
  }
  if (i < N_NODES) rowptr[i + 1] = buf[t];
  if (t == 1023) bsum[blockIdx.x] = buf[t];
  if (i == 0) rowptr[0] = 0;
}

__global__ __launch_bounds__(128) void scan2_kernel(int* __restrict__ bsum) {
  __shared__ int buf[128];
  int t = threadIdx.x;
  int v = (t < NSCANB) ? bsum[t] : 0;
  buf[t] = v;
  __syncthreads();
  for (int off = 1; off < 128; off <<= 1) {
    int add = (t >= off) ? buf[t - off] : 0;
    __syncthreads();
    buf[t] += add;
    __syncthreads();
  }
  if (t < NSCANB) bsum[t] = buf[t];
}

__global__ __launch_bounds__(1024) void scan3_kernel(int* __restrict__ rowptr,
                                                     const int* __restrict__ bsum) {
  int b = blockIdx.x;
  if (b == 0) return;
  int i = b * 1024 + threadIdx.x;
  if (i < N_NODES) rowptr[i + 1] += bsum[b - 1];
}

__global__ void scatter_kernel(const int* __restrict__ ei, const int* __restrict__ rowptr,
                               int* __restrict__ cursor, int* __restrict__ csr) {
  for (int e = blockIdx.x * blockDim.x + threadIdx.x; e < N_EDGES; e += gridDim.x * blockDim.x) {
    int t = ei[N_EDGES + e];
    int pos = atomicAdd(&cursor[t], 1);
    csr[rowptr[t] + pos] = e;
  }
}

__global__ void brp_kernel(const int* __restrict__ batch, int* __restrict__ brp) {
  for (int i = blockIdx.x * blockDim.x + threadIdx.x; i < N_NODES; i += gridDim.x * blockDim.x) {
    int bi = batch[i];
    int bp = (i == 0) ? -1 : batch[i - 1];
    for (int b = bp + 1; b <= bi; ++b) brp[b] = i;
    if (i == N_NODES - 1) {
      for (int b = bi + 1; b <= N_B; ++b) brp[b] = N_NODES;
    }
  }
}

// ---------------- x -> padded bf16 [N,128] (K pad for BK=64 GEMM) ----------------
__global__ void convx_kernel(const float* __restrict__ x, unsigned short* __restrict__ xp) {
  int total = N_NODES * 128;
  for (int idx = blockIdx.x * blockDim.x + threadIdx.x; idx < total; idx += gridDim.x * blockDim.x) {
    int nn = idx >> 7;
    int j = idx & 127;
    unsigned short v = 0;
    if (j < 75) v = f2bf(x[(size_t)nn * 75 + j]);
    xp[idx] = v;
  }
}

// ---------------- weight transpose+bf16 ----------------
__global__ void wt_kernel(const float* __restrict__ src, unsigned short* __restrict__ dst,
                          int K, int Kp, int N) {
  int idx = blockIdx.x * blockDim.x + threadIdx.x;
  int total = N * Kp;
  if (idx >= total) return;
  int n = idx / Kp, k = idx - n * Kp;
  dst[idx] = (k < K) ? f2bf(src[(size_t)k * N + n]) : (unsigned short)0;
}

// ---------------- all 4 layers Wl^T||Wr^T in one launch ----------------
__global__ void wlr_kernel(const float* __restrict__ Wl, const float* __restrict__ Wr,
                           unsigned short* __restrict__ dst) {
  const int total = 4 * 512 * 256;
  for (int idx = blockIdx.x * blockDim.x + threadIdx.x; idx < total; idx += gridDim.x * blockDim.x) {
    int i = idx >> 17;          // /131072
    int rem = idx & 131071;
    int n = rem >> 8;           // 0..511
    int k = rem & 255;
    float v = (n < 256) ? Wl[(size_t)i * 65536 + k * 256 + n]
                        : Wr[(size_t)i * 65536 + k * 256 + (n - 256)];
    dst[idx] = f2bf(v);
  }
}

// ---------------- bf16 MFMA GEMM: 128x64 block tile, 64x32 per wave ----------------
// Occupancy-first redesign: acc 32 regs/wave (was 64) -> 4-5 waves/SIMD.
// BK=64 swizzled staging as before (slot^=(row&7) on pre-swizzled global src
// + ds_read addr; g2lds dest linear). Requires K % 64 == 0, Ncol % 64 == 0.
__global__ __launch_bounds__(256) void gemm_mfma(
    const unsigned short* __restrict__ A, const unsigned short* __restrict__ Bt,
    const float* __restrict__ bias, float* __restrict__ Cf, unsigned short* __restrict__ Cb,
    int M, int Ncol, int K, int act, float scale, int gx)
{
  __shared__ unsigned short smem[12288];   // 24KB: As[128*64]=8192, Bs[64*64]=4096; C-stage reuses
  unsigned short* As = smem;
  unsigned short* Bs = smem + 8192;
  const int tid = threadIdx.x;
  const int wave = tid >> 6;
  const int lane = tid & 63;

  const int wg = xcd_swz(blockIdx.x, gridDim.x);
  const int col0 = (wg % gx) * 64;
  const int row0 = (wg / gx) * 128;

  const int wrow = (wave >> 1) * 64;   // 0 or 64
  const int wcol = (wave & 1) * 32;    // 0 or 32
  const int lrow = lane & 15;
  const int quad = lane >> 4;

  // staging: wave stages A rows [32*wave,32*wave+32) (4 g2lds) and
  //          B rows [16*wave,16*wave+16) (2 g2lds); each g2lds = 8 rows.
  const int lr8 = lane >> 3;               // 0..7
  const int slot = lane & 7;               // 16B slot within 64-elem row
  const int sw = ((slot ^ lr8) << 3);      // pre-swizzled source elem offset
  const unsigned short* pa[4];
  const unsigned short* pb[2];
#pragma unroll
  for (int j = 0; j < 4; ++j) {
    int tr = wave * 32 + j * 8 + lr8;
    int gra = row0 + tr; if (gra > M - 1) gra = M - 1;  // clamp: rows >= M discarded in epilogue
    pa[j] = A + (size_t)gra * K + sw;
  }
#pragma unroll
  for (int j = 0; j < 2; ++j) {
    int tr = wave * 16 + j * 8 + lr8;
    pb[j] = Bt + (size_t)(col0 + tr) * K + sw;
  }

  f32x4 acc[4][2] = {};

  for (int k0 = 0; k0 < K; k0 += 64) {
#pragma unroll
    for (int j = 0; j < 4; ++j)
      g2lds16(pa[j] + k0, &As[(wave * 32 + j * 8) * 64]);
#pragma unroll
    for (int j = 0; j < 2; ++j)
      g2lds16(pb[j] + k0, &Bs[(wave * 16 + j * 8) * 64]);
    __syncthreads();   // drains vmcnt (global_load_lds) before LDS reads
#pragma unroll
    for (int kk = 0; kk < 2; ++kk) {
      bf16x8 afr[4], bfr[2];
#pragma unroll
      for (int mt = 0; mt < 4; ++mt) {
        int rr = wrow + mt * 16 + lrow;
        afr[mt] = *(const bf16x8*)(&As[rr * 64 + ((((kk << 2) + quad) ^ (rr & 7)) << 3)]);
      }
#pragma unroll
      for (int nt = 0; nt < 2; ++nt) {
        int rr = wcol + nt * 16 + lrow;
        bfr[nt] = *(const bf16x8*)(&Bs[rr * 64 + ((((kk << 2) + quad) ^ (rr & 7)) << 3)]);
      }
#pragma unroll
      for (int mt = 0; mt < 4; ++mt)
#pragma unroll
        for (int nt = 0; nt < 2; ++nt)
          acc[mt][nt] = __builtin_amdgcn_mfma_f32_16x16x32_bf16(afr[mt], bfr[nt], acc[mt][nt], 0, 0, 0);
    }
    __syncthreads();
  }

  // ---- epilogue: single pass, stage 128x64 bf16 tile (stride 72), coalesced 16B stores ----
#pragma unroll
  for (int mt = 0; mt < 4; ++mt) {
#pragma unroll
    for (int nt = 0; nt < 2; ++nt) {
      int lcol = wcol + nt * 16 + lrow;
      float bv = bias ? bias[col0 + lcol] : 0.f;
#pragma unroll
      for (int r = 0; r < 4; ++r) {
        float v = (acc[mt][nt][r] + bv) * scale;
        if (act == 1) v = fmaxf(v, 0.f);
        else if (act == 2) v = (v > 0.f) ? v : (__expf(v) - 1.f);
        int srow = wrow + mt * 16 + quad * 4 + r;
        smem[srow * 72 + lcol] = f2bf(v);
        if (Cf) {
          int grow = row0 + srow;
          if (grow < M) Cf[(size_t)grow * Ncol + col0 + lcol] = v;
        }
      }
    }
  }
  __syncthreads();
  if (Cb) {
#pragma unroll
    for (int round = 0; round < 4; ++round) {
      int sr = round * 32 + (tid >> 3);
      int ce = (tid & 7) * 8;
      int grow = row0 + sr;
      if (grow < M) {
        uint4 v = *(const uint4*)(&smem[sr * 72 + ce]);
        *(uint4*)(Cb + (size_t)grow * Ncol + col0 + ce) = v;
      }
    }
  }
}

// ---------------- fused pooling-gate GEMM (single-buffer BK=32 staging, K=256) ----------------
__global__ __launch_bounds__(256) void gemm_gate(
    const unsigned short* __restrict__ A, const unsigned short* __restrict__ Bt,
    const float* __restrict__ bg1, const float* __restrict__ Wg2,
    const float* __restrict__ bg2, float* __restrict__ gate, int M)
{
  __shared__ unsigned short As[128 * 32];
  __shared__ unsigned short Bs[128 * 32];
  __shared__ float gbuf[128][2];
  const int tid = threadIdx.x;
  const int wave = tid >> 6;
  const int lane = tid & 63;

  const int wg = xcd_swz(blockIdx.x, gridDim.x);
  const int row0 = wg * 128;

  const int wrow = (wave >> 1) * 64;
  const int wcol = (wave & 1) * 64;
  const int lrow = lane & 15;
  const int quad = lane >> 4;

  const int rbase = wave * 32;
  const int lr4 = lane >> 2;
  const int lc = lane & 3;
  const int tr0 = rbase + lr4;
  const int tr1 = rbase + 16 + lr4;
  int gra0 = row0 + tr0; if (gra0 > M - 1) gra0 = M - 1;
  int gra1 = row0 + tr1; if (gra1 > M - 1) gra1 = M - 1;
  const int sca0 = (lc ^ ((tr0 >> 1) & 3)) * 8;
  const int sca1 = (lc ^ ((tr1 >> 1) & 3)) * 8;
  const unsigned short* pa0 = A + (size_t)gra0 * 256 + sca0;
  const unsigned short* pa1 = A + (size_t)gra1 * 256 + sca1;
  const unsigned short* pb0 = Bt + (size_t)tr0 * 256 + sca0;
  const unsigned short* pb1 = Bt + (size_t)tr1 * 256 + sca1;

  f32x4 acc[4][4] = {};

  for (int k0 = 0; k0 < 256; k0 += 32) {
    g2lds16(pa0 + k0, &As[rbase * 32]);
    g2lds16(pa1 + k0, &As[(rbase + 16) * 32]);
    g2lds16(pb0 + k0, &Bs[rbase * 32]);
    g2lds16(pb1 + k0, &Bs[(rbase + 16) * 32]);
    __syncthreads();
    bf16x8 afr[4], bfr[4];
#pragma unroll
    for (int mt = 0; mt < 4; ++mt) {
      int rr = wrow + mt * 16 + lrow;
      afr[mt] = *(const bf16x8*)(&As[rr * 32 + ((quad ^ ((rr >> 1) & 3)) << 3)]);
    }
#pragma unroll
    for (int nt = 0; nt < 4; ++nt) {
      int rr = wcol + nt * 16 + lrow;
      bfr[nt] = *(const bf16x8*)(&Bs[rr * 32 + ((quad ^ ((rr >> 1) & 3)) << 3)]);
    }
#pragma unroll
    for (int mt = 0; mt < 4; ++mt)
#pragma unroll
      for (int nt = 0; nt < 4; ++nt)
        acc[mt][nt] = __builtin_amdgcn_mfma_f32_16x16x32_bf16(afr[mt], bfr[nt], acc[mt][nt], 0, 0, 0);
    __syncthreads();
  }

  float p[4][4];
#pragma unroll
  for (int mt = 0; mt < 4; ++mt)
#pragma unroll
    for (int r = 0; r < 4; ++r) p[mt][r] = 0.f;
#pragma unroll
  for (int nt = 0; nt < 4; ++nt) {
    int gcol = wcol + nt * 16 + lrow;
    float b1v = bg1[gcol];
    float w2v = Wg2[gcol];
#pragma unroll
    for (int mt = 0; mt < 4; ++mt)
#pragma unroll
      for (int r = 0; r < 4; ++r) {
        float v = fmaxf(acc[mt][nt][r] + b1v, 0.f);
        p[mt][r] = fmaf(v, w2v, p[mt][r]);
      }
  }
#pragma unroll
  for (int mt = 0; mt < 4; ++mt)
#pragma unroll
    for (int r = 0; r < 4; ++r) {
      float v = p[mt][r];
      v += __shfl_xor(v, 1);
      v += __shfl_xor(v, 2);
      v += __shfl_xor(v, 4);
      v += __shfl_xor(v, 8);
      if (lrow == 0) gbuf[wrow + mt * 16 + quad * 4 + r][wcol >> 6] = v;
    }
  __syncthreads();
  if (tid < 128) {
    int grow = row0 + tid;
    if (grow < M) gate[grow] = gbuf[tid][0] + gbuf[tid][1] + bg2[0];
  }
}

// ---------------- f32 GEMM for the tiny readout layers ----------------
__global__ __launch_bounds__(256) void gemm_f32(
    const float* __restrict__ A, const float* __restrict__ B,
    const float* __restrict__ bias, float* __restrict__ C,
    int M, int Ncol, int K, int act, float scale)
{
  __shared__ float As[32][68];
  __shared__ float Bs[32][68];
  const int tid = threadIdx.x;
  const int tx = tid & 15, ty = tid >> 4;
  const int col0 = blockIdx.x * 64;
  const int row0 = blockIdx.y * 64;
  float acc[4][4];
#pragma unroll
  for (int i = 0; i < 4; ++i)
#pragma unroll
    for (int j = 0; j < 4; ++j) acc[i][j] = 0.f;

  const int ar = tid >> 3;
  const int ak = (tid & 7) * 4;
  const int bk = tid >> 4;
  const int bc = (tid & 15) * 4;

  for (int k0 = 0; k0 < K; k0 += 32) {
#pragma unroll
    for (int p = 0; p < 2; ++p) {
      int r = ar + p * 32;
      int grow = row0 + r;
      float4 v = make_float4(0.f, 0.f, 0.f, 0.f);
      if (grow < M) v = *(const float4*)(A + (size_t)grow * K + k0 + ak);
      As[ak + 0][r] = v.x; As[ak + 1][r] = v.y; As[ak + 2][r] = v.z; As[ak + 3][r] = v.w;
    }
#pragma unroll
    for (int p = 0; p < 2; ++p) {
      int kk = bk + p * 16;
      float4 v = *(const float4*)(B + (size_t)(k0 + kk) * Ncol + col0 + bc);
      *(float4*)(&Bs[kk][bc]) = v;
    }
    __syncthreads();
#pragma unroll
    for (int kk = 0; kk < 32; ++kk) {
      float4 a = *(const float4*)(&As[kk][ty * 4]);
      float4 b = *(const float4*)(&Bs[kk][tx * 4]);
      float av[4] = {a.x, a.y, a.z, a.w};
      float bv[4] = {b.x, b.y, b.z, b.w};
#pragma unroll
      for (int i = 0; i < 4; ++i)
#pragma unroll
        for (int j = 0; j < 4; ++j) acc[i][j] = fmaf(av[i], bv[j], acc[i][j]);
    }
    __syncthreads();
  }
  float bvals[4] = {0.f, 0.f, 0.f, 0.f};
  if (bias) {
#pragma unroll
    for (int j = 0; j < 4; ++j) bvals[j] = bias[col0 + tx * 4 + j];
  }
#pragma unroll
  for (int i = 0; i < 4; ++i) {
    int r = row0 + ty * 4 + i;
    if (r >= M) continue;
    float4 outv;
    float* o = (float*)&outv;
#pragma unroll
    for (int j = 0; j < 4; ++j) {
      float v = (acc[i][j] + bvals[j]) * scale;
      if (act == 1) v = fmaxf(v, 0.f);
      else if (act == 2) v = (v > 0.f) ? v : (__expf(v) - 1.f);
      o[j] = v;
    }
    *(float4*)(C + (size_t)r * Ncol + col0 + tx * 4) = outv;
  }
}

// ---------------- PASS A: edge-parallel logits (real edges only) ----------------
__global__ __launch_bounds__(256) void logits_kernel(
    const unsigned short* __restrict__ xlr,
    const int* __restrict__ ei, const float* __restrict__ eattr,
    const float* __restrict__ We, const float* __restrict__ att,
    float* __restrict__ logits)
{
  const int lane = threadIdx.x & 63;
  const int wv = threadIdx.x >> 6;
  const int c0 = lane * 4;
  const int head = lane >> 3;

  float4 attf4 = *(const float4*)(att + c0);
  float attf[4] = {attf4.x, attf4.y, attf4.z, attf4.w};
  float wef[10][4];
#pragma unroll
  for (int k = 0; k < 10; ++k) {
    float4 w4 = *(const float4*)(We + k * 256 + c0);
    wef[k][0] = w4.x; wef[k][1] = w4.y; wef[k][2] = w4.z; wef[k][3] = w4.w;
  }

  auto edge_logit = [&](int e) {
    int src = ei[e];
    int tgt = ei[N_EDGES + e];
    const float* eap = eattr + (size_t)e * 10;
    float2 q0 = *(const float2*)(eap + 0);
    float2 q1 = *(const float2*)(eap + 2);
    float2 q2 = *(const float2*)(eap + 4);
    float2 q3 = *(const float2*)(eap + 6);
    float2 q4 = *(const float2*)(eap + 8);
    ushort4 ua = *(const ushort4*)(xlr + (size_t)src * 512 + c0);
    ushort4 ub = *(const ushort4*)(xlr + (size_t)tgt * 512 + 256 + c0);
    float ev[10] = {q0.x, q0.y, q1.x, q1.y, q2.x, q2.y, q3.x, q3.y, q4.x, q4.y};
    float p0 = 0.f, p1 = 0.f, p2 = 0.f, p3 = 0.f;
#pragma unroll
    for (int k = 0; k < 10; ++k) {
      p0 = fmaf(ev[k], wef[k][0], p0);
      p1 = fmaf(ev[k], wef[k][1], p1);
      p2 = fmaf(ev[k], wef[k][2], p2);
      p3 = fmaf(ev[k], wef[k][3], p3);
    }
    float s0 = bf2f(ua.x) + bf2f(ub.x) + p0;
    float s1 = bf2f(ua.y) + bf2f(ub.y) + p1;
    float s2 = bf2f(ua.z) + bf2f(ub.z) + p2;
    float s3 = bf2f(ua.w) + bf2f(ub.w) + p3;
    s0 = (s0 > 0.f) ? s0 : 0.2f * s0;
    s1 = (s1 > 0.f) ? s1 : 0.2f * s1;
    s2 = (s2 > 0.f) ? s2 : 0.2f * s2;
    s3 = (s3 > 0.f) ? s3 : 0.2f * s3;
    float part = s0 * attf[0] + s1 * attf[1] + s2 * attf[2] + s3 * attf[3];
    part += __shfl_xor(part, 1);
    part += __shfl_xor(part, 2);
    part += __shfl_xor(part, 4);
    if ((lane & 7) == 0) logits[(size_t)e * 8 + head] = part;
  };

  const int nw = gridDim.x * 4;
  const int e0 = (blockIdx.x * 4 + wv) * 2;
  for (int e = e0; e < N_EDGES; e += nw * 2) {
    edge_logit(e);
    if (e + 1 < N_EDGES) edge_logit(e + 1);
  }
}

// ---------------- PASS B: node-parallel softmax + aggregate + BN/ELU/residual ----------------
// Register-phase softmax with wave-uniform degree specialization:
// deg<=4 (93% of nodes, Poisson(2.2)) uses a 4-slot phase; deg 5..8 the 8-slot
// phase; deg>8 loops. 32-bit indices. Padding slots: w=0, self row (no NaN).
__global__ __launch_bounds__(256) void attn_kernel(
    const unsigned short* __restrict__ xlr,
    float* __restrict__ h, unsigned short* __restrict__ hb,
    const int* __restrict__ ei, const float* __restrict__ logits,
    const float* __restrict__ att, const float* __restrict__ bgat,
    const float* __restrict__ ep_self,
    const int* __restrict__ rowptr, const int* __restrict__ csr)
{
  const int lane = threadIdx.x & 63;
  const int wv = threadIdx.x >> 6;
  const int n = blockIdx.x * 4 + wv;
  if (n >= N_NODES) return;
  const int c0 = lane * 4;
  const int head = lane >> 3;

  const int s = rowptr[n], e = rowptr[n + 1];
  const int deg = e - s;

  ushort4 ul = *(const ushort4*)(xlr + n * 512 + c0);        // xl[n]
  ushort4 ur = *(const ushort4*)(xlr + n * 512 + 256 + c0);  // xr[n]
  float4 hold = *(const float4*)(h + n * HIDDEN + c0);
  float4 attf = *(const float4*)(att + c0);
  float4 eps = *(const float4*)(ep_self + c0);

  float xln[4] = {bf2f(ul.x), bf2f(ul.y), bf2f(ul.z), bf2f(ul.w)};

  // self-loop logit
  float lself;
  {
    float s0 = xln[0] + bf2f(ur.x) + eps.x;
    float s1 = xln[1] + bf2f(ur.y) + eps.y;
    float s2 = xln[2] + bf2f(ur.z) + eps.z;
    float s3 = xln[3] + bf2f(ur.w) + eps.w;
    s0 = (s0 > 0.f) ? s0 : 0.2f * s0;
    s1 = (s1 > 0.f) ? s1 : 0.2f * s1;
    s2 = (s2 > 0.f) ? s2 : 0.2f * s2;
    s3 = (s3 > 0.f) ? s3 : 0.2f * s3;
    float part = s0 * attf.x + s1 * attf.y + s2 * attf.z + s3 * attf.w;
    part += __shfl_xor(part, 1);
    part += __shfl_xor(part, 2);
    part += __shfl_xor(part, 4);
    lself = part;
  }

  float m = lself;
  float d, a0, a1, a2, a3;

  if (deg <= 4) {
    // ---- 4-slot fast path (93% of nodes; wave-uniform branch) ----
    float lg[4];
    int src[4];
    if (deg > 0) {
      const int elast = e - 1;
      int eid[4];
#pragma unroll
      for (int j = 0; j < 4; ++j) {
        int idx = s + j; if (idx > elast) idx = elast;
        eid[j] = csr[idx];
      }
#pragma unroll
      for (int j = 0; j < 4; ++j) {
        lg[j] = logits[eid[j] * 8 + head];
        src[j] = ei[eid[j]];
      }
#pragma unroll
      for (int j = 0; j < 4; ++j)
        if (j < deg) m = fmaxf(m, lg[j]);
    }
    float w[4];
#pragma unroll
    for (int j = 0; j < 4; ++j)
      w[j] = (j < deg) ? __expf(lg[j] - m) : 0.f;
    ushort4 uu[4];
#pragma unroll
    for (int j = 0; j < 4; ++j) uu[j] = ul;
#pragma unroll
    for (int j = 0; j < 4; ++j)
      if (j < deg) uu[j] = *(const ushort4*)(xlr + src[j] * 512 + c0);
    float wself = __expf(lself - m);
    d = wself;
    a0 = wself * xln[0]; a1 = wself * xln[1]; a2 = wself * xln[2]; a3 = wself * xln[3];
#pragma unroll
    for (int j = 0; j < 4; ++j) {
      d += w[j];
      a0 += w[j] * bf2f(uu[j].x);
      a1 += w[j] * bf2f(uu[j].y);
      a2 += w[j] * bf2f(uu[j].z);
      a3 += w[j] * bf2f(uu[j].w);
    }
  } else {
    // ---- 8-slot path + loop tail (deg > 4) ----
    float lg[8];
    int src[8];
    const int elast = e - 1;
    int eid[8];
#pragma unroll
    for (int j = 0; j < 8; ++j) {
      int idx = s + j; if (idx > elast) idx = elast;
      eid[j] = csr[idx];
    }
#pragma unroll
    for (int j = 0; j < 8; ++j) {
      lg[j] = logits[eid[j] * 8 + head];
      src[j] = ei[eid[j]];
    }
#pragma unroll
    for (int j = 0; j < 8; ++j)
      if (j < deg) m = fmaxf(m, lg[j]);
    for (int idx = s + 8; idx < e; ++idx) {   // rare tail (deg > 8)
      int eidt = csr[idx];
      m = fmaxf(m, logits[eidt * 8 + head]);
    }
    float w[8];
#pragma unroll
    for (int j = 0; j < 8; ++j)
      w[j] = (j < deg) ? __expf(lg[j] - m) : 0.f;
    ushort4 uu[8];
#pragma unroll
    for (int j = 0; j < 8; ++j) uu[j] = ul;
#pragma unroll
    for (int j = 0; j < 8; ++j)
      if (j < deg) uu[j] = *(const ushort4*)(xlr + src[j] * 512 + c0);
    float wself = __expf(lself - m);
    d = wself;
    a0 = wself * xln[0]; a1 = wself * xln[1]; a2 = wself * xln[2]; a3 = wself * xln[3];
#pragma unroll
    for (int j = 0; j < 8; ++j) {
      d += w[j];
      a0 += w[j] * bf2f(uu[j].x);
      a1 += w[j] * bf2f(uu[j].y);
      a2 += w[j] * bf2f(uu[j].z);
      a3 += w[j] * bf2f(uu[j].w);
    }
    for (int idx = s + 8; idx < e; ++idx) {   // rare tail (deg > 8)
      int eidt = csr[idx];
      float l = logits[eidt * 8 + head];
      int sn = ei[eidt];
      float ww = __expf(l - m);
      ushort4 u = *(const ushort4*)(xlr + sn * 512 + c0);
      d += ww;
      a0 += ww * bf2f(u.x);
      a1 += ww * bf2f(u.y);
      a2 += ww * bf2f(u.z);
      a3 += ww * bf2f(u.w);
    }
  }

  float inv = 1.f / (d + 1e-16f);
  float4 bg = *(const float4*)(bgat + c0);
  float ov[4] = {a0 * inv, a1 * inv, a2 * inv, a3 * inv};
  float bgv[4] = {bg.x, bg.y, bg.z, bg.w};
  float hv[4] = {hold.x, hold.y, hold.z, hold.w};
  float4 res;
  float* rp = (float*)&res;
  ushort4 resb;
  unsigned short* rb = (unsigned short*)&resb;
#pragma unroll
  for (int j = 0; j < 4; ++j) {
    float v = (ov[j] + bgv[j]) * BN_S;
    v = (v > 0.f) ? v : (__expf(v) - 1.f);
    float nv = v + hv[j];
    rp[j] = nv;
    rb[j] = f2bf(nv);
  }
  *(float4*)(h + n * HIDDEN + c0) = res;
  *(ushort4*)(hb + n * HIDDEN + c0) = resb;
}

// ---------------- global attention pooling per graph ----------------
__global__ __launch_bounds__(64) void pool_kernel(
    const float* __restrict__ gate, const float* __restrict__ h,
    const int* __restrict__ brp, float* __restrict__ pooled)
{
  int b = blockIdx.x;
  int lane = threadIdx.x;
  int s = brp[b], e = brp[b + 1];
  float m = -__builtin_inff();
  for (int i = s + lane; i < e; i += 64) m = fmaxf(m, gate[i]);
#pragma unroll
  for (int o = 1; o < 64; o <<= 1) m = fmaxf(m, __shfl_xor(m, o));
  float d = 0.f;
  for (int i = s + lane; i < e; i += 64) d += __expf(gate[i] - m);
#pragma unroll
  for (int o = 1; o < 64; o <<= 1) d += __shfl_xor(d, o);
  float inv = 1.f / (d + 1e-16f);
  int c0 = lane * 4;
  float acc[4] = {0.f, 0.f, 0.f, 0.f};
  for (int i = s; i < e; ++i) {
    float w = __expf(gate[i] - m) * inv;
    float4 hv = *(const float4*)(h + (size_t)i * HIDDEN + c0);
    acc[0] = fmaf(w, hv.x, acc[0]);
    acc[1] = fmaf(w, hv.y, acc[1]);
    acc[2] = fmaf(w, hv.z, acc[2]);
    acc[3] = fmaf(w, hv.w, acc[3]);
  }
  float4 outv = make_float4(acc[0], acc[1], acc[2], acc[3]);
  *(float4*)(pooled + (size_t)b * HIDDEN + c0) = outv;
}

// ---------------- final: out[b] = r3[b,:] . W4 + b4 ----------------
__global__ __launch_bounds__(256) void out_kernel(
    const float* __restrict__ r3, const float* __restrict__ W4,
    const float* __restrict__ b4, float* __restrict__ out)
{
  int lane = threadIdx.x & 63;
  int wv = threadIdx.x >> 6;
  int b = blockIdx.x * 4 + wv;
  if (b >= N_B) return;
  float v = r3[(size_t)b * 64 + lane] * W4[lane];
#pragma unroll
  for (int o = 1; o < 64; o <<= 1) v += __shfl_xor(v, o);
  if (lane == 0) out[b] = v + b4[0];
}

extern "C" void kernel_launch(void* const* d_in, const int* in_sizes, int n_in,
                              void* d_out, int out_size, void* d_ws, size_t ws_size,
                              hipStream_t stream)
{
  const float* x    = (const float*)d_in[0];
  const int* ei     = (const int*)d_in[1];
  const float* ea   = (const float*)d_in[2];
  const int* batch  = (const int*)d_in[3];
  const float* W_in = (const float*)d_in[4];
  const float* b_in = (const float*)d_in[5];
  const float* Wl   = (const float*)d_in[6];
  const float* Wr   = (const float*)d_in[7];
  const float* We   = (const float*)d_in[8];
  const float* att  = (const float*)d_in[9];
  const float* bgat = (const float*)d_in[10];
  const float* Wg1  = (const float*)d_in[11];
  const float* bg1  = (const float*)d_in[12];
  const float* Wg2  = (const float*)d_in[13];
  const float* bg2  = (const float*)d_in[14];
  const float* W1   = (const float*)d_in[15];
  const float* b1   = (const float*)d_in[16];
  const float* W2   = (const float*)d_in[17];
  const float* b2   = (const float*)d_in[18];
  const float* W3   = (const float*)d_in[19];
  const float* b3   = (const float*)d_in[20];
  const float* W4   = (const float*)d_in[21];
  const float* b4   = (const float*)d_in[22];
  float* out = (float*)d_out;

  char* ws = (char*)d_ws;
  size_t off = 0;
  auto alloc = [&](size_t bytes) -> char* {
    char* p = ws + off;
    off += (bytes + 255) & ~(size_t)255;
    return p;
  };
  float* h            = (float*)alloc((size_t)N_NODES * HIDDEN * 4);           // 102.4 MB
  unsigned short* hb  = (unsigned short*)alloc((size_t)N_NODES * HIDDEN * 2);  // 51.2 MB
  unsigned short* xlr = (unsigned short*)alloc((size_t)N_NODES * 512 * 2);     // 102.4 MB
  int* deg       = (int*)alloc((size_t)N_NODES * 4);
  int* rowptr    = (int*)alloc((size_t)(N_NODES + 1) * 4);
  int* cursor    = (int*)alloc((size_t)N_NODES * 4);
  int* csr       = (int*)alloc((size_t)N_EDGES * 4);       // real edges only
  int* brp       = (int*)alloc((size_t)(N_B + 1) * 4);
  int* bsum      = (int*)alloc(512);
  float* macc    = (float*)alloc(64);
  float* meanattr= (float*)alloc(64);
  float* ep_self = (float*)alloc(4 * 256 * 4);
  float* logits  = (float*)alloc((size_t)N_EDGES * 8 * 4); // 7.04 MB
  unsigned short* Wint  = (unsigned short*)alloc(256 * 128 * 2);      // [256][128]
  unsigned short* Wlrt  = (unsigned short*)alloc(4 * 512 * 256 * 2);  // [i][512][256] = Wl^T || Wr^T
  unsigned short* Wg1t  = (unsigned short*)alloc(128 * 256 * 2);      // [128][256]
  // total ≈ 266.3 MB < 268.4 MB ws  ✓

  // aliases into dead regions of xlr:
  unsigned short* xpad = xlr;            // [N,128] bf16, pre-layer0 only (25.6 MB < 102.4)
  float* base2  = (float*)xlr;           // xlr fully dead after last attn layer
  float* gate   = base2;                 // [N] f32
  float* pooled = base2 + 1000000;       // [B,256] f32
  float* r1     = base2 + 3000000;       // [B,256] f32
  float* r2     = base2 + 5000000;       // [B,128] f32
  float* r3     = base2 + 6000000;       // [B,64]  f32

  if (ws_size < off) {
    hipMemsetAsync(d_out, 0, (size_t)out_size * 4, stream);
    return;
  }

  zero_kernel<<<391, 256, 0, stream>>>(deg, cursor, macc);
  mean_kernel<<<64, 256, 0, stream>>>(ea, macc);
  meanattr_kernel<<<1, 64, 0, stream>>>(macc, meanattr);
  epself_kernel<<<4, 256, 0, stream>>>(meanattr, We, ep_self);
  count_kernel<<<860, 256, 0, stream>>>(ei, deg);
  scan1_kernel<<<NSCANB, 1024, 0, stream>>>(deg, rowptr, bsum);
  scan2_kernel<<<1, 128, 0, stream>>>(bsum);
  scan3_kernel<<<NSCANB, 1024, 0, stream>>>(rowptr, bsum);
  scatter_kernel<<<860, 256, 0, stream>>>(ei, rowptr, cursor, csr);
  brp_kernel<<<512, 256, 0, stream>>>(batch, brp);

  // weight conversions (transpose + bf16); Wint padded to K=128
  wt_kernel<<<(256 * 128 + 255) / 256, 256, 0, stream>>>(W_in, Wint, 75, 128, 256);
  wlr_kernel<<<512, 256, 0, stream>>>(Wl, Wr, Wlrt);
  wt_kernel<<<128, 256, 0, stream>>>(Wg1, Wg1t, 256, 256, 128);
  convx_kernel<<<4096, 256, 0, stream>>>(x, xpad);

  // input projection: h = elu((x @ W_in + b_in) * BN_S)  [MFMA, K=128 padded, gx=4]
  gemm_mfma<<<3128, 256, 0, stream>>>(xpad, Wint, b_in, h, hb,
                                      N_NODES, 256, 128, 2, BN_S, 4);

  for (int i = 0; i < 4; ++i) {
    // fused xl||xr GEMM: [N,256] @ [256,512] -> xlr [N,512]  (gx=8, 64-col tiles)
    gemm_mfma<<<6256, 256, 0, stream>>>(hb, Wlrt + (size_t)i * 131072, nullptr,
                                        nullptr, xlr, N_NODES, 512, 256, 0, 1.f, 8);
    // pass A: edge-parallel logits
    logits_kernel<<<2048, 256, 0, stream>>>(xlr, ei, ea, We + (size_t)i * 2560,
                                            att + (size_t)i * 256, logits);
    // pass B: node-parallel softmax + aggregate
    attn_kernel<<<25000, 256, 0, stream>>>(xlr, h, hb, ei, logits,
                                           att + (size_t)i * 256, bgat + (size_t)i * 256,
                                           ep_self + (size_t)i * 256, rowptr, csr);
  }

  // fused pooling gate: gate = relu(hb @ Wg1 + bg1) . Wg2 + bg2
  gemm_gate<<<782, 256, 0, stream>>>(hb, Wg1t, bg1, Wg2, bg2, gate, N_NODES);
  pool_kernel<<<N_B, 64, 0, stream>>>(gate, h, brp, pooled);

  // readout MLP (f32, tiny)
  gemm_f32<<<dim3(4, 64), 256, 0, stream>>>(pooled, W1, b1, r1, N_B, 256, 256, 1, BN_S);
  gemm_f32<<<dim3(2, 64), 256, 0, stream>>>(r1, W2, b2, r2, N_B, 128, 256, 1, BN_S);
  gemm_f32<<<dim3(1, 64), 256, 0, stream>>>(r2, W3, b3, r3, N_B, 64, 128, 1, 1.f);
  out_kernel<<<1024, 256, 0, stream>>>(r3, W4, b4, out);
}

// Round 13
// 1077.834 us; speedup vs baseline: 1.1214x; 1.0570x over previous
//
#include <hip/hip_runtime.h>

#define N_NODES 100000
#define N_EDGES 220000
#define N_B     4096
#define HIDDEN  256
#define BN_S    0.9999950000374997f
#define NSCANB  98       // ceil(100000/1024)

typedef __attribute__((ext_vector_type(8))) short bf16x8;
typedef __attribute__((ext_vector_type(4))) float f32x4;

__device__ __forceinline__ float bf2f(unsigned short u) {
  return __uint_as_float(((unsigned int)u) << 16);
}
__device__ __forceinline__ unsigned short f2bf(float f) {
  unsigned int x = __float_as_uint(f);
  unsigned int lsb = (x >> 16) & 1u;
  x += 0x7fffu + lsb;
  return (unsigned short)(x >> 16);
}

// async global->LDS 16B: dest is wave-uniform base + lane*16 (linear);
// per-lane GLOBAL address carries the XOR swizzle (m173 pattern).
__device__ __forceinline__ void g2lds16(const void* g, void* l) {
  __builtin_amdgcn_global_load_lds(
      (const __attribute__((address_space(1))) unsigned int*)g,
      (__attribute__((address_space(3))) unsigned int*)l, 16, 0, 0);
}

// bijective XCD swizzle (m204)
__device__ __forceinline__ int xcd_swz(int b, int nwg) {
  int q = nwg >> 3, r = nwg & 7;
  int xcd = b & 7, idx = b >> 3;
  int base = (xcd < r) ? xcd * (q + 1) : r * (q + 1) + (xcd - r) * q;
  return base + idx;
}

// ---------------- zero-init of counters ----------------
__global__ void zero_kernel(int* __restrict__ deg, int* __restrict__ cursor, float* __restrict__ macc) {
  int i = blockIdx.x * blockDim.x + threadIdx.x;
  if (i < N_NODES) { deg[i] = 0; cursor[i] = 0; }
  if (i < 16) macc[i] = 0.f;
}

// ---------------- mean of edge_attr (block-reduced, 1 atomic/k/block) ----------------
__global__ __launch_bounds__(256) void mean_kernel(const float* __restrict__ ea, float* __restrict__ macc) {
  __shared__ float sred[4][16];
  int lane = threadIdx.x & 63;
  int wv = threadIdx.x >> 6;
  float loc[10];
#pragma unroll
  for (int k = 0; k < 10; ++k) loc[k] = 0.f;
  for (int e = blockIdx.x * blockDim.x + threadIdx.x; e < N_EDGES; e += gridDim.x * blockDim.x) {
    const float* p = ea + (size_t)e * 10;
#pragma unroll
    for (int k = 0; k < 10; ++k) loc[k] += p[k];
  }
#pragma unroll
  for (int k = 0; k < 10; ++k) {
    float v = loc[k];
#pragma unroll
    for (int o = 1; o < 64; o <<= 1) v += __shfl_xor(v, o);
    if (lane == 0) sred[wv][k] = v;
  }
  __syncthreads();
  if (threadIdx.x < 10) {
    float s = sred[0][threadIdx.x] + sred[1][threadIdx.x] +
              sred[2][threadIdx.x] + sred[3][threadIdx.x];
    atomicAdd(&macc[threadIdx.x], s);
  }
}

__global__ void meanattr_kernel(const float* __restrict__ macc, float* __restrict__ meanattr) {
  int t = threadIdx.x;
  const float invE = 1.f / (float)N_EDGES;
  if (t < 10) meanattr[t] = macc[t] * invE;
}

// ---------------- ep_self[i][c] = meanattr . We[i][:,c] ----------------
__global__ void epself_kernel(const float* __restrict__ meanattr, const float* __restrict__ We,
                              float* __restrict__ ep_self) {
  int i = blockIdx.x;
  int c = threadIdx.x;
  float s = 0.f;
#pragma unroll
  for (int k = 0; k < 10; ++k)
    s += meanattr[k] * We[(size_t)i * 2560 + k * 256 + c];
  ep_self[i * 256 + c] = s;
}

// ---------------- CSR build (REAL edges only) ----------------
__global__ void count_kernel(const int* __restrict__ ei, int* __restrict__ deg) {
  for (int e = blockIdx.x * blockDim.x + threadIdx.x; e < N_EDGES; e += gridDim.x * blockDim.x) {
    atomicAdd(&deg[ei[N_EDGES + e]], 1);
  }
}

// ---------------- 3-phase scan ----------------
__global__ __launch_bounds__(1024) void scan1_kernel(const int* __restrict__ deg,
                                                     int* __restrict__ rowptr,
                                                     int* __restrict__ bsum) {
  __shared__ int buf[1024];
  int t = threadIdx.x;
  int i = blockIdx.x * 1024 + t;
  int v = (i < N_NODES) ? deg[i] : 0;
  buf[t] = v;
  __syncthreads();
  for (int off = 1; off < 1024; off <<= 1) {
    int add = (t >= off) ? buf[t - off] : 0;
    __syncthreads();
    buf[t] += add;
    __syncthreads();
  }
  if (i < N_NODES) rowptr[i + 1] = buf[t];
  if (t == 1023) bsum[blockIdx.x] = buf[t];
  if (i == 0) rowptr[0] = 0;
}

__global__ __launch_bounds__(128) void scan2_kernel(int* __restrict__ bsum) {
  __shared__ int buf[128];
  int t = threadIdx.x;
  int v = (t < NSCANB) ? bsum[t] : 0;
  buf[t] = v;
  __syncthreads();
  for (int off = 1; off < 128; off <<= 1) {
    int add = (t >= off) ? buf[t - off] : 0;
    __syncthreads();
    buf[t] += add;
    __syncthreads();
  }
  if (t < NSCANB) bsum[t] = buf[t];
}

__global__ __launch_bounds__(1024) void scan3_kernel(int* __restrict__ rowptr,
                                                     const int* __restrict__ bsum) {
  int b = blockIdx.x;
  if (b == 0) return;
  int i = b * 1024 + threadIdx.x;
  if (i < N_NODES) rowptr[i + 1] += bsum[b - 1];
}

__global__ void scatter_kernel(const int* __restrict__ ei, const int* __restrict__ rowptr,
                               int* __restrict__ cursor, int* __restrict__ csr) {
  for (int e = blockIdx.x * blockDim.x + threadIdx.x; e < N_EDGES; e += gridDim.x * blockDim.x) {
    int t = ei[N_EDGES + e];
    int pos = atomicAdd(&cursor[t], 1);
    csr[rowptr[t] + pos] = e;
  }
}

__global__ void brp_kernel(const int* __restrict__ batch, int* __restrict__ brp) {
  for (int i = blockIdx.x * blockDim.x + threadIdx.x; i < N_NODES; i += gridDim.x * blockDim.x) {
    int bi = batch[i];
    int bp = (i == 0) ? -1 : batch[i - 1];
    for (int b = bp + 1; b <= bi; ++b) brp[b] = i;
    if (i == N_NODES - 1) {
      for (int b = bi + 1; b <= N_B; ++b) brp[b] = N_NODES;
    }
  }
}

// ---------------- x -> padded bf16 [N,128] (K pad for BK=64 GEMM) ----------------
__global__ void convx_kernel(const float* __restrict__ x, unsigned short* __restrict__ xp) {
  int total = N_NODES * 128;
  for (int idx = blockIdx.x * blockDim.x + threadIdx.x; idx < total; idx += gridDim.x * blockDim.x) {
    int nn = idx >> 7;
    int j = idx & 127;
    unsigned short v = 0;
    if (j < 75) v = f2bf(x[(size_t)nn * 75 + j]);
    xp[idx] = v;
  }
}

// ---------------- weight transpose+bf16 ----------------
__global__ void wt_kernel(const float* __restrict__ src, unsigned short* __restrict__ dst,
                          int K, int Kp, int N) {
  int idx = blockIdx.x * blockDim.x + threadIdx.x;
  int total = N * Kp;
  if (idx >= total) return;
  int n = idx / Kp, k = idx - n * Kp;
  dst[idx] = (k < K) ? f2bf(src[(size_t)k * N + n]) : (unsigned short)0;
}

// ---------------- all 4 layers Wl^T||Wr^T in one launch ----------------
__global__ void wlr_kernel(const float* __restrict__ Wl, const float* __restrict__ Wr,
                           unsigned short* __restrict__ dst) {
  const int total = 4 * 512 * 256;
  for (int idx = blockIdx.x * blockDim.x + threadIdx.x; idx < total; idx += gridDim.x * blockDim.x) {
    int i = idx >> 17;          // /131072
    int rem = idx & 131071;
    int n = rem >> 8;           // 0..511
    int k = rem & 255;
    float v = (n < 256) ? Wl[(size_t)i * 65536 + k * 256 + n]
                        : Wr[(size_t)i * 65536 + k * 256 + (n - 256)];
    dst[idx] = f2bf(v);
  }
}

// ---------------- bf16 MFMA GEMM: 128x64 block tile, 64x32 per wave ----------------
// Occupancy-first: acc 32 regs/wave -> 4-5 waves/SIMD. BK=64 swizzled staging
// (slot^=(row&7) on pre-swizzled global src + ds_read addr; g2lds dest linear).
// Requires K % 64 == 0, Ncol % 64 == 0.
__global__ __launch_bounds__(256) void gemm_mfma(
    const unsigned short* __restrict__ A, const unsigned short* __restrict__ Bt,
    const float* __restrict__ bias, float* __restrict__ Cf, unsigned short* __restrict__ Cb,
    int M, int Ncol, int K, int act, float scale, int gx)
{
  __shared__ unsigned short smem[12288];   // 24KB: As[128*64]=8192, Bs[64*64]=4096; C-stage reuses
  unsigned short* As = smem;
  unsigned short* Bs = smem + 8192;
  const int tid = threadIdx.x;
  const int wave = tid >> 6;
  const int lane = tid & 63;

  const int wg = xcd_swz(blockIdx.x, gridDim.x);
  const int col0 = (wg % gx) * 64;
  const int row0 = (wg / gx) * 128;

  const int wrow = (wave >> 1) * 64;   // 0 or 64
  const int wcol = (wave & 1) * 32;    // 0 or 32
  const int lrow = lane & 15;
  const int quad = lane >> 4;

  const int lr8 = lane >> 3;               // 0..7
  const int slot = lane & 7;               // 16B slot within 64-elem row
  const int sw = ((slot ^ lr8) << 3);      // pre-swizzled source elem offset
  const unsigned short* pa[4];
  const unsigned short* pb[2];
#pragma unroll
  for (int j = 0; j < 4; ++j) {
    int tr = wave * 32 + j * 8 + lr8;
    int gra = row0 + tr; if (gra > M - 1) gra = M - 1;  // clamp: rows >= M discarded in epilogue
    pa[j] = A + (size_t)gra * K + sw;
  }
#pragma unroll
  for (int j = 0; j < 2; ++j) {
    int tr = wave * 16 + j * 8 + lr8;
    pb[j] = Bt + (size_t)(col0 + tr) * K + sw;
  }

  f32x4 acc[4][2] = {};

  for (int k0 = 0; k0 < K; k0 += 64) {
#pragma unroll
    for (int j = 0; j < 4; ++j)
      g2lds16(pa[j] + k0, &As[(wave * 32 + j * 8) * 64]);
#pragma unroll
    for (int j = 0; j < 2; ++j)
      g2lds16(pb[j] + k0, &Bs[(wave * 16 + j * 8) * 64]);
    __syncthreads();   // drains vmcnt (global_load_lds) before LDS reads
#pragma unroll
    for (int kk = 0; kk < 2; ++kk) {
      bf16x8 afr[4], bfr[2];
#pragma unroll
      for (int mt = 0; mt < 4; ++mt) {
        int rr = wrow + mt * 16 + lrow;
        afr[mt] = *(const bf16x8*)(&As[rr * 64 + ((((kk << 2) + quad) ^ (rr & 7)) << 3)]);
      }
#pragma unroll
      for (int nt = 0; nt < 2; ++nt) {
        int rr = wcol + nt * 16 + lrow;
        bfr[nt] = *(const bf16x8*)(&Bs[rr * 64 + ((((kk << 2) + quad) ^ (rr & 7)) << 3)]);
      }
#pragma unroll
      for (int mt = 0; mt < 4; ++mt)
#pragma unroll
        for (int nt = 0; nt < 2; ++nt)
          acc[mt][nt] = __builtin_amdgcn_mfma_f32_16x16x32_bf16(afr[mt], bfr[nt], acc[mt][nt], 0, 0, 0);
    }
    __syncthreads();
  }

  // ---- epilogue: single pass, stage 128x64 bf16 tile (stride 72), coalesced 16B stores ----
#pragma unroll
  for (int mt = 0; mt < 4; ++mt) {
#pragma unroll
    for (int nt = 0; nt < 2; ++nt) {
      int lcol = wcol + nt * 16 + lrow;
      float bv = bias ? bias[col0 + lcol] : 0.f;
#pragma unroll
      for (int r = 0; r < 4; ++r) {
        float v = (acc[mt][nt][r] + bv) * scale;
        if (act == 1) v = fmaxf(v, 0.f);
        else if (act == 2) v = (v > 0.f) ? v : (__expf(v) - 1.f);
        int srow = wrow + mt * 16 + quad * 4 + r;
        smem[srow * 72 + lcol] = f2bf(v);
        if (Cf) {
          int grow = row0 + srow;
          if (grow < M) Cf[(size_t)grow * Ncol + col0 + lcol] = v;
        }
      }
    }
  }
  __syncthreads();
  if (Cb) {
#pragma unroll
    for (int round = 0; round < 4; ++round) {
      int sr = round * 32 + (tid >> 3);
      int ce = (tid & 7) * 8;
      int grow = row0 + sr;
      if (grow < M) {
        uint4 v = *(const uint4*)(&smem[sr * 72 + ce]);
        *(uint4*)(Cb + (size_t)grow * Ncol + col0 + ce) = v;
      }
    }
  }
}

// ---------------- fused pooling-gate GEMM (single-buffer BK=32 staging, K=256) ----------------
__global__ __launch_bounds__(256) void gemm_gate(
    const unsigned short* __restrict__ A, const unsigned short* __restrict__ Bt,
    const float* __restrict__ bg1, const float* __restrict__ Wg2,
    const float* __restrict__ bg2, float* __restrict__ gate, int M)
{
  __shared__ unsigned short As[128 * 32];
  __shared__ unsigned short Bs[128 * 32];
  __shared__ float gbuf[128][2];
  const int tid = threadIdx.x;
  const int wave = tid >> 6;
  const int lane = tid & 63;

  const int wg = xcd_swz(blockIdx.x, gridDim.x);
  const int row0 = wg * 128;

  const int wrow = (wave >> 1) * 64;
  const int wcol = (wave & 1) * 64;
  const int lrow = lane & 15;
  const int quad = lane >> 4;

  const int rbase = wave * 32;
  const int lr4 = lane >> 2;
  const int lc = lane & 3;
  const int tr0 = rbase + lr4;
  const int tr1 = rbase + 16 + lr4;
  int gra0 = row0 + tr0; if (gra0 > M - 1) gra0 = M - 1;
  int gra1 = row0 + tr1; if (gra1 > M - 1) gra1 = M - 1;
  const int sca0 = (lc ^ ((tr0 >> 1) & 3)) * 8;
  const int sca1 = (lc ^ ((tr1 >> 1) & 3)) * 8;
  const unsigned short* pa0 = A + (size_t)gra0 * 256 + sca0;
  const unsigned short* pa1 = A + (size_t)gra1 * 256 + sca1;
  const unsigned short* pb0 = Bt + (size_t)tr0 * 256 + sca0;
  const unsigned short* pb1 = Bt + (size_t)tr1 * 256 + sca1;

  f32x4 acc[4][4] = {};

  for (int k0 = 0; k0 < 256; k0 += 32) {
    g2lds16(pa0 + k0, &As[rbase * 32]);
    g2lds16(pa1 + k0, &As[(rbase + 16) * 32]);
    g2lds16(pb0 + k0, &Bs[rbase * 32]);
    g2lds16(pb1 + k0, &Bs[(rbase + 16) * 32]);
    __syncthreads();
    bf16x8 afr[4], bfr[4];
#pragma unroll
    for (int mt = 0; mt < 4; ++mt) {
      int rr = wrow + mt * 16 + lrow;
      afr[mt] = *(const bf16x8*)(&As[rr * 32 + ((quad ^ ((rr >> 1) & 3)) << 3)]);
    }
#pragma unroll
    for (int nt = 0; nt < 4; ++nt) {
      int rr = wcol + nt * 16 + lrow;
      bfr[nt] = *(const bf16x8*)(&Bs[rr * 32 + ((quad ^ ((rr >> 1) & 3)) << 3)]);
    }
#pragma unroll
    for (int mt = 0; mt < 4; ++mt)
#pragma unroll
      for (int nt = 0; nt < 4; ++nt)
        acc[mt][nt] = __builtin_amdgcn_mfma_f32_16x16x32_bf16(afr[mt], bfr[nt], acc[mt][nt], 0, 0, 0);
    __syncthreads();
  }

  float p[4][4];
#pragma unroll
  for (int mt = 0; mt < 4; ++mt)
#pragma unroll
    for (int r = 0; r < 4; ++r) p[mt][r] = 0.f;
#pragma unroll
  for (int nt = 0; nt < 4; ++nt) {
    int gcol = wcol + nt * 16 + lrow;
    float b1v = bg1[gcol];
    float w2v = Wg2[gcol];
#pragma unroll
    for (int mt = 0; mt < 4; ++mt)
#pragma unroll
      for (int r = 0; r < 4; ++r) {
        float v = fmaxf(acc[mt][nt][r] + b1v, 0.f);
        p[mt][r] = fmaf(v, w2v, p[mt][r]);
      }
  }
#pragma unroll
  for (int mt = 0; mt < 4; ++mt)
#pragma unroll
    for (int r = 0; r < 4; ++r) {
      float v = p[mt][r];
      v += __shfl_xor(v, 1);
      v += __shfl_xor(v, 2);
      v += __shfl_xor(v, 4);
      v += __shfl_xor(v, 8);
      if (lrow == 0) gbuf[wrow + mt * 16 + quad * 4 + r][wcol >> 6] = v;
    }
  __syncthreads();
  if (tid < 128) {
    int grow = row0 + tid;
    if (grow < M) gate[grow] = gbuf[tid][0] + gbuf[tid][1] + bg2[0];
  }
}

// ---------------- f32 GEMM for the tiny readout layers ----------------
__global__ __launch_bounds__(256) void gemm_f32(
    const float* __restrict__ A, const float* __restrict__ B,
    const float* __restrict__ bias, float* __restrict__ C,
    int M, int Ncol, int K, int act, float scale)
{
  __shared__ float As[32][68];
  __shared__ float Bs[32][68];
  const int tid = threadIdx.x;
  const int tx = tid & 15, ty = tid >> 4;
  const int col0 = blockIdx.x * 64;
  const int row0 = blockIdx.y * 64;
  float acc[4][4];
#pragma unroll
  for (int i = 0; i < 4; ++i)
#pragma unroll
    for (int j = 0; j < 4; ++j) acc[i][j] = 0.f;

  const int ar = tid >> 3;
  const int ak = (tid & 7) * 4;
  const int bk = tid >> 4;
  const int bc = (tid & 15) * 4;

  for (int k0 = 0; k0 < K; k0 += 32) {
#pragma unroll
    for (int p = 0; p < 2; ++p) {
      int r = ar + p * 32;
      int grow = row0 + r;
      float4 v = make_float4(0.f, 0.f, 0.f, 0.f);
      if (grow < M) v = *(const float4*)(A + (size_t)grow * K + k0 + ak);
      As[ak + 0][r] = v.x; As[ak + 1][r] = v.y; As[ak + 2][r] = v.z; As[ak + 3][r] = v.w;
    }
#pragma unroll
    for (int p = 0; p < 2; ++p) {
      int kk = bk + p * 16;
      float4 v = *(const float4*)(B + (size_t)(k0 + kk) * Ncol + col0 + bc);
      *(float4*)(&Bs[kk][bc]) = v;
    }
    __syncthreads();
#pragma unroll
    for (int kk = 0; kk < 32; ++kk) {
      float4 a = *(const float4*)(&As[kk][ty * 4]);
      float4 b = *(const float4*)(&Bs[kk][tx * 4]);
      float av[4] = {a.x, a.y, a.z, a.w};
      float bv[4] = {b.x, b.y, b.z, b.w};
#pragma unroll
      for (int i = 0; i < 4; ++i)
#pragma unroll
        for (int j = 0; j < 4; ++j) acc[i][j] = fmaf(av[i], bv[j], acc[i][j]);
    }
    __syncthreads();
  }
  float bvals[4] = {0.f, 0.f, 0.f, 0.f};
  if (bias) {
#pragma unroll
    for (int j = 0; j < 4; ++j) bvals[j] = bias[col0 + tx * 4 + j];
  }
#pragma unroll
  for (int i = 0; i < 4; ++i) {
    int r = row0 + ty * 4 + i;
    if (r >= M) continue;
    float4 outv;
    float* o = (float*)&outv;
#pragma unroll
    for (int j = 0; j < 4; ++j) {
      float v = (acc[i][j] + bvals[j]) * scale;
      if (act == 1) v = fmaxf(v, 0.f);
      else if (act == 2) v = (v > 0.f) ? v : (__expf(v) - 1.f);
      o[j] = v;
    }
    *(float4*)(C + (size_t)r * Ncol + col0 + tx * 4) = outv;
  }
}

// ---------------- PASS A: edge-parallel logits (real edges only) ----------------
// One-shot launch, 4 edges per wave: 4 independent gather chains in flight
// (ei/eattr loads for all 4 edges hoist above the xlr row gathers).
__global__ __launch_bounds__(256) void logits_kernel(
    const unsigned short* __restrict__ xlr,
    const int* __restrict__ ei, const float* __restrict__ eattr,
    const float* __restrict__ We, const float* __restrict__ att,
    float* __restrict__ logits)
{
  const int lane = threadIdx.x & 63;
  const int wv = threadIdx.x >> 6;
  const int c0 = lane * 4;
  const int head = lane >> 3;

  float4 attf4 = *(const float4*)(att + c0);
  float attf[4] = {attf4.x, attf4.y, attf4.z, attf4.w};
  float wef[10][4];
#pragma unroll
  for (int k = 0; k < 10; ++k) {
    float4 w4 = *(const float4*)(We + k * 256 + c0);
    wef[k][0] = w4.x; wef[k][1] = w4.y; wef[k][2] = w4.z; wef[k][3] = w4.w;
  }

  const int e0 = (blockIdx.x * 4 + wv) * 4;   // one-shot: 4 consecutive edges per wave
  if (e0 >= N_EDGES) return;
  const int ne = (N_EDGES - e0 < 4) ? (N_EDGES - e0) : 4;

  // phase 1: edge metadata for all slots (clamped; independent loads)
  int src[4], tgt[4];
  float ev[4][10];
#pragma unroll
  for (int j = 0; j < 4; ++j) {
    int e = e0 + ((j < ne) ? j : (ne - 1));
    src[j] = ei[e];
    tgt[j] = ei[N_EDGES + e];
    const float* eap = eattr + (size_t)e * 10;
    float2 q0 = *(const float2*)(eap + 0);
    float2 q1 = *(const float2*)(eap + 2);
    float2 q2 = *(const float2*)(eap + 4);
    float2 q3 = *(const float2*)(eap + 6);
    float2 q4 = *(const float2*)(eap + 8);
    ev[j][0] = q0.x; ev[j][1] = q0.y; ev[j][2] = q1.x; ev[j][3] = q1.y;
    ev[j][4] = q2.x; ev[j][5] = q2.y; ev[j][6] = q3.x; ev[j][7] = q3.y;
    ev[j][8] = q4.x; ev[j][9] = q4.y;
  }

  // phase 2: all xlr gathers in flight
  ushort4 ua[4], ub[4];
#pragma unroll
  for (int j = 0; j < 4; ++j) {
    ua[j] = *(const ushort4*)(xlr + src[j] * 512 + c0);
    ub[j] = *(const ushort4*)(xlr + tgt[j] * 512 + 256 + c0);
  }

  // phase 3: compute + reduce + store
#pragma unroll
  for (int j = 0; j < 4; ++j) {
    float p0 = 0.f, p1 = 0.f, p2 = 0.f, p3 = 0.f;
#pragma unroll
    for (int k = 0; k < 10; ++k) {
      p0 = fmaf(ev[j][k], wef[k][0], p0);
      p1 = fmaf(ev[j][k], wef[k][1], p1);
      p2 = fmaf(ev[j][k], wef[k][2], p2);
      p3 = fmaf(ev[j][k], wef[k][3], p3);
    }
    float s0 = bf2f(ua[j].x) + bf2f(ub[j].x) + p0;
    float s1 = bf2f(ua[j].y) + bf2f(ub[j].y) + p1;
    float s2 = bf2f(ua[j].z) + bf2f(ub[j].z) + p2;
    float s3 = bf2f(ua[j].w) + bf2f(ub[j].w) + p3;
    s0 = (s0 > 0.f) ? s0 : 0.2f * s0;
    s1 = (s1 > 0.f) ? s1 : 0.2f * s1;
    s2 = (s2 > 0.f) ? s2 : 0.2f * s2;
    s3 = (s3 > 0.f) ? s3 : 0.2f * s3;
    float part = s0 * attf[0] + s1 * attf[1] + s2 * attf[2] + s3 * attf[3];
    part += __shfl_xor(part, 1);
    part += __shfl_xor(part, 2);
    part += __shfl_xor(part, 4);
    if (j < ne && (lane & 7) == 0) logits[(e0 + j) * 8 + head] = part;
  }
}

// ---------------- PASS B: node-parallel softmax + aggregate + BN/ELU/residual ----------------
// Register-phase softmax with wave-uniform degree specialization:
// deg<=4 (93% of nodes, Poisson(2.2)) uses a 4-slot phase; deg 5..8 the 8-slot
// phase; deg>8 loops. 32-bit indices. Padding slots: w=0, self row (no NaN).
__global__ __launch_bounds__(256) void attn_kernel(
    const unsigned short* __restrict__ xlr,
    float* __restrict__ h, unsigned short* __restrict__ hb,
    const int* __restrict__ ei, const float* __restrict__ logits,
    const float* __restrict__ att, const float* __restrict__ bgat,
    const float* __restrict__ ep_self,
    const int* __restrict__ rowptr, const int* __restrict__ csr)
{
  const int lane = threadIdx.x & 63;
  const int wv = threadIdx.x >> 6;
  const int n = blockIdx.x * 4 + wv;
  if (n >= N_NODES) return;
  const int c0 = lane * 4;
  const int head = lane >> 3;

  const int s = rowptr[n], e = rowptr[n + 1];
  const int deg = e - s;

  ushort4 ul = *(const ushort4*)(xlr + n * 512 + c0);        // xl[n]
  ushort4 ur = *(const ushort4*)(xlr + n * 512 + 256 + c0);  // xr[n]
  float4 hold = *(const float4*)(h + n * HIDDEN + c0);
  float4 attf = *(const float4*)(att + c0);
  float4 eps = *(const float4*)(ep_self + c0);

  float xln[4] = {bf2f(ul.x), bf2f(ul.y), bf2f(ul.z), bf2f(ul.w)};

  // self-loop logit
  float lself;
  {
    float s0 = xln[0] + bf2f(ur.x) + eps.x;
    float s1 = xln[1] + bf2f(ur.y) + eps.y;
    float s2 = xln[2] + bf2f(ur.z) + eps.z;
    float s3 = xln[3] + bf2f(ur.w) + eps.w;
    s0 = (s0 > 0.f) ? s0 : 0.2f * s0;
    s1 = (s1 > 0.f) ? s1 : 0.2f * s1;
    s2 = (s2 > 0.f) ? s2 : 0.2f * s2;
    s3 = (s3 > 0.f) ? s3 : 0.2f * s3;
    float part = s0 * attf.x + s1 * attf.y + s2 * attf.z + s3 * attf.w;
    part += __shfl_xor(part, 1);
    part += __shfl_xor(part, 2);
    part += __shfl_xor(part, 4);
    lself = part;
  }

  float m = lself;
  float d, a0, a1, a2, a3;

  if (deg <= 4) {
    // ---- 4-slot fast path (93% of nodes; wave-uniform branch) ----
    float lg[4];
    int src[4];
    if (deg > 0) {
      const int elast = e - 1;
      int eid[4];
#pragma unroll
      for (int j = 0; j < 4; ++j) {
        int idx = s + j; if (idx > elast) idx = elast;
        eid[j] = csr[idx];
      }
#pragma unroll
      for (int j = 0; j < 4; ++j) {
        lg[j] = logits[eid[j] * 8 + head];
        src[j] = ei[eid[j]];
      }
#pragma unroll
      for (int j = 0; j < 4; ++j)
        if (j < deg) m = fmaxf(m, lg[j]);
    }
    float w[4];
#pragma unroll
    for (int j = 0; j < 4; ++j)
      w[j] = (j < deg) ? __expf(lg[j] - m) : 0.f;
    ushort4 uu[4];
#pragma unroll
    for (int j = 0; j < 4; ++j) uu[j] = ul;
#pragma unroll
    for (int j = 0; j < 4; ++j)
      if (j < deg) uu[j] = *(const ushort4*)(xlr + src[j] * 512 + c0);
    float wself = __expf(lself - m);
    d = wself;
    a0 = wself * xln[0]; a1 = wself * xln[1]; a2 = wself * xln[2]; a3 = wself * xln[3];
#pragma unroll
    for (int j = 0; j < 4; ++j) {
      d += w[j];
      a0 += w[j] * bf2f(uu[j].x);
      a1 += w[j] * bf2f(uu[j].y);
      a2 += w[j] * bf2f(uu[j].z);
      a3 += w[j] * bf2f(uu[j].w);
    }
  } else {
    // ---- 8-slot path + loop tail (deg > 4) ----
    float lg[8];
    int src[8];
    const int elast = e - 1;
    int eid[8];
#pragma unroll
    for (int j = 0; j < 8; ++j) {
      int idx = s + j; if (idx > elast) idx = elast;
      eid[j] = csr[idx];
    }
#pragma unroll
    for (int j = 0; j < 8; ++j) {
      lg[j] = logits[eid[j] * 8 + head];
      src[j] = ei[eid[j]];
    }
#pragma unroll
    for (int j = 0; j < 8; ++j)
      if (j < deg) m = fmaxf(m, lg[j]);
    for (int idx = s + 8; idx < e; ++idx) {   // rare tail (deg > 8)
      int eidt = csr[idx];
      m = fmaxf(m, logits[eidt * 8 + head]);
    }
    float w[8];
#pragma unroll
    for (int j = 0; j < 8; ++j)
      w[j] = (j < deg) ? __expf(lg[j] - m) : 0.f;
    ushort4 uu[8];
#pragma unroll
    for (int j = 0; j < 8; ++j) uu[j] = ul;
#pragma unroll
    for (int j = 0; j < 8; ++j)
      if (j < deg) uu[j] = *(const ushort4*)(xlr + src[j] * 512 + c0);
    float wself = __expf(lself - m);
    d = wself;
    a0 = wself * xln[0]; a1 = wself * xln[1]; a2 = wself * xln[2]; a3 = wself * xln[3];
#pragma unroll
    for (int j = 0; j < 8; ++j) {
      d += w[j];
      a0 += w[j] * bf2f(uu[j].x);
      a1 += w[j] * bf2f(uu[j].y);
      a2 += w[j] * bf2f(uu[j].z);
      a3 += w[j] * bf2f(uu[j].w);
    }
    for (int idx = s + 8; idx < e; ++idx) {   // rare tail (deg > 8)
      int eidt = csr[idx];
      float l = logits[eidt * 8 + head];
      int sn = ei[eidt];
      float ww = __expf(l - m);
      ushort4 u = *(const ushort4*)(xlr + sn * 512 + c0);
      d += ww;
      a0 += ww * bf2f(u.x);
      a1 += ww * bf2f(u.y);
      a2 += ww * bf2f(u.z);
      a3 += ww * bf2f(u.w);
    }
  }

  float inv = 1.f / (d + 1e-16f);
  float4 bg = *(const float4*)(bgat + c0);
  float ov[4] = {a0 * inv, a1 * inv, a2 * inv, a3 * inv};
  float bgv[4] = {bg.x, bg.y, bg.z, bg.w};
  float hv[4] = {hold.x, hold.y, hold.z, hold.w};
  float4 res;
  float* rp = (float*)&res;
  ushort4 resb;
  unsigned short* rb = (unsigned short*)&resb;
#pragma unroll
  for (int j = 0; j < 4; ++j) {
    float v = (ov[j] + bgv[j]) * BN_S;
    v = (v > 0.f) ? v : (__expf(v) - 1.f);
    float nv = v + hv[j];
    rp[j] = nv;
    rb[j] = f2bf(nv);
  }
  *(float4*)(h + n * HIDDEN + c0) = res;
  *(ushort4*)(hb + n * HIDDEN + c0) = resb;
}

// ---------------- global attention pooling per graph ----------------
__global__ __launch_bounds__(64) void pool_kernel(
    const float* __restrict__ gate, const float* __restrict__ h,
    const int* __restrict__ brp, float* __restrict__ pooled)
{
  int b = blockIdx.x;
  int lane = threadIdx.x;
  int s = brp[b], e = brp[b + 1];
  float m = -__builtin_inff();
  for (int i = s + lane; i < e; i += 64) m = fmaxf(m, gate[i]);
#pragma unroll
  for (int o = 1; o < 64; o <<= 1) m = fmaxf(m, __shfl_xor(m, o));
  float d = 0.f;
  for (int i = s + lane; i < e; i += 64) d += __expf(gate[i] - m);
#pragma unroll
  for (int o = 1; o < 64; o <<= 1) d += __shfl_xor(d, o);
  float inv = 1.f / (d + 1e-16f);
  int c0 = lane * 4;
  float acc[4] = {0.f, 0.f, 0.f, 0.f};
  for (int i = s; i < e; ++i) {
    float w = __expf(gate[i] - m) * inv;
    float4 hv = *(const float4*)(h + (size_t)i * HIDDEN + c0);
    acc[0] = fmaf(w, hv.x, acc[0]);
    acc[1] = fmaf(w, hv.y, acc[1]);
    acc[2] = fmaf(w, hv.z, acc[2]);
    acc[3] = fmaf(w, hv.w, acc[3]);
  }
  float4 outv = make_float4(acc[0], acc[1], acc[2], acc[3]);
  *(float4*)(pooled + (size_t)b * HIDDEN + c0) = outv;
}

// ---------------- final: out[b] = r3[b,:] . W4 + b4 ----------------
__global__ __launch_bounds__(256) void out_kernel(
    const float* __restrict__ r3, const float* __restrict__ W4,
    const float* __restrict__ b4, float* __restrict__ out)
{
  int lane = threadIdx.x & 63;
  int wv = threadIdx.x >> 6;
  int b = blockIdx.x * 4 + wv;
  if (b >= N_B) return;
  float v = r3[(size_t)b * 64 + lane] * W4[lane];
#pragma unroll
  for (int o = 1; o < 64; o <<= 1) v += __shfl_xor(v, o);
  if (lane == 0) out[b] = v + b4[0];
}

extern "C" void kernel_launch(void* const* d_in, const int* in_sizes, int n_in,
                              void* d_out, int out_size, void* d_ws, size_t ws_size,
                              hipStream_t stream)
{
  const float* x    = (const float*)d_in[0];
  const int* ei     = (const int*)d_in[1];
  const float* ea   = (const float*)d_in[2];
  const int* batch  = (const int*)d_in[3];
  const float* W_in = (const float*)d_in[4];
  const float* b_in = (const float*)d_in[5];
  const float* Wl   = (const float*)d_in[6];
  const float* Wr   = (const float*)d_in[7];
  const float* We   = (const float*)d_in[8];
  const float* att  = (const float*)d_in[9];
  const float* bgat = (const float*)d_in[10];
  const float* Wg1  = (const float*)d_in[11];
  const float* bg1  = (const float*)d_in[12];
  const float* Wg2  = (const float*)d_in[13];
  const float* bg2  = (const float*)d_in[14];
  const float* W1   = (const float*)d_in[15];
  const float* b1   = (const float*)d_in[16];
  const float* W2   = (const float*)d_in[17];
  const float* b2   = (const float*)d_in[18];
  const float* W3   = (const float*)d_in[19];
  const float* b3   = (const float*)d_in[20];
  const float* W4   = (const float*)d_in[21];
  const float* b4   = (const float*)d_in[22];
  float* out = (float*)d_out;

  char* ws = (char*)d_ws;
  size_t off = 0;
  auto alloc = [&](size_t bytes) -> char* {
    char* p = ws + off;
    off += (bytes + 255) & ~(size_t)255;
    return p;
  };
  float* h            = (float*)alloc((size_t)N_NODES * HIDDEN * 4);           // 102.4 MB
  unsigned short* hb  = (unsigned short*)alloc((size_t)N_NODES * HIDDEN * 2);  // 51.2 MB
  unsigned short* xlr = (unsigned short*)alloc((size_t)N_NODES * 512 * 2);     // 102.4 MB
  int* deg       = (int*)alloc((size_t)N_NODES * 4);
  int* rowptr    = (int*)alloc((size_t)(N_NODES + 1) * 4);
  int* cursor    = (int*)alloc((size_t)N_NODES * 4);
  int* csr       = (int*)alloc((size_t)N_EDGES * 4);       // real edges only
  int* brp       = (int*)alloc((size_t)(N_B + 1) * 4);
  int* bsum      = (int*)alloc(512);
  float* macc    = (float*)alloc(64);
  float* meanattr= (float*)alloc(64);
  float* ep_self = (float*)alloc(4 * 256 * 4);
  float* logits  = (float*)alloc((size_t)N_EDGES * 8 * 4); // 7.04 MB
  unsigned short* Wint  = (unsigned short*)alloc(256 * 128 * 2);      // [256][128]
  unsigned short* Wlrt  = (unsigned short*)alloc(4 * 512 * 256 * 2);  // [i][512][256] = Wl^T || Wr^T
  unsigned short* Wg1t  = (unsigned short*)alloc(128 * 256 * 2);      // [128][256]
  // total ≈ 266.3 MB < 268.4 MB ws  ✓

  // aliases into dead regions of xlr:
  unsigned short* xpad = xlr;            // [N,128] bf16, pre-layer0 only (25.6 MB < 102.4)
  float* base2  = (float*)xlr;           // xlr fully dead after last attn layer
  float* gate   = base2;                 // [N] f32
  float* pooled = base2 + 1000000;       // [B,256] f32
  float* r1     = base2 + 3000000;       // [B,256] f32
  float* r2     = base2 + 5000000;       // [B,128] f32
  float* r3     = base2 + 6000000;       // [B,64]  f32

  if (ws_size < off) {
    hipMemsetAsync(d_out, 0, (size_t)out_size * 4, stream);
    return;
  }

  zero_kernel<<<391, 256, 0, stream>>>(deg, cursor, macc);
  mean_kernel<<<64, 256, 0, stream>>>(ea, macc);
  meanattr_kernel<<<1, 64, 0, stream>>>(macc, meanattr);
  epself_kernel<<<4, 256, 0, stream>>>(meanattr, We, ep_self);
  count_kernel<<<860, 256, 0, stream>>>(ei, deg);
  scan1_kernel<<<NSCANB, 1024, 0, stream>>>(deg, rowptr, bsum);
  scan2_kernel<<<1, 128, 0, stream>>>(bsum);
  scan3_kernel<<<NSCANB, 1024, 0, stream>>>(rowptr, bsum);
  scatter_kernel<<<860, 256, 0, stream>>>(ei, rowptr, cursor, csr);
  brp_kernel<<<512, 256, 0, stream>>>(batch, brp);

  // weight conversions (transpose + bf16); Wint padded to K=128
  wt_kernel<<<(256 * 128 + 255) / 256, 256, 0, stream>>>(W_in, Wint, 75, 128, 256);
  wlr_kernel<<<512, 256, 0, stream>>>(Wl, Wr, Wlrt);
  wt_kernel<<<128, 256, 0, stream>>>(Wg1, Wg1t, 256, 256, 128);
  convx_kernel<<<4096, 256, 0, stream>>>(x, xpad);

  // input projection: h = elu((x @ W_in + b_in) * BN_S)  [MFMA, K=128 padded, gx=4]
  gemm_mfma<<<3128, 256, 0, stream>>>(xpad, Wint, b_in, h, hb,
                                      N_NODES, 256, 128, 2, BN_S, 4);

  for (int i = 0; i < 4; ++i) {
    // fused xl||xr GEMM: [N,256] @ [256,512] -> xlr [N,512]  (gx=8, 64-col tiles)
    gemm_mfma<<<6256, 256, 0, stream>>>(hb, Wlrt + (size_t)i * 131072, nullptr,
                                        nullptr, xlr, N_NODES, 512, 256, 0, 1.f, 8);
    // pass A: edge-parallel logits (one-shot, 4 edges/wave)
    logits_kernel<<<13750, 256, 0, stream>>>(xlr, ei, ea, We + (size_t)i * 2560,
                                             att + (size_t)i * 256, logits);
    // pass B: node-parallel softmax + aggregate
    attn_kernel<<<25000, 256, 0, stream>>>(xlr, h, hb, ei, logits,
                                           att + (size_t)i * 256, bgat + (size_t)i * 256,
                                           ep_self + (size_t)i * 256, rowptr, csr);
  }

  // fused pooling gate: gate = relu(hb @ Wg1 + bg1) . Wg2 + bg2
  gemm_gate<<<782, 256, 0, stream>>>(hb, Wg1t, bg1, Wg2, bg2, gate, N_NODES);
  pool_kernel<<<N_B, 64, 0, stream>>>(gate, h, brp, pooled);

  // readout MLP (f32, tiny)
  gemm_f32<<<dim3(4, 64), 256, 0, stream>>>(pooled, W1, b1, r1, N_B, 256, 256, 1, BN_S);
  gemm_f32<<<dim3(2, 64), 256, 0, stream>>>(r1, W2, b2, r2, N_B, 128, 256, 1, BN_S);
  gemm_f32<<<dim3(1, 64), 256, 0, stream>>>(r2, W3, b3, r3, N_B, 64, 128, 1, 1.f);
  out_kernel<<<1024, 256, 0, stream>>>(r3, W4, b4, out);
}

// Round 14
// 1075.401 us; speedup vs baseline: 1.1240x; 1.0023x over previous
//
#include <hip/hip_runtime.h>

#define N_NODES 100000
#define N_EDGES 220000
#define N_B     4096
#define HIDDEN  256
#define BN_S    0.9999950000374997f
#define NSCANB  98       // ceil(100000/1024)

typedef __attribute__((ext_vector_type(8))) short bf16x8;
typedef __attribute__((ext_vector_type(4))) float f32x4;

__device__ __forceinline__ float bf2f(unsigned short u) {
  return __uint_as_float(((unsigned int)u) << 16);
}
__device__ __forceinline__ unsigned short f2bf(float f) {
  unsigned int x = __float_as_uint(f);
  unsigned int lsb = (x >> 16) & 1u;
  x += 0x7fffu + lsb;
  return (unsigned short)(x >> 16);
}

// async global->LDS 16B: dest is wave-uniform base + lane*16 (linear);
// per-lane GLOBAL address carries the XOR swizzle (m173 pattern).
__device__ __forceinline__ void g2lds16(const void* g, void* l) {
  __builtin_amdgcn_global_load_lds(
      (const __attribute__((address_space(1))) unsigned int*)g,
      (__attribute__((address_space(3))) unsigned int*)l, 16, 0, 0);
}

// bijective XCD swizzle (m204)
__device__ __forceinline__ int xcd_swz(int b, int nwg) {
  int q = nwg >> 3, r = nwg & 7;
  int xcd = b & 7, idx = b >> 3;
  int base = (xcd < r) ? xcd * (q + 1) : r * (q + 1) + (xcd - r) * q;
  return base + idx;
}

// ---------------- zero-init of counters ----------------
__global__ void zero_kernel(int* __restrict__ deg, int* __restrict__ cursor, float* __restrict__ macc) {
  int i = blockIdx.x * blockDim.x + threadIdx.x;
  if (i < N_NODES) { deg[i] = 0; cursor[i] = 0; }
  if (i < 16) macc[i] = 0.f;
}

// ---------------- mean of edge_attr (block-reduced, 1 atomic/k/block) ----------------
__global__ __launch_bounds__(256) void mean_kernel(const float* __restrict__ ea, float* __restrict__ macc) {
  __shared__ float sred[4][16];
  int lane = threadIdx.x & 63;
  int wv = threadIdx.x >> 6;
  float loc[10];
#pragma unroll
  for (int k = 0; k < 10; ++k) loc[k] = 0.f;
  for (int e = blockIdx.x * blockDim.x + threadIdx.x; e < N_EDGES; e += gridDim.x * blockDim.x) {
    const float* p = ea + (size_t)e * 10;
#pragma unroll
    for (int k = 0; k < 10; ++k) loc[k] += p[k];
  }
#pragma unroll
  for (int k = 0; k < 10; ++k) {
    float v = loc[k];
#pragma unroll
    for (int o = 1; o < 64; o <<= 1) v += __shfl_xor(v, o);
    if (lane == 0) sred[wv][k] = v;
  }
  __syncthreads();
  if (threadIdx.x < 10) {
    float s = sred[0][threadIdx.x] + sred[1][threadIdx.x] +
              sred[2][threadIdx.x] + sred[3][threadIdx.x];
    atomicAdd(&macc[threadIdx.x], s);
  }
}

__global__ void meanattr_kernel(const float* __restrict__ macc, float* __restrict__ meanattr) {
  int t = threadIdx.x;
  const float invE = 1.f / (float)N_EDGES;
  if (t < 10) meanattr[t] = macc[t] * invE;
}

// ---------------- ep_self[i][c] = meanattr . We[i][:,c] ----------------
__global__ void epself_kernel(const float* __restrict__ meanattr, const float* __restrict__ We,
                              float* __restrict__ ep_self) {
  int i = blockIdx.x;
  int c = threadIdx.x;
  float s = 0.f;
#pragma unroll
  for (int k = 0; k < 10; ++k)
    s += meanattr[k] * We[(size_t)i * 2560 + k * 256 + c];
  ep_self[i * 256 + c] = s;
}

// ---------------- CSR build (REAL edges only) ----------------
__global__ void count_kernel(const int* __restrict__ ei, int* __restrict__ deg) {
  for (int e = blockIdx.x * blockDim.x + threadIdx.x; e < N_EDGES; e += gridDim.x * blockDim.x) {
    atomicAdd(&deg[ei[N_EDGES + e]], 1);
  }
}

// ---------------- 3-phase scan ----------------
__global__ __launch_bounds__(1024) void scan1_kernel(const int* __restrict__ deg,
                                                     int* __restrict__ rowptr,
                                                     int* __restrict__ bsum) {
  __shared__ int buf[1024];
  int t = threadIdx.x;
  int i = blockIdx.x * 1024 + t;
  int v = (i < N_NODES) ? deg[i] : 0;
  buf[t] = v;
  __syncthreads();
  for (int off = 1; off < 1024; off <<= 1) {
    int add = (t >= off) ? buf[t - off] : 0;
    __syncthreads();
    buf[t] += add;
    __syncthreads();
  }
  if (i < N_NODES) rowptr[i + 1] = buf[t];
  if (t == 1023) bsum[blockIdx.x] = buf[t];
  if (i == 0) rowptr[0] = 0;
}

__global__ __launch_bounds__(128) void scan2_kernel(int* __restrict__ bsum) {
  __shared__ int buf[128];
  int t = threadIdx.x;
  int v = (t < NSCANB) ? bsum[t] : 0;
  buf[t] = v;
  __syncthreads();
  for (int off = 1; off < 128; off <<= 1) {
    int add = (t >= off) ? buf[t - off] : 0;
    __syncthreads();
    buf[t] += add;
    __syncthreads();
  }
  if (t < NSCANB) bsum[t] = buf[t];
}

__global__ __launch_bounds__(1024) void scan3_kernel(int* __restrict__ rowptr,
                                                     const int* __restrict__ bsum) {
  int b = blockIdx.x;
  if (b == 0) return;
  int i = b * 1024 + threadIdx.x;
  if (i < N_NODES) rowptr[i + 1] += bsum[b - 1];
}

__global__ void scatter_kernel(const int* __restrict__ ei, const int* __restrict__ rowptr,
                               int* __restrict__ cursor, int* __restrict__ csr) {
  for (int e = blockIdx.x * blockDim.x + threadIdx.x; e < N_EDGES; e += gridDim.x * blockDim.x) {
    int t = ei[N_EDGES + e];
    int pos = atomicAdd(&cursor[t], 1);
    csr[rowptr[t] + pos] = e;
  }
}

__global__ void brp_kernel(const int* __restrict__ batch, int* __restrict__ brp) {
  for (int i = blockIdx.x * blockDim.x + threadIdx.x; i < N_NODES; i += gridDim.x * blockDim.x) {
    int bi = batch[i];
    int bp = (i == 0) ? -1 : batch[i - 1];
    for (int b = bp + 1; b <= bi; ++b) brp[b] = i;
    if (i == N_NODES - 1) {
      for (int b = bi + 1; b <= N_B; ++b) brp[b] = N_NODES;
    }
  }
}

// ---------------- x -> padded bf16 [N,128] (K pad for BK=64 GEMM) ----------------
__global__ void convx_kernel(const float* __restrict__ x, unsigned short* __restrict__ xp) {
  int total = N_NODES * 128;
  for (int idx = blockIdx.x * blockDim.x + threadIdx.x; idx < total; idx += gridDim.x * blockDim.x) {
    int nn = idx >> 7;
    int j = idx & 127;
    unsigned short v = 0;
    if (j < 75) v = f2bf(x[(size_t)nn * 75 + j]);
    xp[idx] = v;
  }
}

// ---------------- weight transpose+bf16 ----------------
__global__ void wt_kernel(const float* __restrict__ src, unsigned short* __restrict__ dst,
                          int K, int Kp, int N) {
  int idx = blockIdx.x * blockDim.x + threadIdx.x;
  int total = N * Kp;
  if (idx >= total) return;
  int n = idx / Kp, k = idx - n * Kp;
  dst[idx] = (k < K) ? f2bf(src[(size_t)k * N + n]) : (unsigned short)0;
}

// ---------------- all 4 layers Wl^T||Wr^T in one launch ----------------
__global__ void wlr_kernel(const float* __restrict__ Wl, const float* __restrict__ Wr,
                           unsigned short* __restrict__ dst) {
  const int total = 4 * 512 * 256;
  for (int idx = blockIdx.x * blockDim.x + threadIdx.x; idx < total; idx += gridDim.x * blockDim.x) {
    int i = idx >> 17;          // /131072
    int rem = idx & 131071;
    int n = rem >> 8;           // 0..511
    int k = rem & 255;
    float v = (n < 256) ? Wl[(size_t)i * 65536 + k * 256 + n]
                        : Wr[(size_t)i * 65536 + k * 256 + (n - 256)];
    dst[idx] = f2bf(v);
  }
}

// ---------------- bf16 MFMA GEMM: 128x64 block tile, 64x32 per wave ----------------
// Occupancy-first: acc 32 regs/wave -> 4-5 waves/SIMD. BK=64 swizzled staging
// (slot^=(row&7) on pre-swizzled global src + ds_read addr; g2lds dest linear).
// Requires K % 64 == 0, Ncol % 64 == 0.
__global__ __launch_bounds__(256) void gemm_mfma(
    const unsigned short* __restrict__ A, const unsigned short* __restrict__ Bt,
    const float* __restrict__ bias, float* __restrict__ Cf, unsigned short* __restrict__ Cb,
    int M, int Ncol, int K, int act, float scale, int gx)
{
  __shared__ unsigned short smem[12288];   // 24KB: As[128*64]=8192, Bs[64*64]=4096; C-stage reuses
  unsigned short* As = smem;
  unsigned short* Bs = smem + 8192;
  const int tid = threadIdx.x;
  const int wave = tid >> 6;
  const int lane = tid & 63;

  const int wg = xcd_swz(blockIdx.x, gridDim.x);
  const int col0 = (wg % gx) * 64;
  const int row0 = (wg / gx) * 128;

  const int wrow = (wave >> 1) * 64;   // 0 or 64
  const int wcol = (wave & 1) * 32;    // 0 or 32
  const int lrow = lane & 15;
  const int quad = lane >> 4;

  const int lr8 = lane >> 3;               // 0..7
  const int slot = lane & 7;               // 16B slot within 64-elem row
  const int sw = ((slot ^ lr8) << 3);      // pre-swizzled source elem offset
  const unsigned short* pa[4];
  const unsigned short* pb[2];
#pragma unroll
  for (int j = 0; j < 4; ++j) {
    int tr = wave * 32 + j * 8 + lr8;
    int gra = row0 + tr; if (gra > M - 1) gra = M - 1;  // clamp: rows >= M discarded in epilogue
    pa[j] = A + (size_t)gra * K + sw;
  }
#pragma unroll
  for (int j = 0; j < 2; ++j) {
    int tr = wave * 16 + j * 8 + lr8;
    pb[j] = Bt + (size_t)(col0 + tr) * K + sw;
  }

  f32x4 acc[4][2] = {};

  for (int k0 = 0; k0 < K; k0 += 64) {
#pragma unroll
    for (int j = 0; j < 4; ++j)
      g2lds16(pa[j] + k0, &As[(wave * 32 + j * 8) * 64]);
#pragma unroll
    for (int j = 0; j < 2; ++j)
      g2lds16(pb[j] + k0, &Bs[(wave * 16 + j * 8) * 64]);
    __syncthreads();   // drains vmcnt (global_load_lds) before LDS reads
#pragma unroll
    for (int kk = 0; kk < 2; ++kk) {
      bf16x8 afr[4], bfr[2];
#pragma unroll
      for (int mt = 0; mt < 4; ++mt) {
        int rr = wrow + mt * 16 + lrow;
        afr[mt] = *(const bf16x8*)(&As[rr * 64 + ((((kk << 2) + quad) ^ (rr & 7)) << 3)]);
      }
#pragma unroll
      for (int nt = 0; nt < 2; ++nt) {
        int rr = wcol + nt * 16 + lrow;
        bfr[nt] = *(const bf16x8*)(&Bs[rr * 64 + ((((kk << 2) + quad) ^ (rr & 7)) << 3)]);
      }
#pragma unroll
      for (int mt = 0; mt < 4; ++mt)
#pragma unroll
        for (int nt = 0; nt < 2; ++nt)
          acc[mt][nt] = __builtin_amdgcn_mfma_f32_16x16x32_bf16(afr[mt], bfr[nt], acc[mt][nt], 0, 0, 0);
    }
    __syncthreads();
  }

  // ---- epilogue: single pass, stage 128x64 bf16 tile (stride 72), coalesced 16B stores ----
#pragma unroll
  for (int mt = 0; mt < 4; ++mt) {
#pragma unroll
    for (int nt = 0; nt < 2; ++nt) {
      int lcol = wcol + nt * 16 + lrow;
      float bv = bias ? bias[col0 + lcol] : 0.f;
#pragma unroll
      for (int r = 0; r < 4; ++r) {
        float v = (acc[mt][nt][r] + bv) * scale;
        if (act == 1) v = fmaxf(v, 0.f);
        else if (act == 2) v = (v > 0.f) ? v : (__expf(v) - 1.f);
        int srow = wrow + mt * 16 + quad * 4 + r;
        smem[srow * 72 + lcol] = f2bf(v);
        if (Cf) {
          int grow = row0 + srow;
          if (grow < M) Cf[(size_t)grow * Ncol + col0 + lcol] = v;
        }
      }
    }
  }
  __syncthreads();
  if (Cb) {
#pragma unroll
    for (int round = 0; round < 4; ++round) {
      int sr = round * 32 + (tid >> 3);
      int ce = (tid & 7) * 8;
      int grow = row0 + sr;
      if (grow < M) {
        uint4 v = *(const uint4*)(&smem[sr * 72 + ce]);
        *(uint4*)(Cb + (size_t)grow * Ncol + col0 + ce) = v;
      }
    }
  }
}

// ---------------- fused pooling-gate GEMM (single-buffer BK=32 staging, K=256) ----------------
__global__ __launch_bounds__(256) void gemm_gate(
    const unsigned short* __restrict__ A, const unsigned short* __restrict__ Bt,
    const float* __restrict__ bg1, const float* __restrict__ Wg2,
    const float* __restrict__ bg2, float* __restrict__ gate, int M)
{
  __shared__ unsigned short As[128 * 32];
  __shared__ unsigned short Bs[128 * 32];
  __shared__ float gbuf[128][2];
  const int tid = threadIdx.x;
  const int wave = tid >> 6;
  const int lane = tid & 63;

  const int wg = xcd_swz(blockIdx.x, gridDim.x);
  const int row0 = wg * 128;

  const int wrow = (wave >> 1) * 64;
  const int wcol = (wave & 1) * 64;
  const int lrow = lane & 15;
  const int quad = lane >> 4;

  const int rbase = wave * 32;
  const int lr4 = lane >> 2;
  const int lc = lane & 3;
  const int tr0 = rbase + lr4;
  const int tr1 = rbase + 16 + lr4;
  int gra0 = row0 + tr0; if (gra0 > M - 1) gra0 = M - 1;
  int gra1 = row0 + tr1; if (gra1 > M - 1) gra1 = M - 1;
  const int sca0 = (lc ^ ((tr0 >> 1) & 3)) * 8;
  const int sca1 = (lc ^ ((tr1 >> 1) & 3)) * 8;
  const unsigned short* pa0 = A + (size_t)gra0 * 256 + sca0;
  const unsigned short* pa1 = A + (size_t)gra1 * 256 + sca1;
  const unsigned short* pb0 = Bt + (size_t)tr0 * 256 + sca0;
  const unsigned short* pb1 = Bt + (size_t)tr1 * 256 + sca1;

  f32x4 acc[4][4] = {};

  for (int k0 = 0; k0 < 256; k0 += 32) {
    g2lds16(pa0 + k0, &As[rbase * 32]);
    g2lds16(pa1 + k0, &As[(rbase + 16) * 32]);
    g2lds16(pb0 + k0, &Bs[rbase * 32]);
    g2lds16(pb1 + k0, &Bs[(rbase + 16) * 32]);
    __syncthreads();
    bf16x8 afr[4], bfr[4];
#pragma unroll
    for (int mt = 0; mt < 4; ++mt) {
      int rr = wrow + mt * 16 + lrow;
      afr[mt] = *(const bf16x8*)(&As[rr * 32 + ((quad ^ ((rr >> 1) & 3)) << 3)]);
    }
#pragma unroll
    for (int nt = 0; nt < 4; ++nt) {
      int rr = wcol + nt * 16 + lrow;
      bfr[nt] = *(const bf16x8*)(&Bs[rr * 32 + ((quad ^ ((rr >> 1) & 3)) << 3)]);
    }
#pragma unroll
    for (int mt = 0; mt < 4; ++mt)
#pragma unroll
      for (int nt = 0; nt < 4; ++nt)
        acc[mt][nt] = __builtin_amdgcn_mfma_f32_16x16x32_bf16(afr[mt], bfr[nt], acc[mt][nt], 0, 0, 0);
    __syncthreads();
  }

  float p[4][4];
#pragma unroll
  for (int mt = 0; mt < 4; ++mt)
#pragma unroll
    for (int r = 0; r < 4; ++r) p[mt][r] = 0.f;
#pragma unroll
  for (int nt = 0; nt < 4; ++nt) {
    int gcol = wcol + nt * 16 + lrow;
    float b1v = bg1[gcol];
    float w2v = Wg2[gcol];
#pragma unroll
    for (int mt = 0; mt < 4; ++mt)
#pragma unroll
      for (int r = 0; r < 4; ++r) {
        float v = fmaxf(acc[mt][nt][r] + b1v, 0.f);
        p[mt][r] = fmaf(v, w2v, p[mt][r]);
      }
  }
#pragma unroll
  for (int mt = 0; mt < 4; ++mt)
#pragma unroll
    for (int r = 0; r < 4; ++r) {
      float v = p[mt][r];
      v += __shfl_xor(v, 1);
      v += __shfl_xor(v, 2);
      v += __shfl_xor(v, 4);
      v += __shfl_xor(v, 8);
      if (lrow == 0) gbuf[wrow + mt * 16 + quad * 4 + r][wcol >> 6] = v;
    }
  __syncthreads();
  if (tid < 128) {
    int grow = row0 + tid;
    if (grow < M) gate[grow] = gbuf[tid][0] + gbuf[tid][1] + bg2[0];
  }
}

// ---------------- f32 GEMM for the tiny readout layers ----------------
__global__ __launch_bounds__(256) void gemm_f32(
    const float* __restrict__ A, const float* __restrict__ B,
    const float* __restrict__ bias, float* __restrict__ C,
    int M, int Ncol, int K, int act, float scale)
{
  __shared__ float As[32][68];
  __shared__ float Bs[32][68];
  const int tid = threadIdx.x;
  const int tx = tid & 15, ty = tid >> 4;
  const int col0 = blockIdx.x * 64;
  const int row0 = blockIdx.y * 64;
  float acc[4][4];
#pragma unroll
  for (int i = 0; i < 4; ++i)
#pragma unroll
    for (int j = 0; j < 4; ++j) acc[i][j] = 0.f;

  const int ar = tid >> 3;
  const int ak = (tid & 7) * 4;
  const int bk = tid >> 4;
  const int bc = (tid & 15) * 4;

  for (int k0 = 0; k0 < K; k0 += 32) {
#pragma unroll
    for (int p = 0; p < 2; ++p) {
      int r = ar + p * 32;
      int grow = row0 + r;
      float4 v = make_float4(0.f, 0.f, 0.f, 0.f);
      if (grow < M) v = *(const float4*)(A + (size_t)grow * K + k0 + ak);
      As[ak + 0][r] = v.x; As[ak + 1][r] = v.y; As[ak + 2][r] = v.z; As[ak + 3][r] = v.w;
    }
#pragma unroll
    for (int p = 0; p < 2; ++p) {
      int kk = bk + p * 16;
      float4 v = *(const float4*)(B + (size_t)(k0 + kk) * Ncol + col0 + bc);
      *(float4*)(&Bs[kk][bc]) = v;
    }
    __syncthreads();
#pragma unroll
    for (int kk = 0; kk < 32; ++kk) {
      float4 a = *(const float4*)(&As[kk][ty * 4]);
      float4 b = *(const float4*)(&Bs[kk][tx * 4]);
      float av[4] = {a.x, a.y, a.z, a.w};
      float bv[4] = {b.x, b.y, b.z, b.w};
#pragma unroll
      for (int i = 0; i < 4; ++i)
#pragma unroll
        for (int j = 0; j < 4; ++j) acc[i][j] = fmaf(av[i], bv[j], acc[i][j]);
    }
    __syncthreads();
  }
  float bvals[4] = {0.f, 0.f, 0.f, 0.f};
  if (bias) {
#pragma unroll
    for (int j = 0; j < 4; ++j) bvals[j] = bias[col0 + tx * 4 + j];
  }
#pragma unroll
  for (int i = 0; i < 4; ++i) {
    int r = row0 + ty * 4 + i;
    if (r >= M) continue;
    float4 outv;
    float* o = (float*)&outv;
#pragma unroll
    for (int j = 0; j < 4; ++j) {
      float v = (acc[i][j] + bvals[j]) * scale;
      if (act == 1) v = fmaxf(v, 0.f);
      else if (act == 2) v = (v > 0.f) ? v : (__expf(v) - 1.f);
      o[j] = v;
    }
    *(float4*)(C + (size_t)r * Ncol + col0 + tx * 4) = outv;
  }
}

// ---------------- PASS A: edge-parallel logits (real edges only) ----------------
// One-shot launch, 4 edges per wave: 4 independent gather chains in flight.
__global__ __launch_bounds__(256) void logits_kernel(
    const unsigned short* __restrict__ xlr,
    const int* __restrict__ ei, const float* __restrict__ eattr,
    const float* __restrict__ We, const float* __restrict__ att,
    float* __restrict__ logits)
{
  const int lane = threadIdx.x & 63;
  const int wv = threadIdx.x >> 6;
  const int c0 = lane * 4;
  const int head = lane >> 3;

  float4 attf4 = *(const float4*)(att + c0);
  float attf[4] = {attf4.x, attf4.y, attf4.z, attf4.w};
  float wef[10][4];
#pragma unroll
  for (int k = 0; k < 10; ++k) {
    float4 w4 = *(const float4*)(We + k * 256 + c0);
    wef[k][0] = w4.x; wef[k][1] = w4.y; wef[k][2] = w4.z; wef[k][3] = w4.w;
  }

  const int e0 = (blockIdx.x * 4 + wv) * 4;   // one-shot: 4 consecutive edges per wave
  if (e0 >= N_EDGES) return;
  const int ne = (N_EDGES - e0 < 4) ? (N_EDGES - e0) : 4;

  // phase 1: edge metadata for all slots (clamped; independent loads)
  int src[4], tgt[4];
  float ev[4][10];
#pragma unroll
  for (int j = 0; j < 4; ++j) {
    int e = e0 + ((j < ne) ? j : (ne - 1));
    src[j] = ei[e];
    tgt[j] = ei[N_EDGES + e];
    const float* eap = eattr + (size_t)e * 10;
    float2 q0 = *(const float2*)(eap + 0);
    float2 q1 = *(const float2*)(eap + 2);
    float2 q2 = *(const float2*)(eap + 4);
    float2 q3 = *(const float2*)(eap + 6);
    float2 q4 = *(const float2*)(eap + 8);
    ev[j][0] = q0.x; ev[j][1] = q0.y; ev[j][2] = q1.x; ev[j][3] = q1.y;
    ev[j][4] = q2.x; ev[j][5] = q2.y; ev[j][6] = q3.x; ev[j][7] = q3.y;
    ev[j][8] = q4.x; ev[j][9] = q4.y;
  }

  // phase 2: all xlr gathers in flight
  ushort4 ua[4], ub[4];
#pragma unroll
  for (int j = 0; j < 4; ++j) {
    ua[j] = *(const ushort4*)(xlr + src[j] * 512 + c0);
    ub[j] = *(const ushort4*)(xlr + tgt[j] * 512 + 256 + c0);
  }

  // phase 3: compute + reduce + store
#pragma unroll
  for (int j = 0; j < 4; ++j) {
    float p0 = 0.f, p1 = 0.f, p2 = 0.f, p3 = 0.f;
#pragma unroll
    for (int k = 0; k < 10; ++k) {
      p0 = fmaf(ev[j][k], wef[k][0], p0);
      p1 = fmaf(ev[j][k], wef[k][1], p1);
      p2 = fmaf(ev[j][k], wef[k][2], p2);
      p3 = fmaf(ev[j][k], wef[k][3], p3);
    }
    float s0 = bf2f(ua[j].x) + bf2f(ub[j].x) + p0;
    float s1 = bf2f(ua[j].y) + bf2f(ub[j].y) + p1;
    float s2 = bf2f(ua[j].z) + bf2f(ub[j].z) + p2;
    float s3 = bf2f(ua[j].w) + bf2f(ub[j].w) + p3;
    s0 = (s0 > 0.f) ? s0 : 0.2f * s0;
    s1 = (s1 > 0.f) ? s1 : 0.2f * s1;
    s2 = (s2 > 0.f) ? s2 : 0.2f * s2;
    s3 = (s3 > 0.f) ? s3 : 0.2f * s3;
    float part = s0 * attf[0] + s1 * attf[1] + s2 * attf[2] + s3 * attf[3];
    part += __shfl_xor(part, 1);
    part += __shfl_xor(part, 2);
    part += __shfl_xor(part, 4);
    if (j < ne && (lane & 7) == 0) logits[(e0 + j) * 8 + head] = part;
  }
}

// ---------------- PASS B: node-parallel softmax + aggregate + BN/ELU/residual ----------------
// Register-phase softmax, three-tier wave-uniform degree specialization:
// deg<=2 (~62% of nodes, Poisson(2.2)) 2-slot; deg<=4 (~31%) 4-slot;
// deg 5..8 8-slot; deg>8 loop tail. 32-bit indices.
// Padding slots: w=0, self row (no NaN).
__global__ __launch_bounds__(256) void attn_kernel(
    const unsigned short* __restrict__ xlr,
    float* __restrict__ h, unsigned short* __restrict__ hb,
    const int* __restrict__ ei, const float* __restrict__ logits,
    const float* __restrict__ att, const float* __restrict__ bgat,
    const float* __restrict__ ep_self,
    const int* __restrict__ rowptr, const int* __restrict__ csr)
{
  const int lane = threadIdx.x & 63;
  const int wv = threadIdx.x >> 6;
  const int n = blockIdx.x * 4 + wv;
  if (n >= N_NODES) return;
  const int c0 = lane * 4;
  const int head = lane >> 3;

  const int s = rowptr[n], e = rowptr[n + 1];
  const int deg = e - s;

  ushort4 ul = *(const ushort4*)(xlr + n * 512 + c0);        // xl[n]
  ushort4 ur = *(const ushort4*)(xlr + n * 512 + 256 + c0);  // xr[n]
  float4 hold = *(const float4*)(h + n * HIDDEN + c0);
  float4 attf = *(const float4*)(att + c0);
  float4 eps = *(const float4*)(ep_self + c0);

  float xln[4] = {bf2f(ul.x), bf2f(ul.y), bf2f(ul.z), bf2f(ul.w)};

  // self-loop logit
  float lself;
  {
    float s0 = xln[0] + bf2f(ur.x) + eps.x;
    float s1 = xln[1] + bf2f(ur.y) + eps.y;
    float s2 = xln[2] + bf2f(ur.z) + eps.z;
    float s3 = xln[3] + bf2f(ur.w) + eps.w;
    s0 = (s0 > 0.f) ? s0 : 0.2f * s0;
    s1 = (s1 > 0.f) ? s1 : 0.2f * s1;
    s2 = (s2 > 0.f) ? s2 : 0.2f * s2;
    s3 = (s3 > 0.f) ? s3 : 0.2f * s3;
    float part = s0 * attf.x + s1 * attf.y + s2 * attf.z + s3 * attf.w;
    part += __shfl_xor(part, 1);
    part += __shfl_xor(part, 2);
    part += __shfl_xor(part, 4);
    lself = part;
  }

  float m = lself;
  float d, a0, a1, a2, a3;

  if (deg <= 2) {
    // ---- 2-slot fast path (~62% of nodes; wave-uniform branch) ----
    float lg[2];
    int src[2];
    if (deg > 0) {
      const int elast = e - 1;
      int eid[2];
#pragma unroll
      for (int j = 0; j < 2; ++j) {
        int idx = s + j; if (idx > elast) idx = elast;
        eid[j] = csr[idx];
      }
#pragma unroll
      for (int j = 0; j < 2; ++j) {
        lg[j] = logits[eid[j] * 8 + head];
        src[j] = ei[eid[j]];
      }
#pragma unroll
      for (int j = 0; j < 2; ++j)
        if (j < deg) m = fmaxf(m, lg[j]);
    }
    float w[2];
#pragma unroll
    for (int j = 0; j < 2; ++j)
      w[j] = (j < deg) ? __expf(lg[j] - m) : 0.f;
    ushort4 uu[2];
#pragma unroll
    for (int j = 0; j < 2; ++j) uu[j] = ul;
#pragma unroll
    for (int j = 0; j < 2; ++j)
      if (j < deg) uu[j] = *(const ushort4*)(xlr + src[j] * 512 + c0);
    float wself = __expf(lself - m);
    d = wself;
    a0 = wself * xln[0]; a1 = wself * xln[1]; a2 = wself * xln[2]; a3 = wself * xln[3];
#pragma unroll
    for (int j = 0; j < 2; ++j) {
      d += w[j];
      a0 += w[j] * bf2f(uu[j].x);
      a1 += w[j] * bf2f(uu[j].y);
      a2 += w[j] * bf2f(uu[j].z);
      a3 += w[j] * bf2f(uu[j].w);
    }
  } else if (deg <= 4) {
    // ---- 4-slot path (~31% of nodes) ----
    float lg[4];
    int src[4];
    const int elast = e - 1;
    int eid[4];
#pragma unroll
    for (int j = 0; j < 4; ++j) {
      int idx = s + j; if (idx > elast) idx = elast;
      eid[j] = csr[idx];
    }
#pragma unroll
    for (int j = 0; j < 4; ++j) {
      lg[j] = logits[eid[j] * 8 + head];
      src[j] = ei[eid[j]];
    }
#pragma unroll
    for (int j = 0; j < 4; ++j)
      if (j < deg) m = fmaxf(m, lg[j]);
    float w[4];
#pragma unroll
    for (int j = 0; j < 4; ++j)
      w[j] = (j < deg) ? __expf(lg[j] - m) : 0.f;
    ushort4 uu[4];
#pragma unroll
    for (int j = 0; j < 4; ++j) uu[j] = ul;
#pragma unroll
    for (int j = 0; j < 4; ++j)
      if (j < deg) uu[j] = *(const ushort4*)(xlr + src[j] * 512 + c0);
    float wself = __expf(lself - m);
    d = wself;
    a0 = wself * xln[0]; a1 = wself * xln[1]; a2 = wself * xln[2]; a3 = wself * xln[3];
#pragma unroll
    for (int j = 0; j < 4; ++j) {
      d += w[j];
      a0 += w[j] * bf2f(uu[j].x);
      a1 += w[j] * bf2f(uu[j].y);
      a2 += w[j] * bf2f(uu[j].z);
      a3 += w[j] * bf2f(uu[j].w);
    }
  } else {
    // ---- 8-slot path + loop tail (deg > 4) ----
    float lg[8];
    int src[8];
    const int elast = e - 1;
    int eid[8];
#pragma unroll
    for (int j = 0; j < 8; ++j) {
      int idx = s + j; if (idx > elast) idx = elast;
      eid[j] = csr[idx];
    }
#pragma unroll
    for (int j = 0; j < 8; ++j) {
      lg[j] = logits[eid[j] * 8 + head];
      src[j] = ei[eid[j]];
    }
#pragma unroll
    for (int j = 0; j < 8; ++j)
      if (j < deg) m = fmaxf(m, lg[j]);
    for (int idx = s + 8; idx < e; ++idx) {   // rare tail (deg > 8)
      int eidt = csr[idx];
      m = fmaxf(m, logits[eidt * 8 + head]);
    }
    float w[8];
#pragma unroll
    for (int j = 0; j < 8; ++j)
      w[j] = (j < deg) ? __expf(lg[j] - m) : 0.f;
    ushort4 uu[8];
#pragma unroll
    for (int j = 0; j < 8; ++j) uu[j] = ul;
#pragma unroll
    for (int j = 0; j < 8; ++j)
      if (j < deg) uu[j] = *(const ushort4*)(xlr + src[j] * 512 + c0);
    float wself = __expf(lself - m);
    d = wself;
    a0 = wself * xln[0]; a1 = wself * xln[1]; a2 = wself * xln[2]; a3 = wself * xln[3];
#pragma unroll
    for (int j = 0; j < 8; ++j) {
      d += w[j];
      a0 += w[j] * bf2f(uu[j].x);
      a1 += w[j] * bf2f(uu[j].y);
      a2 += w[j] * bf2f(uu[j].z);
      a3 += w[j] * bf2f(uu[j].w);
    }
    for (int idx = s + 8; idx < e; ++idx) {   // rare tail (deg > 8)
      int eidt = csr[idx];
      float l = logits[eidt * 8 + head];
      int sn = ei[eidt];
      float ww = __expf(l - m);
      ushort4 u = *(const ushort4*)(xlr + sn * 512 + c0);
      d += ww;
      a0 += ww * bf2f(u.x);
      a1 += ww * bf2f(u.y);
      a2 += ww * bf2f(u.z);
      a3 += ww * bf2f(u.w);
    }
  }

  float inv = 1.f / (d + 1e-16f);
  float4 bg = *(const float4*)(bgat + c0);
  float ov[4] = {a0 * inv, a1 * inv, a2 * inv, a3 * inv};
  float bgv[4] = {bg.x, bg.y, bg.z, bg.w};
  float hv[4] = {hold.x, hold.y, hold.z, hold.w};
  float4 res;
  float* rp = (float*)&res;
  ushort4 resb;
  unsigned short* rb = (unsigned short*)&resb;
#pragma unroll
  for (int j = 0; j < 4; ++j) {
    float v = (ov[j] + bgv[j]) * BN_S;
    v = (v > 0.f) ? v : (__expf(v) - 1.f);
    float nv = v + hv[j];
    rp[j] = nv;
    rb[j] = f2bf(nv);
  }
  *(float4*)(h + n * HIDDEN + c0) = res;
  *(ushort4*)(hb + n * HIDDEN + c0) = resb;
}

// ---------------- global attention pooling per graph ----------------
__global__ __launch_bounds__(64) void pool_kernel(
    const float* __restrict__ gate, const float* __restrict__ h,
    const int* __restrict__ brp, float* __restrict__ pooled)
{
  int b = blockIdx.x;
  int lane = threadIdx.x;
  int s = brp[b], e = brp[b + 1];
  float m = -__builtin_inff();
  for (int i = s + lane; i < e; i += 64) m = fmaxf(m, gate[i]);
#pragma unroll
  for (int o = 1; o < 64; o <<= 1) m = fmaxf(m, __shfl_xor(m, o));
  float d = 0.f;
  for (int i = s + lane; i < e; i += 64) d += __expf(gate[i] - m);
#pragma unroll
  for (int o = 1; o < 64; o <<= 1) d += __shfl_xor(d, o);
  float inv = 1.f / (d + 1e-16f);
  int c0 = lane * 4;
  float acc[4] = {0.f, 0.f, 0.f, 0.f};
  for (int i = s; i < e; ++i) {
    float w = __expf(gate[i] - m) * inv;
    float4 hv = *(const float4*)(h + (size_t)i * HIDDEN + c0);
    acc[0] = fmaf(w, hv.x, acc[0]);
    acc[1] = fmaf(w, hv.y, acc[1]);
    acc[2] = fmaf(w, hv.z, acc[2]);
    acc[3] = fmaf(w, hv.w, acc[3]);
  }
  float4 outv = make_float4(acc[0], acc[1], acc[2], acc[3]);
  *(float4*)(pooled + (size_t)b * HIDDEN + c0) = outv;
}

// ---------------- final: out[b] = r3[b,:] . W4 + b4 ----------------
__global__ __launch_bounds__(256) void out_kernel(
    const float* __restrict__ r3, const float* __restrict__ W4,
    const float* __restrict__ b4, float* __restrict__ out)
{
  int lane = threadIdx.x & 63;
  int wv = threadIdx.x >> 6;
  int b = blockIdx.x * 4 + wv;
  if (b >= N_B) return;
  float v = r3[(size_t)b * 64 + lane] * W4[lane];
#pragma unroll
  for (int o = 1; o < 64; o <<= 1) v += __shfl_xor(v, o);
  if (lane == 0) out[b] = v + b4[0];
}

extern "C" void kernel_launch(void* const* d_in, const int* in_sizes, int n_in,
                              void* d_out, int out_size, void* d_ws, size_t ws_size,
                              hipStream_t stream)
{
  const float* x    = (const float*)d_in[0];
  const int* ei     = (const int*)d_in[1];
  const float* ea   = (const float*)d_in[2];
  const int* batch  = (const int*)d_in[3];
  const float* W_in = (const float*)d_in[4];
  const float* b_in = (const float*)d_in[5];
  const float* Wl   = (const float*)d_in[6];
  const float* Wr   = (const float*)d_in[7];
  const float* We   = (const float*)d_in[8];
  const float* att  = (const float*)d_in[9];
  const float* bgat = (const float*)d_in[10];
  const float* Wg1  = (const float*)d_in[11];
  const float* bg1  = (const float*)d_in[12];
  const float* Wg2  = (const float*)d_in[13];
  const float* bg2  = (const float*)d_in[14];
  const float* W1   = (const float*)d_in[15];
  const float* b1   = (const float*)d_in[16];
  const float* W2   = (const float*)d_in[17];
  const float* b2   = (const float*)d_in[18];
  const float* W3   = (const float*)d_in[19];
  const float* b3   = (const float*)d_in[20];
  const float* W4   = (const float*)d_in[21];
  const float* b4   = (const float*)d_in[22];
  float* out = (float*)d_out;

  char* ws = (char*)d_ws;
  size_t off = 0;
  auto alloc = [&](size_t bytes) -> char* {
    char* p = ws + off;
    off += (bytes + 255) & ~(size_t)255;
    return p;
  };
  float* h            = (float*)alloc((size_t)N_NODES * HIDDEN * 4);           // 102.4 MB
  unsigned short* hb  = (unsigned short*)alloc((size_t)N_NODES * HIDDEN * 2);  // 51.2 MB
  unsigned short* xlr = (unsigned short*)alloc((size_t)N_NODES * 512 * 2);     // 102.4 MB
  int* deg       = (int*)alloc((size_t)N_NODES * 4);
  int* rowptr    = (int*)alloc((size_t)(N_NODES + 1) * 4);
  int* cursor    = (int*)alloc((size_t)N_NODES * 4);
  int* csr       = (int*)alloc((size_t)N_EDGES * 4);       // real edges only
  int* brp       = (int*)alloc((size_t)(N_B + 1) * 4);
  int* bsum      = (int*)alloc(512);
  float* macc    = (float*)alloc(64);
  float* meanattr= (float*)alloc(64);
  float* ep_self = (float*)alloc(4 * 256 * 4);
  float* logits  = (float*)alloc((size_t)N_EDGES * 8 * 4); // 7.04 MB
  unsigned short* Wint  = (unsigned short*)alloc(256 * 128 * 2);      // [256][128]
  unsigned short* Wlrt  = (unsigned short*)alloc(4 * 512 * 256 * 2);  // [i][512][256] = Wl^T || Wr^T
  unsigned short* Wg1t  = (unsigned short*)alloc(128 * 256 * 2);      // [128][256]
  // total ≈ 266.3 MB < 268.4 MB ws  ✓

  // aliases into dead regions of xlr:
  unsigned short* xpad = xlr;            // [N,128] bf16, pre-layer0 only (25.6 MB < 102.4)
  float* base2  = (float*)xlr;           // xlr fully dead after last attn layer
  float* gate   = base2;                 // [N] f32
  float* pooled = base2 + 1000000;       // [B,256] f32
  float* r1     = base2 + 3000000;       // [B,256] f32
  float* r2     = base2 + 5000000;       // [B,128] f32
  float* r3     = base2 + 6000000;       // [B,64]  f32

  if (ws_size < off) {
    hipMemsetAsync(d_out, 0, (size_t)out_size * 4, stream);
    return;
  }

  zero_kernel<<<391, 256, 0, stream>>>(deg, cursor, macc);
  mean_kernel<<<64, 256, 0, stream>>>(ea, macc);
  meanattr_kernel<<<1, 64, 0, stream>>>(macc, meanattr);
  epself_kernel<<<4, 256, 0, stream>>>(meanattr, We, ep_self);
  count_kernel<<<860, 256, 0, stream>>>(ei, deg);
  scan1_kernel<<<NSCANB, 1024, 0, stream>>>(deg, rowptr, bsum);
  scan2_kernel<<<1, 128, 0, stream>>>(bsum);
  scan3_kernel<<<NSCANB, 1024, 0, stream>>>(rowptr, bsum);
  scatter_kernel<<<860, 256, 0, stream>>>(ei, rowptr, cursor, csr);
  brp_kernel<<<512, 256, 0, stream>>>(batch, brp);

  // weight conversions (transpose + bf16); Wint padded to K=128
  wt_kernel<<<(256 * 128 + 255) / 256, 256, 0, stream>>>(W_in, Wint, 75, 128, 256);
  wlr_kernel<<<512, 256, 0, stream>>>(Wl, Wr, Wlrt);
  wt_kernel<<<128, 256, 0, stream>>>(Wg1, Wg1t, 256, 256, 128);
  convx_kernel<<<4096, 256, 0, stream>>>(x, xpad);

  // input projection: h = elu((x @ W_in + b_in) * BN_S)  [MFMA, K=128 padded, gx=4]
  gemm_mfma<<<3128, 256, 0, stream>>>(xpad, Wint, b_in, h, hb,
                                      N_NODES, 256, 128, 2, BN_S, 4);

  for (int i = 0; i < 4; ++i) {
    // fused xl||xr GEMM: [N,256] @ [256,512] -> xlr [N,512]  (gx=8, 64-col tiles)
    gemm_mfma<<<6256, 256, 0, stream>>>(hb, Wlrt + (size_t)i * 131072, nullptr,
                                        nullptr, xlr, N_NODES, 512, 256, 0, 1.f, 8);
    // pass A: edge-parallel logits (one-shot, 4 edges/wave)
    logits_kernel<<<13750, 256, 0, stream>>>(xlr, ei, ea, We + (size_t)i * 2560,
                                             att + (size_t)i * 256, logits);
    // pass B: node-parallel softmax + aggregate
    attn_kernel<<<25000, 256, 0, stream>>>(xlr, h, hb, ei, logits,
                                           att + (size_t)i * 256, bgat + (size_t)i * 256,
                                           ep_self + (size_t)i * 256, rowptr, csr);
  }

  // fused pooling gate: gate = relu(hb @ Wg1 + bg1) . Wg2 + bg2
  gemm_gate<<<782, 256, 0, stream>>>(hb, Wg1t, bg1, Wg2, bg2, gate, N_NODES);
  pool_kernel<<<N_B, 64, 0, stream>>>(gate, h, brp, pooled);

  // readout MLP (f32, tiny)
  gemm_f32<<<dim3(4, 64), 256, 0, stream>>>(pooled, W1, b1, r1, N_B, 256, 256, 1, BN_S);
  gemm_f32<<<dim3(2, 64), 256, 0, stream>>>(r1, W2, b2, r2, N_B, 128, 256, 1, BN_S);
  gemm_f32<<<dim3(1, 64), 256, 0, stream>>>(r2, W3, b3, r3, N_B, 64, 128, 1, 1.f);
  out_kernel<<<1024, 256, 0, stream>>>(r3, W4, b4, out);
}